// Round 1
// baseline (1050.376 us; speedup 1.0000x reference)
//
#include <hip/hip_runtime.h>
#include <math.h>

#define BIMG 8
#define HW 9216
#define CENC 512
#define NS 64
#define NN 128      // nodes per image
#define DD 256
#define NHEAD 8
#define DH 32
#define ROWS1 1024   // BIMG*NN
#define ROWS2 2048   // 2*BIMG*NN

// ---------------- top-k (64 pos desc, 64 neg asc) on sigmoid(score) ----------------
__global__ __launch_bounds__(256) void topk_kernel(const float* __restrict__ score_s,
                                                   const float* __restrict__ score_t,
                                                   int* __restrict__ idx_out,
                                                   float* __restrict__ loss_acc) {
  __shared__ float sc[HW];
  __shared__ float rv[256];
  __shared__ int   ri[256];
  int bi = blockIdx.x;            // 0..15 : tensor = bi/8, image = bi%8
  int tid = threadIdx.x;
  if (bi == 0 && tid < 2) loss_acc[tid] = 0.f;
  const float* sp = (bi < 8 ? score_s : score_t) + (size_t)(bi & 7) * HW;
  for (int i = tid; i < HW; i += 256) {
    float x = sp[i];
    sc[i] = 1.0f / (1.0f + expf(-x));
  }
  __syncthreads();
  int* myidx = idx_out + bi * NN;
  // positives: iterative argmax, tie -> lower index
  for (int it = 0; it < NS; ++it) {
    float bv = -1e30f; int bj = 0x7fffffff;
    for (int i = tid; i < HW; i += 256) {
      float v = sc[i];
      if (v > bv) { bv = v; bj = i; }
    }
    rv[tid] = bv; ri[tid] = bj;
    __syncthreads();
    for (int s = 128; s > 0; s >>= 1) {
      if (tid < s) {
        float ov = rv[tid+s]; int oj = ri[tid+s];
        if (ov > rv[tid] || (ov == rv[tid] && oj < ri[tid])) { rv[tid]=ov; ri[tid]=oj; }
      }
      __syncthreads();
    }
    int sel = ri[0];
    if (tid == 0) myidx[it] = sel;
    __syncthreads();
    if (tid == 0) sc[sel] = -1e30f;
    __syncthreads();
  }
  // reload, then negatives: iterative argmin, tie -> lower index
  for (int i = tid; i < HW; i += 256) {
    float x = sp[i];
    sc[i] = 1.0f / (1.0f + expf(-x));
  }
  __syncthreads();
  for (int it = 0; it < NS; ++it) {
    float bv = 1e30f; int bj = 0x7fffffff;
    for (int i = tid; i < HW; i += 256) {
      float v = sc[i];
      if (v < bv) { bv = v; bj = i; }
    }
    rv[tid] = bv; ri[tid] = bj;
    __syncthreads();
    for (int s = 128; s > 0; s >>= 1) {
      if (tid < s) {
        float ov = rv[tid+s]; int oj = ri[tid+s];
        if (ov < rv[tid] || (ov == rv[tid] && oj < ri[tid])) { rv[tid]=ov; ri[tid]=oj; }
      }
      __syncthreads();
    }
    int sel = ri[0];
    if (tid == 0) myidx[NS + it] = sel;
    __syncthreads();
    if (tid == 0) sc[sel] = 1e30f;
    __syncthreads();
  }
}

// ---------------- gather nodes[row][c] = feat[b][c][pos] ----------------
__global__ __launch_bounds__(256) void gather_kernel(const float* __restrict__ feat_s,
                                                     const float* __restrict__ feat_t,
                                                     const int* __restrict__ idx,
                                                     float* __restrict__ nodes) {
  int blk = blockIdx.x;           // bi*NN + n, bi in [0,16)
  int bi = blk / NN, n = blk % NN;
  int b = bi & 7;
  const float* fp = (bi < 8) ? feat_s : feat_t;
  int pos = idx[bi * NN + n];
  const float* src = fp + (size_t)b * CENC * HW + pos;
  float* dst = nodes + (size_t)blk * CENC;
  for (int c = threadIdx.x; c < CENC; c += 256)
    dst[c] = src[(size_t)c * HW];
}

// ---------------- generic fp32 GEMM: C = A[M,K] @ W[K,N] + bias, opt relu ----------------
__global__ __launch_bounds__(256) void gemm_bias(const float* __restrict__ A,
                                                 const float* __restrict__ W,
                                                 const float* __restrict__ bias,
                                                 float* __restrict__ C,
                                                 int M, int N, int K, int relu) {
  __shared__ float As[16][65];   // [k][m], padded
  __shared__ float Bs[16][64];   // [k][n]
  int n0 = blockIdx.x * 64;
  int m0 = blockIdx.y * 64;
  int tid = threadIdx.x;
  int tx = tid & 15, ty = tid >> 4;
  float acc[4][4] = {{0.f}};
  for (int k0 = 0; k0 < K; k0 += 16) {
#pragma unroll
    for (int i = 0; i < 4; ++i) {
      int idx = tid + i * 256;
      int r = idx >> 4, c = idx & 15;
      As[c][r] = A[(size_t)(m0 + r) * K + k0 + c];
      int rb = idx >> 6, cb = idx & 63;
      Bs[rb][cb] = W[(size_t)(k0 + rb) * N + n0 + cb];
    }
    __syncthreads();
#pragma unroll
    for (int kk = 0; kk < 16; ++kk) {
      float a[4], b[4];
#pragma unroll
      for (int i = 0; i < 4; ++i) a[i] = As[kk][ty*4+i];
#pragma unroll
      for (int j = 0; j < 4; ++j) b[j] = Bs[kk][tx*4+j];
#pragma unroll
      for (int i = 0; i < 4; ++i)
#pragma unroll
        for (int j = 0; j < 4; ++j)
          acc[i][j] += a[i] * b[j];
    }
    __syncthreads();
  }
#pragma unroll
  for (int i = 0; i < 4; ++i) {
    int m = m0 + ty*4 + i;
#pragma unroll
    for (int j = 0; j < 4; ++j) {
      int n = n0 + tx*4 + j;
      float v = acc[i][j] + (bias ? bias[n] : 0.f);
      if (relu) v = fmaxf(v, 0.f);
      C[(size_t)m * N + n] = v;
    }
  }
}

// ---------------- LayerNorm (no affine) over D=256, optional ReLU after ----------------
__global__ __launch_bounds__(256) void ln_kernel(const float* __restrict__ x,
                                                 float* __restrict__ y, int relu_after) {
  __shared__ float red[256];
  int row = blockIdx.x;
  int tid = threadIdx.x;
  float v = x[(size_t)row * DD + tid];
  red[tid] = v;
  __syncthreads();
  for (int s = 128; s > 0; s >>= 1) { if (tid < s) red[tid] += red[tid+s]; __syncthreads(); }
  float mean = red[0] * (1.0f / DD);
  __syncthreads();
  float d = v - mean;
  red[tid] = d * d;
  __syncthreads();
  for (int s = 128; s > 0; s >>= 1) { if (tid < s) red[tid] += red[tid+s]; __syncthreads(); }
  float var = red[0] * (1.0f / DD);
  float out = d / sqrtf(var + 1e-5f);
  if (relu_after) out = fmaxf(out, 0.f);
  y[(size_t)row * DD + tid] = out;
}

// ---------------- fused attention per (bb, head): softmax(QK^T/sqrt(32)) V ----------------
__global__ __launch_bounds__(128) void attn_kernel(const float* __restrict__ q,
                                                   const float* __restrict__ k,
                                                   const float* __restrict__ v,
                                                   float* __restrict__ o, int swap) {
  __shared__ float Ks[NN][DH];
  __shared__ float Vs[NN][DH];
  int blk = blockIdx.x;          // bb*8 + h, bb in [0,16)
  int bb = blk >> 3, h = blk & 7;
  int kb = swap ? (bb ^ 8) : bb;
  int tid = threadIdx.x;         // 128: one q-row per thread
  for (int e = tid; e < NN * DH; e += 128) {
    int r = e >> 5, c = e & 31;
    Ks[r][c] = k[(size_t)(kb * NN + r) * DD + h * DH + c];
    Vs[r][c] = v[(size_t)(kb * NN + r) * DD + h * DH + c];
  }
  __syncthreads();
  float qreg[DH];
  const float* qp = q + (size_t)(bb * NN + tid) * DD + h * DH;
#pragma unroll
  for (int c = 0; c < DH; ++c) qreg[c] = qp[c];
  const float scale = 0.17677669529663687f;   // 1/sqrt(32)
  float mx = -1e30f;
  for (int j = 0; j < NN; ++j) {
    float s = 0.f;
#pragma unroll
    for (int c = 0; c < DH; ++c) s += qreg[c] * Ks[j][c];
    mx = fmaxf(mx, s * scale);
  }
  float acc[DH];
#pragma unroll
  for (int c = 0; c < DH; ++c) acc[c] = 0.f;
  float denom = 0.f;
  for (int j = 0; j < NN; ++j) {
    float s = 0.f;
#pragma unroll
    for (int c = 0; c < DH; ++c) s += qreg[c] * Ks[j][c];
    float e = expf(s * scale - mx);
    denom += e;
#pragma unroll
    for (int c = 0; c < DH; ++c) acc[c] += e * Vs[j][c];
  }
  float inv = 1.f / denom;
  float* op = o + (size_t)(bb * NN + tid) * DD + h * DH;
#pragma unroll
  for (int c = 0; c < DH; ++c) op[c] = acc[c] * inv;
}

// ---------------- cls MLP + BCEWithLogits, accumulate sum/1024 into loss_acc[0] ----------------
__global__ __launch_bounds__(128) void cls_loss_kernel(const float* __restrict__ x,
                                                       const float* __restrict__ W1,
                                                       const float* __restrict__ b1,
                                                       const float* __restrict__ W2,
                                                       const float* __restrict__ b2,
                                                       float* __restrict__ loss_acc) {
  __shared__ float xs[DD];
  __shared__ float red[128];
  int row = blockIdx.x;          // 0..2047
  int tid = threadIdx.x;         // 128
  xs[tid]       = x[(size_t)row * DD + tid];
  xs[tid + 128] = x[(size_t)row * DD + tid + 128];
  __syncthreads();
  float h = b1[tid];
  for (int kk = 0; kk < DD; ++kk) h += xs[kk] * W1[kk * 128 + tid];
  h = fmaxf(h, 0.f);
  red[tid] = h * W2[tid];
  __syncthreads();
  for (int s = 64; s > 0; s >>= 1) { if (tid < s) red[tid] += red[tid+s]; __syncthreads(); }
  if (tid == 0) {
    float z = red[0] + b2[0];
    float lab = ((row & 127) < 64) ? 1.f : 0.f;
    float bce = fmaxf(z, 0.f) - z * lab + log1pf(expf(-fabsf(z)));
    atomicAdd(loss_acc, bce * (1.0f / 1024.0f));
  }
}

// ---------------- Mmat[b][i][j] = dot(t1[b,i,:], n2[b,j,:]) ----------------
__global__ __launch_bounds__(128) void mmat_kernel(const float* __restrict__ t1,
                                                   const float* __restrict__ n2,
                                                   float* __restrict__ Mm) {
  __shared__ float ts[DD];
  int blk = blockIdx.x;          // b*NN + i
  int b = blk >> 7, i = blk & 127;
  int tid = threadIdx.x;         // 128: j
  ts[tid]       = t1[(size_t)blk * DD + tid];
  ts[tid + 128] = t1[(size_t)blk * DD + tid + 128];
  __syncthreads();
  const float* np2 = n2 + (size_t)(b * NN + tid) * DD;
  float s = 0.f;
  for (int kk = 0; kk < DD; ++kk) s += ts[kk] * np2[kk];
  Mm[(size_t)b * NN * NN + (size_t)i * NN + tid] = s;
}

// ---------------- instance-norm + 10 sinkhorn iters + focal loss (per b) ----------------
__global__ __launch_bounds__(256) void sinkhorn_kernel(const float* __restrict__ Mm,
                                                       float* __restrict__ loss_acc) {
  // element (i,j) stored at Km[i*128 + (j ^ (i&31))] -> both row & col passes conflict-free
  __shared__ float Km[NN * NN];
  __shared__ float red[256];
  __shared__ float lse[NN];
  int b = blockIdx.x;
  int tid = threadIdx.x;
  const float* src = Mm + (size_t)b * NN * NN;
  float lsum = 0.f;
  for (int l = tid; l < NN * NN; l += 256) {
    int i = l >> 7, j = l & 127;
    float v = src[l];
    Km[i * NN + (j ^ (i & 31))] = v;
    lsum += v;
  }
  red[tid] = lsum; __syncthreads();
  for (int s = 128; s > 0; s >>= 1) { if (tid < s) red[tid] += red[tid+s]; __syncthreads(); }
  float mu = red[0] * (1.0f / 16384.f);
  __syncthreads();
  float lsq = 0.f;
  for (int l = tid; l < NN * NN; l += 256) {
    float d = Km[l] - mu;      // swizzle permutes within rows; full-sum invariant
    lsq += d * d;
  }
  red[tid] = lsq; __syncthreads();
  for (int s = 128; s > 0; s >>= 1) { if (tid < s) red[tid] += red[tid+s]; __syncthreads(); }
  float inv = 1.0f / sqrtf(red[0] * (1.0f / 16384.f) + 1e-5f);
  __syncthreads();
  for (int l = tid; l < NN * NN; l += 256)
    Km[l] = (Km[l] - mu) * inv;
  __syncthreads();
  for (int iter = 0; iter < 10; ++iter) {
    if (tid < NN) {                       // row lse
      int r = tid, rx = r & 31;
      float mx = -1e30f;
      for (int j = 0; j < NN; ++j) mx = fmaxf(mx, Km[r * NN + (j ^ rx)]);
      float sm = 0.f;
      for (int j = 0; j < NN; ++j) sm += expf(Km[r * NN + (j ^ rx)] - mx);
      lse[r] = mx + logf(sm);
    }
    __syncthreads();
    for (int l = tid; l < NN * NN; l += 256)
      Km[l] -= lse[l >> 7];
    __syncthreads();
    if (tid < NN) {                       // col lse
      int j = tid;
      float mx = -1e30f;
      for (int i = 0; i < NN; ++i) mx = fmaxf(mx, Km[i * NN + (j ^ (i & 31))]);
      float sm = 0.f;
      for (int i = 0; i < NN; ++i) sm += expf(Km[i * NN + (j ^ (i & 31))] - mx);
      lse[j] = mx + logf(sm);
    }
    __syncthreads();
    for (int l = tid; l < NN * NN; l += 256) {
      int i = l >> 7, jj = l & 127;
      Km[l] -= lse[jj ^ (i & 31)];
    }
    __syncthreads();
  }
  float fsum = 0.f;
  for (int l = tid; l < NN * NN; l += 256) {
    int i = l >> 7, jj = l & 127;
    int j = jj ^ (i & 31);
    float P = expf(Km[l]);
    float pt = fminf(fmaxf(P, 1e-6f), 1.0f - 1e-6f);
    float gt = ((i < 64) == (j < 64)) ? 1.f : 0.f;
    fsum += -0.25f * (1.f - pt) * (1.f - pt) * gt * logf(pt)
            -0.75f * pt * pt * (1.f - gt) * logf(1.f - pt);
  }
  red[tid] = fsum; __syncthreads();
  for (int s = 128; s > 0; s >>= 1) { if (tid < s) red[tid] += red[tid+s]; __syncthreads(); }
  if (tid == 0) atomicAdd(loss_acc + 1, red[0] * (1.0f / 131072.f));
}

// ---------------- copy n1 + total loss ----------------
__global__ __launch_bounds__(256) void finalize_kernel(const float* __restrict__ c1,
                                                       const float* __restrict__ loss_acc,
                                                       float* __restrict__ out) {
  int g = blockIdx.x * 256 + threadIdx.x;
  if (g < ROWS1 * DD) out[g] = c1[g];
  if (g == 0) out[ROWS1 * DD] = loss_acc[0] + 10.0f * loss_acc[1];
}

extern "C" void kernel_launch(void* const* d_in, const int* in_sizes, int n_in,
                              void* d_out, int out_size, void* d_ws, size_t ws_size,
                              hipStream_t stream) {
  const float* feat_s  = (const float*)d_in[0];
  const float* score_s = (const float*)d_in[1];
  const float* feat_t  = (const float*)d_in[2];
  const float* score_t = (const float*)d_in[3];
  const float* head_W1 = (const float*)d_in[4];
  const float* head_b1 = (const float*)d_in[5];
  const float* head_W2 = (const float*)d_in[6];
  const float* head_b2 = (const float*)d_in[7];
  const float* intra_W = (const float*)d_in[8];
  const float* intra_b = (const float*)d_in[9];
  const float* cross_W = (const float*)d_in[10];
  const float* cross_b = (const float*)d_in[11];
  const float* cls_W1  = (const float*)d_in[12];
  const float* cls_b1  = (const float*)d_in[13];
  const float* cls_W2  = (const float*)d_in[14];
  const float* cls_b2  = (const float*)d_in[15];
  const float* aff_A   = (const float*)d_in[16];

  float* ws = (float*)d_ws;
  float* nodes = ws;                         // 2048*512
  float* bufA  = nodes + 2048 * 512;         // 2048*256 each below
  float* bufB  = bufA + ROWS2 * DD;
  float* bufQ  = bufB + ROWS2 * DD;
  float* bufK  = bufQ + ROWS2 * DD;
  float* bufV  = bufK + ROWS2 * DD;
  float* acc   = bufV + ROWS2 * DD;          // 2 floats (pad 8)
  int*   idxb  = (int*)(acc + 8);            // 16*128 ints
  float* Mm    = (float*)(idxb + 2048);      // 8*128*128

  topk_kernel<<<16, 256, 0, stream>>>(score_s, score_t, idxb, acc);
  gather_kernel<<<16 * NN, 256, 0, stream>>>(feat_s, feat_t, idxb, nodes);

  dim3 g1(4, 32);   // N/64, M/64 for M=2048
  // head: Linear->LN->ReLU->Linear->LN
  gemm_bias<<<g1, 256, 0, stream>>>(nodes, head_W1, head_b1, bufA, ROWS2, DD, CENC, 0);
  ln_kernel<<<ROWS2, 256, 0, stream>>>(bufA, bufB, 1);
  gemm_bias<<<g1, 256, 0, stream>>>(bufB, head_W2, head_b2, bufA, ROWS2, DD, DD, 0);
  ln_kernel<<<ROWS2, 256, 0, stream>>>(bufA, bufB, 0);            // bufB = H

  // intra self-attention (shared weights, both domains batched)
  gemm_bias<<<g1, 256, 0, stream>>>(bufB, intra_W + 0*65536, intra_b + 0*256, bufQ, ROWS2, DD, DD, 0);
  gemm_bias<<<g1, 256, 0, stream>>>(bufB, intra_W + 1*65536, intra_b + 1*256, bufK, ROWS2, DD, DD, 0);
  gemm_bias<<<g1, 256, 0, stream>>>(bufB, intra_W + 2*65536, intra_b + 2*256, bufV, ROWS2, DD, DD, 0);
  attn_kernel<<<16 * NHEAD, 128, 0, stream>>>(bufQ, bufK, bufV, bufA, 0);
  gemm_bias<<<g1, 256, 0, stream>>>(bufA, intra_W + 3*65536, intra_b + 3*256, bufB, ROWS2, DD, DD, 0); // G

  // cross attention (swap kv halves)
  gemm_bias<<<g1, 256, 0, stream>>>(bufB, cross_W + 0*65536, cross_b + 0*256, bufQ, ROWS2, DD, DD, 0);
  gemm_bias<<<g1, 256, 0, stream>>>(bufB, cross_W + 1*65536, cross_b + 1*256, bufK, ROWS2, DD, DD, 0);
  gemm_bias<<<g1, 256, 0, stream>>>(bufB, cross_W + 2*65536, cross_b + 2*256, bufV, ROWS2, DD, DD, 0);
  attn_kernel<<<16 * NHEAD, 128, 0, stream>>>(bufQ, bufK, bufV, bufA, 1);
  gemm_bias<<<g1, 256, 0, stream>>>(bufA, cross_W + 3*65536, cross_b + 3*256, bufQ, ROWS2, DD, DD, 0); // C=bufQ

  // node classification loss (both domains)
  cls_loss_kernel<<<ROWS2, 128, 0, stream>>>(bufQ, cls_W1, cls_b1, cls_W2, cls_b2, acc);

  // affinity: tmp = c1 @ aff_A ; Mmat = tmp @ c2^T
  dim3 g2(4, 16);
  gemm_bias<<<g2, 256, 0, stream>>>(bufQ, aff_A, (const float*)nullptr, bufA, ROWS1, DD, DD, 0);
  mmat_kernel<<<ROWS1, 128, 0, stream>>>(bufA, bufQ + (size_t)ROWS1 * DD, Mm);

  // instance-norm + sinkhorn + focal loss
  sinkhorn_kernel<<<BIMG, 256, 0, stream>>>(Mm, acc);

  // output: n1 (=c1) then total loss
  finalize_kernel<<<ROWS1 * DD / 256, 256, 0, stream>>>(bufQ, acc, (float*)d_out);
}

// Round 2
// 583.688 us; speedup vs baseline: 1.7996x; 1.7996x over previous
//
#include <hip/hip_runtime.h>
#include <math.h>

#define BIMG 8
#define HW 9216
#define CENC 512
#define NS 64
#define NN 128      // nodes per image
#define DD 256
#define NHEAD 8
#define DH 32
#define ROWS1 1024   // BIMG*NN
#define ROWS2 2048   // 2*BIMG*NN
#define LPT 36       // HW / 256

// ---------------- top-k (64 pos desc, 64 neg asc) on raw score (sigmoid monotone) ----------------
__global__ __launch_bounds__(256) void topk_kernel(const float* __restrict__ score_s,
                                                   const float* __restrict__ score_t,
                                                   int* __restrict__ idx_out,
                                                   float* __restrict__ loss_acc) {
  __shared__ float wv[4];
  __shared__ int   wi[4];
  __shared__ int   ssel;
  int bi = blockIdx.x, tid = threadIdx.x;
  int lane = tid & 63, wid = tid >> 6;
  if (bi == 0 && tid < 2) loss_acc[tid] = 0.f;
  const float* sp = (bi < 8 ? score_s : score_t) + (size_t)(bi & 7) * HW;
  float val[LPT];
#pragma unroll
  for (int q = 0; q < LPT; ++q) val[q] = sp[q * 256 + tid];
  int* myidx = idx_out + bi * NN;

  // ================= positives: iterative argmax, tie -> lower index =================
  {
    unsigned long long removed = 0ull;
    float v1 = -3.0e38f, v2 = -3.0e38f; int i1 = 1 << 30, i2 = 1 << 30;
#pragma unroll
    for (int q = 0; q < LPT; ++q) {
      float x = val[q]; int gi = q * 256 + tid;
      if (x > v1 || (x == v1 && gi < i1)) { v2 = v1; i2 = i1; v1 = x; i1 = gi; }
      else if (x > v2 || (x == v2 && gi < i2)) { v2 = x; i2 = gi; }
    }
    for (int it = 0; it < NS; ++it) {
      float bv = v1; int bj = i1;
      for (int m = 1; m < 64; m <<= 1) {
        float ov = __shfl_xor(bv, m); int oj = __shfl_xor(bj, m);
        if (ov > bv || (ov == bv && oj < bj)) { bv = ov; bj = oj; }
      }
      if (lane == 0) { wv[wid] = bv; wi[wid] = bj; }
      __syncthreads();
      if (tid == 0) {
        float fv = wv[0]; int fj = wi[0];
        for (int w = 1; w < 4; ++w)
          if (wv[w] > fv || (wv[w] == fv && wi[w] < fj)) { fv = wv[w]; fj = wi[w]; }
        myidx[it] = fj; ssel = fj;
      }
      __syncthreads();
      int sel = ssel;
      if ((sel & 255) == tid) {
        removed |= 1ull << (sel >> 8);
        if (i2 != (1 << 30)) { v1 = v2; i1 = i2; v2 = -3.0e38f; i2 = 1 << 30; }
        else {
          v1 = -3.0e38f; i1 = 1 << 30; v2 = -3.0e38f; i2 = 1 << 30;
#pragma unroll
          for (int q = 0; q < LPT; ++q) {
            if (removed & (1ull << q)) continue;
            float x = val[q]; int gi = q * 256 + tid;
            if (x > v1 || (x == v1 && gi < i1)) { v2 = v1; i2 = i1; v1 = x; i1 = gi; }
            else if (x > v2 || (x == v2 && gi < i2)) { v2 = x; i2 = gi; }
          }
        }
      }
    }
  }
  __syncthreads();
  // ================= negatives: iterative argmin, tie -> lower index =================
  {
    unsigned long long removed = 0ull;
    float v1 = 3.0e38f, v2 = 3.0e38f; int i1 = 1 << 30, i2 = 1 << 30;
#pragma unroll
    for (int q = 0; q < LPT; ++q) {
      float x = val[q]; int gi = q * 256 + tid;
      if (x < v1 || (x == v1 && gi < i1)) { v2 = v1; i2 = i1; v1 = x; i1 = gi; }
      else if (x < v2 || (x == v2 && gi < i2)) { v2 = x; i2 = gi; }
    }
    for (int it = 0; it < NS; ++it) {
      float bv = v1; int bj = i1;
      for (int m = 1; m < 64; m <<= 1) {
        float ov = __shfl_xor(bv, m); int oj = __shfl_xor(bj, m);
        if (ov < bv || (ov == bv && oj < bj)) { bv = ov; bj = oj; }
      }
      if (lane == 0) { wv[wid] = bv; wi[wid] = bj; }
      __syncthreads();
      if (tid == 0) {
        float fv = wv[0]; int fj = wi[0];
        for (int w = 1; w < 4; ++w)
          if (wv[w] < fv || (wv[w] == fv && wi[w] < fj)) { fv = wv[w]; fj = wi[w]; }
        myidx[NS + it] = fj; ssel = fj;
      }
      __syncthreads();
      int sel = ssel;
      if ((sel & 255) == tid) {
        removed |= 1ull << (sel >> 8);
        if (i2 != (1 << 30)) { v1 = v2; i1 = i2; v2 = 3.0e38f; i2 = 1 << 30; }
        else {
          v1 = 3.0e38f; i1 = 1 << 30; v2 = 3.0e38f; i2 = 1 << 30;
#pragma unroll
          for (int q = 0; q < LPT; ++q) {
            if (removed & (1ull << q)) continue;
            float x = val[q]; int gi = q * 256 + tid;
            if (x < v1 || (x == v1 && gi < i1)) { v2 = v1; i2 = i1; v1 = x; i1 = gi; }
            else if (x < v2 || (x == v2 && gi < i2)) { v2 = x; i2 = gi; }
          }
        }
      }
    }
  }
}

// ---------------- gather nodes[row][c] = feat[b][c][pos] ----------------
__global__ __launch_bounds__(256) void gather_kernel(const float* __restrict__ feat_s,
                                                     const float* __restrict__ feat_t,
                                                     const int* __restrict__ idx,
                                                     float* __restrict__ nodes) {
  int blk = blockIdx.x;           // bi*NN + n, bi in [0,16)
  int bi = blk / NN, n = blk % NN;
  int b = bi & 7;
  const float* fp = (bi < 8) ? feat_s : feat_t;
  int pos = idx[bi * NN + n];
  const float* src = fp + (size_t)b * CENC * HW + pos;
  float* dst = nodes + (size_t)blk * CENC;
  for (int c = threadIdx.x; c < CENC; c += 256)
    dst[c] = src[(size_t)c * HW];
}

// ---------------- fp32 GEMM: C = A[M,K] @ W[K,N] + bias, opt relu, z-batched weights ----------------
__global__ __launch_bounds__(256) void gemm_bias(const float* __restrict__ A,
                                                 const float* __restrict__ W,
                                                 const float* __restrict__ bias,
                                                 float* __restrict__ C,
                                                 int M, int N, int K, int relu,
                                                 int Wstride, int bstride, int Cstride) {
  __shared__ float As[16][68];   // [k][m], padded, float4-aligned rows
  __shared__ float Bs[16][64];   // [k][n]
  int z = blockIdx.z;
  W += (size_t)z * Wstride;
  if (bias) bias += (size_t)z * bstride;
  C += (size_t)z * Cstride;
  int n0 = blockIdx.x * 64;
  int m0 = blockIdx.y * 64;
  int tid = threadIdx.x;
  int tx = tid & 15, ty = tid >> 4;
  int ar = tid >> 2, ac4 = tid & 3;     // A-tile: 64 rows x 4 float4-chunks
  int bk = tid >> 4, bn4 = tid & 15;    // B-tile: 16 k-rows x 16 float4-chunks
  float acc[4][4] = {{0.f}};
  for (int k0 = 0; k0 < K; k0 += 16) {
    float4 a4 = *(const float4*)&A[(size_t)(m0 + ar) * K + k0 + ac4 * 4];
    float4 b4 = *(const float4*)&W[(size_t)(k0 + bk) * N + n0 + bn4 * 4];
    As[ac4 * 4 + 0][ar] = a4.x;
    As[ac4 * 4 + 1][ar] = a4.y;
    As[ac4 * 4 + 2][ar] = a4.z;
    As[ac4 * 4 + 3][ar] = a4.w;
    *(float4*)&Bs[bk][bn4 * 4] = b4;
    __syncthreads();
#pragma unroll
    for (int kk = 0; kk < 16; ++kk) {
      float4 av = *(const float4*)&As[kk][ty * 4];
      float4 bv = *(const float4*)&Bs[kk][tx * 4];
      float a[4] = {av.x, av.y, av.z, av.w};
      float b[4] = {bv.x, bv.y, bv.z, bv.w};
#pragma unroll
      for (int i = 0; i < 4; ++i)
#pragma unroll
        for (int j = 0; j < 4; ++j)
          acc[i][j] += a[i] * b[j];
    }
    __syncthreads();
  }
  float4 bb = {0.f, 0.f, 0.f, 0.f};
  if (bias) bb = *(const float4*)&bias[n0 + tx * 4];
#pragma unroll
  for (int i = 0; i < 4; ++i) {
    int m = m0 + ty * 4 + i;
    float4 o;
    o.x = acc[i][0] + bb.x; o.y = acc[i][1] + bb.y;
    o.z = acc[i][2] + bb.z; o.w = acc[i][3] + bb.w;
    if (relu) {
      o.x = fmaxf(o.x, 0.f); o.y = fmaxf(o.y, 0.f);
      o.z = fmaxf(o.z, 0.f); o.w = fmaxf(o.w, 0.f);
    }
    *(float4*)&C[(size_t)m * N + n0 + tx * 4] = o;
  }
}

// ---------------- NT GEMM per image: Mm[b] = A[b](128x256) @ Bt[b](128x256)^T ----------------
__global__ __launch_bounds__(256) void gemm_nt(const float* __restrict__ A,
                                               const float* __restrict__ Bt,
                                               float* __restrict__ C) {
  __shared__ float As[16][68];
  __shared__ float Bs[16][68];
  int b = blockIdx.z;
  int m0 = blockIdx.y * 64, n0 = blockIdx.x * 64;
  const float* Ab = A + (size_t)b * NN * DD;
  const float* Bb = Bt + (size_t)b * NN * DD;
  int tid = threadIdx.x;
  int tx = tid & 15, ty = tid >> 4;
  int ar = tid >> 2, ac4 = tid & 3;
  float acc[4][4] = {{0.f}};
  for (int k0 = 0; k0 < DD; k0 += 16) {
    float4 a4 = *(const float4*)&Ab[(size_t)(m0 + ar) * DD + k0 + ac4 * 4];
    float4 b4 = *(const float4*)&Bb[(size_t)(n0 + ar) * DD + k0 + ac4 * 4];
    As[ac4 * 4 + 0][ar] = a4.x; As[ac4 * 4 + 1][ar] = a4.y;
    As[ac4 * 4 + 2][ar] = a4.z; As[ac4 * 4 + 3][ar] = a4.w;
    Bs[ac4 * 4 + 0][ar] = b4.x; Bs[ac4 * 4 + 1][ar] = b4.y;
    Bs[ac4 * 4 + 2][ar] = b4.z; Bs[ac4 * 4 + 3][ar] = b4.w;
    __syncthreads();
#pragma unroll
    for (int kk = 0; kk < 16; ++kk) {
      float4 av = *(const float4*)&As[kk][ty * 4];
      float4 bv = *(const float4*)&Bs[kk][tx * 4];
      float a[4] = {av.x, av.y, av.z, av.w};
      float bx[4] = {bv.x, bv.y, bv.z, bv.w};
#pragma unroll
      for (int i = 0; i < 4; ++i)
#pragma unroll
        for (int j = 0; j < 4; ++j)
          acc[i][j] += a[i] * bx[j];
    }
    __syncthreads();
  }
#pragma unroll
  for (int i = 0; i < 4; ++i) {
    float4 o = {acc[i][0], acc[i][1], acc[i][2], acc[i][3]};
    *(float4*)&C[(size_t)b * NN * NN + (size_t)(m0 + ty * 4 + i) * NN + n0 + tx * 4] = o;
  }
}

// ---------------- LayerNorm (no affine) over D=256, one row per wave ----------------
__global__ __launch_bounds__(256) void ln_kernel(const float* __restrict__ x,
                                                 float* __restrict__ y, int relu_after) {
  int wid = threadIdx.x >> 6, lane = threadIdx.x & 63;
  int row = blockIdx.x * 4 + wid;
  float4 v = ((const float4*)(x + (size_t)row * DD))[lane];
  float s = v.x + v.y + v.z + v.w;
  for (int m = 1; m < 64; m <<= 1) s += __shfl_xor(s, m);
  float mean = s * (1.0f / DD);
  float d0 = v.x - mean, d1 = v.y - mean, d2 = v.z - mean, d3 = v.w - mean;
  float ss = d0 * d0 + d1 * d1 + d2 * d2 + d3 * d3;
  for (int m = 1; m < 64; m <<= 1) ss += __shfl_xor(ss, m);
  float inv = 1.0f / sqrtf(ss * (1.0f / DD) + 1e-5f);
  float4 o = {d0 * inv, d1 * inv, d2 * inv, d3 * inv};
  if (relu_after) {
    o.x = fmaxf(o.x, 0.f); o.y = fmaxf(o.y, 0.f);
    o.z = fmaxf(o.z, 0.f); o.w = fmaxf(o.w, 0.f);
  }
  ((float4*)(y + (size_t)row * DD))[lane] = o;
}

// ---------------- fused attention per (bb, head): softmax(QK^T/sqrt(32)) V ----------------
__global__ __launch_bounds__(128) void attn_kernel(const float* __restrict__ q,
                                                   const float* __restrict__ k,
                                                   const float* __restrict__ v,
                                                   float* __restrict__ o, int swap) {
  __shared__ __align__(16) float Ks[NN][DH];
  __shared__ __align__(16) float Vs[NN][DH];
  int blk = blockIdx.x;          // bb*8 + h, bb in [0,16)
  int bb = blk >> 3, h = blk & 7;
  int kb = swap ? (bb ^ 8) : bb;
  int tid = threadIdx.x;         // 128: one q-row per thread
  for (int e4 = tid; e4 < NN * DH / 4; e4 += 128) {
    int r = e4 >> 3, c4 = e4 & 7;
    ((float4*)Ks[r])[c4] = *(const float4*)&k[(size_t)(kb * NN + r) * DD + h * DH + c4 * 4];
    ((float4*)Vs[r])[c4] = *(const float4*)&v[(size_t)(kb * NN + r) * DD + h * DH + c4 * 4];
  }
  __syncthreads();
  float4 q4[8];
  const float* qp = q + (size_t)(bb * NN + tid) * DD + h * DH;
#pragma unroll
  for (int c4 = 0; c4 < 8; ++c4) q4[c4] = ((const float4*)qp)[c4];
  const float scale = 0.17677669529663687f;   // 1/sqrt(32)
  float mx = -1e30f;
  for (int j = 0; j < NN; ++j) {
    const float4* kp = (const float4*)Ks[j];
    float s = 0.f;
#pragma unroll
    for (int c4 = 0; c4 < 8; ++c4) {
      float4 kv = kp[c4];
      s += q4[c4].x * kv.x + q4[c4].y * kv.y + q4[c4].z * kv.z + q4[c4].w * kv.w;
    }
    mx = fmaxf(mx, s * scale);
  }
  float acc[DH];
#pragma unroll
  for (int c = 0; c < DH; ++c) acc[c] = 0.f;
  float denom = 0.f;
  for (int j = 0; j < NN; ++j) {
    const float4* kp = (const float4*)Ks[j];
    float s = 0.f;
#pragma unroll
    for (int c4 = 0; c4 < 8; ++c4) {
      float4 kv = kp[c4];
      s += q4[c4].x * kv.x + q4[c4].y * kv.y + q4[c4].z * kv.z + q4[c4].w * kv.w;
    }
    float e = expf(s * scale - mx);
    denom += e;
    const float4* vp = (const float4*)Vs[j];
#pragma unroll
    for (int c4 = 0; c4 < 8; ++c4) {
      float4 vv = vp[c4];
      acc[c4 * 4 + 0] += e * vv.x; acc[c4 * 4 + 1] += e * vv.y;
      acc[c4 * 4 + 2] += e * vv.z; acc[c4 * 4 + 3] += e * vv.w;
    }
  }
  float inv = 1.f / denom;
  float* op = o + (size_t)(bb * NN + tid) * DD + h * DH;
#pragma unroll
  for (int c4 = 0; c4 < 8; ++c4) {
    float4 ov = {acc[c4 * 4 + 0] * inv, acc[c4 * 4 + 1] * inv,
                 acc[c4 * 4 + 2] * inv, acc[c4 * 4 + 3] * inv};
    ((float4*)op)[c4] = ov;
  }
}

// ---------------- cls MLP + BCEWithLogits, accumulate sum/1024 into loss_acc[0] ----------------
__global__ __launch_bounds__(128) void cls_loss_kernel(const float* __restrict__ x,
                                                       const float* __restrict__ W1,
                                                       const float* __restrict__ b1,
                                                       const float* __restrict__ W2,
                                                       const float* __restrict__ b2,
                                                       float* __restrict__ loss_acc) {
  __shared__ float xs[DD];
  __shared__ float red[128];
  int row = blockIdx.x;          // 0..2047
  int tid = threadIdx.x;         // 128
  xs[tid]       = x[(size_t)row * DD + tid];
  xs[tid + 128] = x[(size_t)row * DD + tid + 128];
  __syncthreads();
  float h = b1[tid];
  for (int kk = 0; kk < DD; ++kk) h += xs[kk] * W1[kk * 128 + tid];
  h = fmaxf(h, 0.f);
  red[tid] = h * W2[tid];
  __syncthreads();
  for (int s = 64; s > 0; s >>= 1) { if (tid < s) red[tid] += red[tid + s]; __syncthreads(); }
  if (tid == 0) {
    float z = red[0] + b2[0];
    float lab = ((row & 127) < 64) ? 1.f : 0.f;
    float bce = fmaxf(z, 0.f) - z * lab + log1pf(expf(-fabsf(z)));
    atomicAdd(loss_acc, bce * (1.0f / 1024.0f));
  }
}

// ---------------- instance-norm + 10 sinkhorn iters (u/v form) + focal loss (per b) ----------------
__global__ __launch_bounds__(1024) void sinkhorn_kernel(const float* __restrict__ Mm,
                                                        float* __restrict__ loss_acc) {
  __shared__ __align__(16) float u_[NN];
  __shared__ __align__(16) float v_[NN];
  __shared__ float red[20];
  int b = blockIdx.x;
  int t = threadIdx.x;
  const float* src = Mm + (size_t)b * NN * NN;
  int r  = t >> 3, cg = t & 7;    // row layout: row r, cols cg*16..+15
  int c  = t >> 3, rg = t & 7;    // col layout: col c, rows rg*16..+15
  float kr[16], kc[16];
  {
    const float4* s4 = (const float4*)(src + (size_t)r * NN + cg * 16);
#pragma unroll
    for (int q4 = 0; q4 < 4; ++q4) {
      float4 f = s4[q4];
      kr[q4 * 4 + 0] = f.x; kr[q4 * 4 + 1] = f.y; kr[q4 * 4 + 2] = f.z; kr[q4 * 4 + 3] = f.w;
    }
#pragma unroll
    for (int q = 0; q < 16; ++q)
      kc[q] = src[(size_t)(rg * 16 + q) * NN + c];
  }
  // ---- instance norm over 16384 ----
  float s = 0.f;
#pragma unroll
  for (int q = 0; q < 16; ++q) s += kr[q];
  for (int m = 1; m < 64; m <<= 1) s += __shfl_xor(s, m);
  if ((t & 63) == 0) red[t >> 6] = s;
  __syncthreads();
  if (t == 0) { float tt = 0.f; for (int i = 0; i < 16; ++i) tt += red[i]; red[16] = tt; }
  __syncthreads();
  float mu = red[16] * (1.0f / 16384.f);
  __syncthreads();
  float sq = 0.f;
#pragma unroll
  for (int q = 0; q < 16; ++q) { float d = kr[q] - mu; sq += d * d; }
  for (int m = 1; m < 64; m <<= 1) sq += __shfl_xor(sq, m);
  if ((t & 63) == 0) red[t >> 6] = sq;
  __syncthreads();
  if (t == 0) { float tt = 0.f; for (int i = 0; i < 16; ++i) tt += red[i]; red[17] = tt; }
  __syncthreads();
  float inv = 1.0f / sqrtf(red[17] * (1.0f / 16384.f) + 1e-5f);
#pragma unroll
  for (int q = 0; q < 16; ++q) { kr[q] = (kr[q] - mu) * inv; kc[q] = (kc[q] - mu) * inv; }
  if (t < NN) { u_[t] = 0.f; v_[t] = 0.f; }
  __syncthreads();
  // ---- 10 sinkhorn iterations: u_r = lse_j(K0 - v), v_c = lse_i(K0 - u) ----
  for (int iter = 0; iter < 10; ++iter) {
    float tmp[16];
    {
      const float4* vp = (const float4*)(v_ + cg * 16);
#pragma unroll
      for (int q4 = 0; q4 < 4; ++q4) {
        float4 f = vp[q4];
        tmp[q4 * 4 + 0] = kr[q4 * 4 + 0] - f.x; tmp[q4 * 4 + 1] = kr[q4 * 4 + 1] - f.y;
        tmp[q4 * 4 + 2] = kr[q4 * 4 + 2] - f.z; tmp[q4 * 4 + 3] = kr[q4 * 4 + 3] - f.w;
      }
      float mx = tmp[0];
#pragma unroll
      for (int q = 1; q < 16; ++q) mx = fmaxf(mx, tmp[q]);
      for (int m = 1; m < 8; m <<= 1) mx = fmaxf(mx, __shfl_xor(mx, m));
      float sm = 0.f;
#pragma unroll
      for (int q = 0; q < 16; ++q) sm += expf(tmp[q] - mx);
      for (int m = 1; m < 8; m <<= 1) sm += __shfl_xor(sm, m);
      if (cg == 0) u_[r] = mx + logf(sm);
    }
    __syncthreads();
    {
      const float4* up = (const float4*)(u_ + rg * 16);
#pragma unroll
      for (int q4 = 0; q4 < 4; ++q4) {
        float4 f = up[q4];
        tmp[q4 * 4 + 0] = kc[q4 * 4 + 0] - f.x; tmp[q4 * 4 + 1] = kc[q4 * 4 + 1] - f.y;
        tmp[q4 * 4 + 2] = kc[q4 * 4 + 2] - f.z; tmp[q4 * 4 + 3] = kc[q4 * 4 + 3] - f.w;
      }
      float mx = tmp[0];
#pragma unroll
      for (int q = 1; q < 16; ++q) mx = fmaxf(mx, tmp[q]);
      for (int m = 1; m < 8; m <<= 1) mx = fmaxf(mx, __shfl_xor(mx, m));
      float sm = 0.f;
#pragma unroll
      for (int q = 0; q < 16; ++q) sm += expf(tmp[q] - mx);
      for (int m = 1; m < 8; m <<= 1) sm += __shfl_xor(sm, m);
      if (rg == 0) v_[c] = mx + logf(sm);
    }
    __syncthreads();
  }
  // ---- focal loss on P = exp(K0 - u - v) ----
  float ur = u_[r];
  float fsum = 0.f;
  {
    const float4* vp = (const float4*)(v_ + cg * 16);
#pragma unroll
    for (int q4 = 0; q4 < 4; ++q4) {
      float4 f = vp[q4];
      float vv[4] = {f.x, f.y, f.z, f.w};
#pragma unroll
      for (int j = 0; j < 4; ++j) {
        float P = expf(kr[q4 * 4 + j] - ur - vv[j]);
        float pt = fminf(fmaxf(P, 1e-6f), 1.0f - 1e-6f);
        int col = cg * 16 + q4 * 4 + j;
        bool gt = (r < 64) == (col < 64);
        float w = gt ? (-0.25f * (1.f - pt) * (1.f - pt)) : (-0.75f * pt * pt);
        float l = gt ? logf(pt) : logf(1.f - pt);
        fsum += w * l;
      }
    }
  }
  for (int m = 1; m < 64; m <<= 1) fsum += __shfl_xor(fsum, m);
  if ((t & 63) == 0) red[t >> 6] = fsum;
  __syncthreads();
  if (t == 0) {
    float tt = 0.f; for (int i = 0; i < 16; ++i) tt += red[i];
    atomicAdd(loss_acc + 1, tt * (1.0f / 131072.f));
  }
}

// ---------------- copy n1 + total loss ----------------
__global__ __launch_bounds__(256) void finalize_kernel(const float* __restrict__ c1,
                                                       const float* __restrict__ loss_acc,
                                                       float* __restrict__ out) {
  int g = blockIdx.x * 256 + threadIdx.x;
  if (g < ROWS1 * DD) out[g] = c1[g];
  if (g == 0) out[ROWS1 * DD] = loss_acc[0] + 10.0f * loss_acc[1];
}

extern "C" void kernel_launch(void* const* d_in, const int* in_sizes, int n_in,
                              void* d_out, int out_size, void* d_ws, size_t ws_size,
                              hipStream_t stream) {
  const float* feat_s  = (const float*)d_in[0];
  const float* score_s = (const float*)d_in[1];
  const float* feat_t  = (const float*)d_in[2];
  const float* score_t = (const float*)d_in[3];
  const float* head_W1 = (const float*)d_in[4];
  const float* head_b1 = (const float*)d_in[5];
  const float* head_W2 = (const float*)d_in[6];
  const float* head_b2 = (const float*)d_in[7];
  const float* intra_W = (const float*)d_in[8];
  const float* intra_b = (const float*)d_in[9];
  const float* cross_W = (const float*)d_in[10];
  const float* cross_b = (const float*)d_in[11];
  const float* cls_W1  = (const float*)d_in[12];
  const float* cls_b1  = (const float*)d_in[13];
  const float* cls_W2  = (const float*)d_in[14];
  const float* cls_b2  = (const float*)d_in[15];
  const float* aff_A   = (const float*)d_in[16];

  float* ws = (float*)d_ws;
  float* nodes = ws;                         // 2048*512
  float* bufA  = nodes + 2048 * 512;         // 2048*256
  float* bufH  = bufA + ROWS2 * DD;          // 2048*256 (H, then G, then C)
  float* bufQ  = bufH + ROWS2 * DD;          // 3 x 2048*256 contiguous (Q,K,V)
  float* bufK  = bufQ + ROWS2 * DD;
  float* bufV  = bufK + ROWS2 * DD;
  float* acc   = bufV + ROWS2 * DD;          // 2 floats (pad 8)
  int*   idxb  = (int*)(acc + 8);            // 16*128 ints
  float* Mm    = (float*)(idxb + 2048);      // 8*128*128

  topk_kernel<<<16, 256, 0, stream>>>(score_s, score_t, idxb, acc);
  gather_kernel<<<16 * NN, 256, 0, stream>>>(feat_s, feat_t, idxb, nodes);

  dim3 g1(4, 32, 1);      // N/64, M/64 for M=2048
  dim3 g3(4, 32, 3);      // z-batched QKV
  const int WS = DD * DD, BS = DD, CS = ROWS2 * DD;

  // head: Linear->LN->ReLU->Linear->LN
  gemm_bias<<<g1, 256, 0, stream>>>(nodes, head_W1, head_b1, bufA, ROWS2, DD, CENC, 0, 0, 0, 0);
  ln_kernel<<<ROWS2 / 4, 256, 0, stream>>>(bufA, bufH, 1);
  gemm_bias<<<g1, 256, 0, stream>>>(bufH, head_W2, head_b2, bufA, ROWS2, DD, DD, 0, 0, 0, 0);
  ln_kernel<<<ROWS2 / 4, 256, 0, stream>>>(bufA, bufH, 0);          // bufH = H

  // intra self-attention (shared weights, both domains batched; QKV z-batched)
  gemm_bias<<<g3, 256, 0, stream>>>(bufH, intra_W, intra_b, bufQ, ROWS2, DD, DD, 0, WS, BS, CS);
  attn_kernel<<<16 * NHEAD, 128, 0, stream>>>(bufQ, bufK, bufV, bufA, 0);
  gemm_bias<<<g1, 256, 0, stream>>>(bufA, intra_W + 3 * WS, intra_b + 3 * BS, bufH, ROWS2, DD, DD, 0, 0, 0, 0); // G

  // cross attention (swap kv halves)
  gemm_bias<<<g3, 256, 0, stream>>>(bufH, cross_W, cross_b, bufQ, ROWS2, DD, DD, 0, WS, BS, CS);
  attn_kernel<<<16 * NHEAD, 128, 0, stream>>>(bufQ, bufK, bufV, bufA, 1);
  gemm_bias<<<g1, 256, 0, stream>>>(bufA, cross_W + 3 * WS, cross_b + 3 * BS, bufH, ROWS2, DD, DD, 0, 0, 0, 0); // C

  // node classification loss (both domains)
  cls_loss_kernel<<<ROWS2, 128, 0, stream>>>(bufH, cls_W1, cls_b1, cls_W2, cls_b2, acc);

  // affinity: tmp = c1 @ aff_A ; Mmat = tmp @ c2^T
  dim3 g2(4, 16, 1);
  gemm_bias<<<g2, 256, 0, stream>>>(bufH, aff_A, (const float*)nullptr, bufA, ROWS1, DD, DD, 0, 0, 0, 0);
  dim3 gnt(2, 2, BIMG);
  gemm_nt<<<gnt, 256, 0, stream>>>(bufA, bufH + (size_t)ROWS1 * DD, Mm);

  // instance-norm + sinkhorn + focal loss
  sinkhorn_kernel<<<BIMG, 1024, 0, stream>>>(Mm, acc);

  // output: n1 (=c1) then total loss
  finalize_kernel<<<ROWS1 * DD / 256, 256, 0, stream>>>(bufH, acc, (float*)d_out);
}

// Round 3
// 431.042 us; speedup vs baseline: 2.4368x; 1.3541x over previous
//
#include <hip/hip_runtime.h>
#include <math.h>

#define BIMG 8
#define HW 9216
#define CENC 512
#define NS 64
#define NN 128      // nodes per image
#define DD 256
#define NHEAD 8
#define DH 32
#define ROWS1 1024   // BIMG*NN
#define ROWS2 2048   // 2*BIMG*NN

typedef unsigned long long ull;

// keep k if (k>o)==keepMax else take o
__device__ __forceinline__ ull cmpex_keep(ull k, ull o, bool keepMax) {
  return ((k > o) == keepMax) ? k : o;
}

// full bitonic sort of 64 keys across a wave, descending
__device__ __forceinline__ void bsort64(ull& k, int lane) {
#pragma unroll
  for (int size = 2; size <= 64; size <<= 1) {
#pragma unroll
    for (int stride = size >> 1; stride > 0; stride >>= 1) {
      ull o = __shfl_xor(k, stride);
      bool keepMax = (((lane & size) == 0) == ((lane & stride) == 0));
      k = cmpex_keep(k, o, keepMax);
    }
  }
}

// merge sorted-desc top with sorted-desc b -> top = top-64 of union, sorted desc
__device__ __forceinline__ void bmerge64(ull& top, ull b, int lane) {
  ull rev = __shfl_xor(b, 63);
  ull m = top > rev ? top : rev;
#pragma unroll
  for (int stride = 32; stride > 0; stride >>= 1) {
    ull o = __shfl_xor(m, stride);
    m = cmpex_keep(m, o, (lane & stride) == 0);
  }
  top = m;
}

// ---------------- top-64 (pos desc / neg asc) via wave-bitonic streaming ----------------
// grid 32: blockIdx = bi*2 + neg ; 256 threads = 4 waves, each wave owns 2304 elements
__global__ __launch_bounds__(256) void topk_kernel(const float* __restrict__ score_s,
                                                   const float* __restrict__ score_t,
                                                   int* __restrict__ idx_out,
                                                   float* __restrict__ loss_acc) {
  __shared__ ull sm[256];
  int blk = blockIdx.x;
  int bi = blk >> 1, neg = blk & 1;
  int tid = threadIdx.x, lane = tid & 63, w = tid >> 6;
  if (blk == 0 && tid < 2) loss_acc[tid] = 0.f;
  const float* sp = (bi < 8 ? score_s : score_t) + (size_t)(bi & 7) * HW;
  int q0 = w * 36;
  float vals[36];
#pragma unroll
  for (int j = 0; j < 36; ++j) vals[j] = sp[(q0 + j) * 64 + lane];

  ull keys[36];
#pragma unroll
  for (int j = 0; j < 36; ++j) {
    unsigned ub = __float_as_uint(vals[j]);
    unsigned u = (ub & 0x80000000u) ? ~ub : (ub | 0x80000000u);  // monotone ascending
    if (neg) u = ~u;                                             // flip for argmin
    int gi = (q0 + j) * 64 + lane;
    keys[j] = ((ull)u << 32) | (unsigned)(~gi);                  // tie -> lower index
  }

  // two independent streams per wave (ILP to overlap shfl chains)
  ull top1 = keys[0];  bsort64(top1, lane);
  ull top2 = keys[18]; bsort64(top2, lane);
#pragma unroll
  for (int j = 1; j < 18; ++j) {
    ull k1 = keys[j], k2 = keys[18 + j];
    bsort64(k1, lane);
    bsort64(k2, lane);
    bmerge64(top1, k1, lane);
    bmerge64(top2, k2, lane);
  }
  bmerge64(top1, top2, lane);
  sm[w * 64 + lane] = top1;
  __syncthreads();
  if (w < 2) {                       // pairwise merge: (0,1) -> slot0 ; (2,3) -> slot128
    ull a = sm[(2 * w) * 64 + lane];
    ull b = sm[(2 * w + 1) * 64 + (63 - lane)];
    ull m = a > b ? a : b;
#pragma unroll
    for (int stride = 32; stride > 0; stride >>= 1) {
      ull o = __shfl_xor(m, stride);
      m = cmpex_keep(m, o, (lane & stride) == 0);
    }
    sm[(2 * w) * 64 + lane] = m;
  }
  __syncthreads();
  if (w == 0) {
    ull a = sm[lane];
    ull b = sm[128 + (63 - lane)];
    ull m = a > b ? a : b;
#pragma unroll
    for (int stride = 32; stride > 0; stride >>= 1) {
      ull o = __shfl_xor(m, stride);
      m = cmpex_keep(m, o, (lane & stride) == 0);
    }
    idx_out[bi * NN + neg * 64 + lane] = (int)(~(unsigned)(m & 0xffffffffull));
  }
}

// ---------------- gather nodes[row][c] = feat[b][c][pos] ----------------
__global__ __launch_bounds__(256) void gather_kernel(const float* __restrict__ feat_s,
                                                     const float* __restrict__ feat_t,
                                                     const int* __restrict__ idx,
                                                     float* __restrict__ nodes) {
  int blk = blockIdx.x;           // bi*NN + n, bi in [0,16)
  int bi = blk / NN, n = blk % NN;
  int b = bi & 7;
  const float* fp = (bi < 8) ? feat_s : feat_t;
  int pos = idx[bi * NN + n];
  const float* src = fp + (size_t)b * CENC * HW + pos;
  float* dst = nodes + (size_t)blk * CENC;
  for (int c = threadIdx.x; c < CENC; c += 256)
    dst[c] = src[(size_t)c * HW];
}

// ---------------- fp32 GEMM: C = A[M,K] @ W[K,N] + bias, opt relu, z-batched weights ----------------
__global__ __launch_bounds__(256) void gemm_bias(const float* __restrict__ A,
                                                 const float* __restrict__ W,
                                                 const float* __restrict__ bias,
                                                 float* __restrict__ C,
                                                 int M, int N, int K, int relu,
                                                 int Wstride, int bstride, int Cstride) {
  __shared__ float As[16][68];   // [k][m], padded, float4-aligned rows
  __shared__ float Bs[16][64];   // [k][n]
  int z = blockIdx.z;
  W += (size_t)z * Wstride;
  if (bias) bias += (size_t)z * bstride;
  C += (size_t)z * Cstride;
  int n0 = blockIdx.x * 64;
  int m0 = blockIdx.y * 64;
  int tid = threadIdx.x;
  int tx = tid & 15, ty = tid >> 4;
  int ar = tid >> 2, ac4 = tid & 3;     // A-tile: 64 rows x 4 float4-chunks
  int bk = tid >> 4, bn4 = tid & 15;    // B-tile: 16 k-rows x 16 float4-chunks
  float acc[4][4] = {{0.f}};
  for (int k0 = 0; k0 < K; k0 += 16) {
    float4 a4 = *(const float4*)&A[(size_t)(m0 + ar) * K + k0 + ac4 * 4];
    float4 b4 = *(const float4*)&W[(size_t)(k0 + bk) * N + n0 + bn4 * 4];
    As[ac4 * 4 + 0][ar] = a4.x;
    As[ac4 * 4 + 1][ar] = a4.y;
    As[ac4 * 4 + 2][ar] = a4.z;
    As[ac4 * 4 + 3][ar] = a4.w;
    *(float4*)&Bs[bk][bn4 * 4] = b4;
    __syncthreads();
#pragma unroll
    for (int kk = 0; kk < 16; ++kk) {
      float4 av = *(const float4*)&As[kk][ty * 4];
      float4 bv = *(const float4*)&Bs[kk][tx * 4];
      float a[4] = {av.x, av.y, av.z, av.w};
      float b[4] = {bv.x, bv.y, bv.z, bv.w};
#pragma unroll
      for (int i = 0; i < 4; ++i)
#pragma unroll
        for (int j = 0; j < 4; ++j)
          acc[i][j] += a[i] * b[j];
    }
    __syncthreads();
  }
  float4 bb = {0.f, 0.f, 0.f, 0.f};
  if (bias) bb = *(const float4*)&bias[n0 + tx * 4];
#pragma unroll
  for (int i = 0; i < 4; ++i) {
    int m = m0 + ty * 4 + i;
    float4 o;
    o.x = acc[i][0] + bb.x; o.y = acc[i][1] + bb.y;
    o.z = acc[i][2] + bb.z; o.w = acc[i][3] + bb.w;
    if (relu) {
      o.x = fmaxf(o.x, 0.f); o.y = fmaxf(o.y, 0.f);
      o.z = fmaxf(o.z, 0.f); o.w = fmaxf(o.w, 0.f);
    }
    *(float4*)&C[(size_t)m * N + n0 + tx * 4] = o;
  }
}

// ---------------- NT GEMM per image: Mm[b] = A[b](128x256) @ Bt[b](128x256)^T ----------------
__global__ __launch_bounds__(256) void gemm_nt(const float* __restrict__ A,
                                               const float* __restrict__ Bt,
                                               float* __restrict__ C) {
  __shared__ float As[16][68];
  __shared__ float Bs[16][68];
  int b = blockIdx.z;
  int m0 = blockIdx.y * 64, n0 = blockIdx.x * 64;
  const float* Ab = A + (size_t)b * NN * DD;
  const float* Bb = Bt + (size_t)b * NN * DD;
  int tid = threadIdx.x;
  int tx = tid & 15, ty = tid >> 4;
  int ar = tid >> 2, ac4 = tid & 3;
  float acc[4][4] = {{0.f}};
  for (int k0 = 0; k0 < DD; k0 += 16) {
    float4 a4 = *(const float4*)&Ab[(size_t)(m0 + ar) * DD + k0 + ac4 * 4];
    float4 b4 = *(const float4*)&Bb[(size_t)(n0 + ar) * DD + k0 + ac4 * 4];
    As[ac4 * 4 + 0][ar] = a4.x; As[ac4 * 4 + 1][ar] = a4.y;
    As[ac4 * 4 + 2][ar] = a4.z; As[ac4 * 4 + 3][ar] = a4.w;
    Bs[ac4 * 4 + 0][ar] = b4.x; Bs[ac4 * 4 + 1][ar] = b4.y;
    Bs[ac4 * 4 + 2][ar] = b4.z; Bs[ac4 * 4 + 3][ar] = b4.w;
    __syncthreads();
#pragma unroll
    for (int kk = 0; kk < 16; ++kk) {
      float4 av = *(const float4*)&As[kk][ty * 4];
      float4 bv = *(const float4*)&Bs[kk][tx * 4];
      float a[4] = {av.x, av.y, av.z, av.w};
      float bx[4] = {bv.x, bv.y, bv.z, bv.w};
#pragma unroll
      for (int i = 0; i < 4; ++i)
#pragma unroll
        for (int j = 0; j < 4; ++j)
          acc[i][j] += a[i] * bx[j];
    }
    __syncthreads();
  }
#pragma unroll
  for (int i = 0; i < 4; ++i) {
    float4 o = {acc[i][0], acc[i][1], acc[i][2], acc[i][3]};
    *(float4*)&C[(size_t)b * NN * NN + (size_t)(m0 + ty * 4 + i) * NN + n0 + tx * 4] = o;
  }
}

// ---------------- LayerNorm (no affine) over D=256, one row per wave ----------------
__global__ __launch_bounds__(256) void ln_kernel(const float* __restrict__ x,
                                                 float* __restrict__ y, int relu_after) {
  int wid = threadIdx.x >> 6, lane = threadIdx.x & 63;
  int row = blockIdx.x * 4 + wid;
  float4 v = ((const float4*)(x + (size_t)row * DD))[lane];
  float s = v.x + v.y + v.z + v.w;
  for (int m = 1; m < 64; m <<= 1) s += __shfl_xor(s, m);
  float mean = s * (1.0f / DD);
  float d0 = v.x - mean, d1 = v.y - mean, d2 = v.z - mean, d3 = v.w - mean;
  float ss = d0 * d0 + d1 * d1 + d2 * d2 + d3 * d3;
  for (int m = 1; m < 64; m <<= 1) ss += __shfl_xor(ss, m);
  float inv = 1.0f / sqrtf(ss * (1.0f / DD) + 1e-5f);
  float4 o = {d0 * inv, d1 * inv, d2 * inv, d3 * inv};
  if (relu_after) {
    o.x = fmaxf(o.x, 0.f); o.y = fmaxf(o.y, 0.f);
    o.z = fmaxf(o.z, 0.f); o.w = fmaxf(o.w, 0.f);
  }
  ((float4*)(y + (size_t)row * DD))[lane] = o;
}

// ---------------- fused attention per (bb, head): softmax(QK^T/sqrt(32)) V ----------------
__global__ __launch_bounds__(128) void attn_kernel(const float* __restrict__ q,
                                                   const float* __restrict__ k,
                                                   const float* __restrict__ v,
                                                   float* __restrict__ o, int swap) {
  __shared__ __align__(16) float Ks[NN][DH];
  __shared__ __align__(16) float Vs[NN][DH];
  int blk = blockIdx.x;          // bb*8 + h, bb in [0,16)
  int bb = blk >> 3, h = blk & 7;
  int kb = swap ? (bb ^ 8) : bb;
  int tid = threadIdx.x;         // 128: one q-row per thread
  for (int e4 = tid; e4 < NN * DH / 4; e4 += 128) {
    int r = e4 >> 3, c4 = e4 & 7;
    ((float4*)Ks[r])[c4] = *(const float4*)&k[(size_t)(kb * NN + r) * DD + h * DH + c4 * 4];
    ((float4*)Vs[r])[c4] = *(const float4*)&v[(size_t)(kb * NN + r) * DD + h * DH + c4 * 4];
  }
  __syncthreads();
  float4 q4[8];
  const float* qp = q + (size_t)(bb * NN + tid) * DD + h * DH;
#pragma unroll
  for (int c4 = 0; c4 < 8; ++c4) q4[c4] = ((const float4*)qp)[c4];
  const float scale = 0.17677669529663687f;   // 1/sqrt(32)
  float mx = -1e30f;
  for (int j = 0; j < NN; ++j) {
    const float4* kp = (const float4*)Ks[j];
    float s = 0.f;
#pragma unroll
    for (int c4 = 0; c4 < 8; ++c4) {
      float4 kv = kp[c4];
      s += q4[c4].x * kv.x + q4[c4].y * kv.y + q4[c4].z * kv.z + q4[c4].w * kv.w;
    }
    mx = fmaxf(mx, s * scale);
  }
  float acc[DH];
#pragma unroll
  for (int c = 0; c < DH; ++c) acc[c] = 0.f;
  float denom = 0.f;
  for (int j = 0; j < NN; ++j) {
    const float4* kp = (const float4*)Ks[j];
    float s = 0.f;
#pragma unroll
    for (int c4 = 0; c4 < 8; ++c4) {
      float4 kv = kp[c4];
      s += q4[c4].x * kv.x + q4[c4].y * kv.y + q4[c4].z * kv.z + q4[c4].w * kv.w;
    }
    float e = expf(s * scale - mx);
    denom += e;
    const float4* vp = (const float4*)Vs[j];
#pragma unroll
    for (int c4 = 0; c4 < 8; ++c4) {
      float4 vv = vp[c4];
      acc[c4 * 4 + 0] += e * vv.x; acc[c4 * 4 + 1] += e * vv.y;
      acc[c4 * 4 + 2] += e * vv.z; acc[c4 * 4 + 3] += e * vv.w;
    }
  }
  float inv = 1.f / denom;
  float* op = o + (size_t)(bb * NN + tid) * DD + h * DH;
#pragma unroll
  for (int c4 = 0; c4 < 8; ++c4) {
    float4 ov = {acc[c4 * 4 + 0] * inv, acc[c4 * 4 + 1] * inv,
                 acc[c4 * 4 + 2] * inv, acc[c4 * 4 + 3] * inv};
    ((float4*)op)[c4] = ov;
  }
}

// ---------------- cls MLP + BCEWithLogits, accumulate sum/1024 into loss_acc[0] ----------------
__global__ __launch_bounds__(128) void cls_loss_kernel(const float* __restrict__ x,
                                                       const float* __restrict__ W1,
                                                       const float* __restrict__ b1,
                                                       const float* __restrict__ W2,
                                                       const float* __restrict__ b2,
                                                       float* __restrict__ loss_acc) {
  __shared__ float xs[DD];
  __shared__ float red[128];
  int row = blockIdx.x;          // 0..2047
  int tid = threadIdx.x;         // 128
  xs[tid]       = x[(size_t)row * DD + tid];
  xs[tid + 128] = x[(size_t)row * DD + tid + 128];
  __syncthreads();
  float h = b1[tid];
  for (int kk = 0; kk < DD; ++kk) h += xs[kk] * W1[kk * 128 + tid];
  h = fmaxf(h, 0.f);
  red[tid] = h * W2[tid];
  __syncthreads();
  for (int s = 64; s > 0; s >>= 1) { if (tid < s) red[tid] += red[tid + s]; __syncthreads(); }
  if (tid == 0) {
    float z = red[0] + b2[0];
    float lab = ((row & 127) < 64) ? 1.f : 0.f;
    float bce = fmaxf(z, 0.f) - z * lab + log1pf(expf(-fabsf(z)));
    atomicAdd(loss_acc, bce * (1.0f / 1024.0f));
  }
}

// ---------------- instance-norm + 10 sinkhorn iters (u/v form) + focal loss (per b) ----------------
__global__ __launch_bounds__(1024) void sinkhorn_kernel(const float* __restrict__ Mm,
                                                        float* __restrict__ loss_acc) {
  __shared__ __align__(16) float u_[NN];
  __shared__ __align__(16) float v_[NN];
  __shared__ float red[20];
  int b = blockIdx.x;
  int t = threadIdx.x;
  const float* src = Mm + (size_t)b * NN * NN;
  int r  = t >> 3, cg = t & 7;    // row layout: row r, cols cg*16..+15
  int c  = t >> 3, rg = t & 7;    // col layout: col c, rows rg*16..+15
  float kr[16], kc[16];
  {
    const float4* s4 = (const float4*)(src + (size_t)r * NN + cg * 16);
#pragma unroll
    for (int q4 = 0; q4 < 4; ++q4) {
      float4 f = s4[q4];
      kr[q4 * 4 + 0] = f.x; kr[q4 * 4 + 1] = f.y; kr[q4 * 4 + 2] = f.z; kr[q4 * 4 + 3] = f.w;
    }
#pragma unroll
    for (int q = 0; q < 16; ++q)
      kc[q] = src[(size_t)(rg * 16 + q) * NN + c];
  }
  // ---- instance norm over 16384 ----
  float s = 0.f;
#pragma unroll
  for (int q = 0; q < 16; ++q) s += kr[q];
  for (int m = 1; m < 64; m <<= 1) s += __shfl_xor(s, m);
  if ((t & 63) == 0) red[t >> 6] = s;
  __syncthreads();
  if (t == 0) { float tt = 0.f; for (int i = 0; i < 16; ++i) tt += red[i]; red[16] = tt; }
  __syncthreads();
  float mu = red[16] * (1.0f / 16384.f);
  __syncthreads();
  float sq = 0.f;
#pragma unroll
  for (int q = 0; q < 16; ++q) { float d = kr[q] - mu; sq += d * d; }
  for (int m = 1; m < 64; m <<= 1) sq += __shfl_xor(sq, m);
  if ((t & 63) == 0) red[t >> 6] = sq;
  __syncthreads();
  if (t == 0) { float tt = 0.f; for (int i = 0; i < 16; ++i) tt += red[i]; red[17] = tt; }
  __syncthreads();
  float inv = 1.0f / sqrtf(red[17] * (1.0f / 16384.f) + 1e-5f);
#pragma unroll
  for (int q = 0; q < 16; ++q) { kr[q] = (kr[q] - mu) * inv; kc[q] = (kc[q] - mu) * inv; }
  if (t < NN) { u_[t] = 0.f; v_[t] = 0.f; }
  __syncthreads();
  // ---- 10 sinkhorn iterations: u_r = lse_j(K0 - v), v_c = lse_i(K0 - u) ----
  for (int iter = 0; iter < 10; ++iter) {
    float tmp[16];
    {
      const float4* vp = (const float4*)(v_ + cg * 16);
#pragma unroll
      for (int q4 = 0; q4 < 4; ++q4) {
        float4 f = vp[q4];
        tmp[q4 * 4 + 0] = kr[q4 * 4 + 0] - f.x; tmp[q4 * 4 + 1] = kr[q4 * 4 + 1] - f.y;
        tmp[q4 * 4 + 2] = kr[q4 * 4 + 2] - f.z; tmp[q4 * 4 + 3] = kr[q4 * 4 + 3] - f.w;
      }
      float mx = tmp[0];
#pragma unroll
      for (int q = 1; q < 16; ++q) mx = fmaxf(mx, tmp[q]);
      for (int m = 1; m < 8; m <<= 1) mx = fmaxf(mx, __shfl_xor(mx, m));
      float sm = 0.f;
#pragma unroll
      for (int q = 0; q < 16; ++q) sm += expf(tmp[q] - mx);
      for (int m = 1; m < 8; m <<= 1) sm += __shfl_xor(sm, m);
      if (cg == 0) u_[r] = mx + logf(sm);
    }
    __syncthreads();
    {
      const float4* up = (const float4*)(u_ + rg * 16);
#pragma unroll
      for (int q4 = 0; q4 < 4; ++q4) {
        float4 f = up[q4];
        tmp[q4 * 4 + 0] = kc[q4 * 4 + 0] - f.x; tmp[q4 * 4 + 1] = kc[q4 * 4 + 1] - f.y;
        tmp[q4 * 4 + 2] = kc[q4 * 4 + 2] - f.z; tmp[q4 * 4 + 3] = kc[q4 * 4 + 3] - f.w;
      }
      float mx = tmp[0];
#pragma unroll
      for (int q = 1; q < 16; ++q) mx = fmaxf(mx, tmp[q]);
      for (int m = 1; m < 8; m <<= 1) mx = fmaxf(mx, __shfl_xor(mx, m));
      float sm = 0.f;
#pragma unroll
      for (int q = 0; q < 16; ++q) sm += expf(tmp[q] - mx);
      for (int m = 1; m < 8; m <<= 1) sm += __shfl_xor(sm, m);
      if (rg == 0) v_[c] = mx + logf(sm);
    }
    __syncthreads();
  }
  // ---- focal loss on P = exp(K0 - u - v) ----
  float ur = u_[r];
  float fsum = 0.f;
  {
    const float4* vp = (const float4*)(v_ + cg * 16);
#pragma unroll
    for (int q4 = 0; q4 < 4; ++q4) {
      float4 f = vp[q4];
      float vv[4] = {f.x, f.y, f.z, f.w};
#pragma unroll
      for (int j = 0; j < 4; ++j) {
        float P = expf(kr[q4 * 4 + j] - ur - vv[j]);
        float pt = fminf(fmaxf(P, 1e-6f), 1.0f - 1e-6f);
        int col = cg * 16 + q4 * 4 + j;
        bool gt = (r < 64) == (col < 64);
        float w = gt ? (-0.25f * (1.f - pt) * (1.f - pt)) : (-0.75f * pt * pt);
        float l = gt ? logf(pt) : logf(1.f - pt);
        fsum += w * l;
      }
    }
  }
  for (int m = 1; m < 64; m <<= 1) fsum += __shfl_xor(fsum, m);
  if ((t & 63) == 0) red[t >> 6] = fsum;
  __syncthreads();
  if (t == 0) {
    float tt = 0.f; for (int i = 0; i < 16; ++i) tt += red[i];
    atomicAdd(loss_acc + 1, tt * (1.0f / 131072.f));
  }
}

// ---------------- copy n1 + total loss ----------------
__global__ __launch_bounds__(256) void finalize_kernel(const float* __restrict__ c1,
                                                       const float* __restrict__ loss_acc,
                                                       float* __restrict__ out) {
  int g = blockIdx.x * 256 + threadIdx.x;
  if (g < ROWS1 * DD) out[g] = c1[g];
  if (g == 0) out[ROWS1 * DD] = loss_acc[0] + 10.0f * loss_acc[1];
}

extern "C" void kernel_launch(void* const* d_in, const int* in_sizes, int n_in,
                              void* d_out, int out_size, void* d_ws, size_t ws_size,
                              hipStream_t stream) {
  const float* feat_s  = (const float*)d_in[0];
  const float* score_s = (const float*)d_in[1];
  const float* feat_t  = (const float*)d_in[2];
  const float* score_t = (const float*)d_in[3];
  const float* head_W1 = (const float*)d_in[4];
  const float* head_b1 = (const float*)d_in[5];
  const float* head_W2 = (const float*)d_in[6];
  const float* head_b2 = (const float*)d_in[7];
  const float* intra_W = (const float*)d_in[8];
  const float* intra_b = (const float*)d_in[9];
  const float* cross_W = (const float*)d_in[10];
  const float* cross_b = (const float*)d_in[11];
  const float* cls_W1  = (const float*)d_in[12];
  const float* cls_b1  = (const float*)d_in[13];
  const float* cls_W2  = (const float*)d_in[14];
  const float* cls_b2  = (const float*)d_in[15];
  const float* aff_A   = (const float*)d_in[16];

  float* ws = (float*)d_ws;
  float* nodes = ws;                         // 2048*512
  float* bufA  = nodes + 2048 * 512;         // 2048*256
  float* bufH  = bufA + ROWS2 * DD;          // 2048*256 (H, then G, then C)
  float* bufQ  = bufH + ROWS2 * DD;          // 3 x 2048*256 contiguous (Q,K,V)
  float* bufK  = bufQ + ROWS2 * DD;
  float* bufV  = bufK + ROWS2 * DD;
  float* acc   = bufV + ROWS2 * DD;          // 2 floats (pad 8)
  int*   idxb  = (int*)(acc + 8);            // 16*128 ints
  float* Mm    = (float*)(idxb + 2048);      // 8*128*128

  topk_kernel<<<32, 256, 0, stream>>>(score_s, score_t, idxb, acc);
  gather_kernel<<<16 * NN, 256, 0, stream>>>(feat_s, feat_t, idxb, nodes);

  dim3 g1(4, 32, 1);      // N/64, M/64 for M=2048
  dim3 g3(4, 32, 3);      // z-batched QKV
  const int WS = DD * DD, BS = DD, CS = ROWS2 * DD;

  // head: Linear->LN->ReLU->Linear->LN
  gemm_bias<<<g1, 256, 0, stream>>>(nodes, head_W1, head_b1, bufA, ROWS2, DD, CENC, 0, 0, 0, 0);
  ln_kernel<<<ROWS2 / 4, 256, 0, stream>>>(bufA, bufH, 1);
  gemm_bias<<<g1, 256, 0, stream>>>(bufH, head_W2, head_b2, bufA, ROWS2, DD, DD, 0, 0, 0, 0);
  ln_kernel<<<ROWS2 / 4, 256, 0, stream>>>(bufA, bufH, 0);          // bufH = H

  // intra self-attention (shared weights, both domains batched; QKV z-batched)
  gemm_bias<<<g3, 256, 0, stream>>>(bufH, intra_W, intra_b, bufQ, ROWS2, DD, DD, 0, WS, BS, CS);
  attn_kernel<<<16 * NHEAD, 128, 0, stream>>>(bufQ, bufK, bufV, bufA, 0);
  gemm_bias<<<g1, 256, 0, stream>>>(bufA, intra_W + 3 * WS, intra_b + 3 * BS, bufH, ROWS2, DD, DD, 0, 0, 0, 0); // G

  // cross attention (swap kv halves)
  gemm_bias<<<g3, 256, 0, stream>>>(bufH, cross_W, cross_b, bufQ, ROWS2, DD, DD, 0, WS, BS, CS);
  attn_kernel<<<16 * NHEAD, 128, 0, stream>>>(bufQ, bufK, bufV, bufA, 1);
  gemm_bias<<<g1, 256, 0, stream>>>(bufA, cross_W + 3 * WS, cross_b + 3 * BS, bufH, ROWS2, DD, DD, 0, 0, 0, 0); // C

  // node classification loss (both domains)
  cls_loss_kernel<<<ROWS2, 128, 0, stream>>>(bufH, cls_W1, cls_b1, cls_W2, cls_b2, acc);

  // affinity: tmp = c1 @ aff_A ; Mmat = tmp @ c2^T
  dim3 g2(4, 16, 1);
  gemm_bias<<<g2, 256, 0, stream>>>(bufH, aff_A, (const float*)nullptr, bufA, ROWS1, DD, DD, 0, 0, 0, 0);
  dim3 gnt(2, 2, BIMG);
  gemm_nt<<<gnt, 256, 0, stream>>>(bufA, bufH + (size_t)ROWS1 * DD, Mm);

  // instance-norm + sinkhorn + focal loss
  sinkhorn_kernel<<<BIMG, 1024, 0, stream>>>(Mm, acc);

  // output: n1 (=c1) then total loss
  finalize_kernel<<<ROWS1 * DD / 256, 256, 0, stream>>>(bufH, acc, (float*)d_out);
}

// Round 4
// 362.158 us; speedup vs baseline: 2.9003x; 1.1902x over previous
//
#include <hip/hip_runtime.h>
#include <math.h>

#define BIMG 8
#define HW 9216
#define CENC 512
#define NS 64
#define NN 128      // nodes per image
#define DD 256
#define NHEAD 8
#define DH 32
#define ROWS1 1024   // BIMG*NN
#define ROWS2 2048   // 2*BIMG*NN

typedef unsigned long long ull;

__device__ __forceinline__ ull cmpex_keep(ull k, ull o, bool keepMax) {
  return ((k > o) == keepMax) ? k : o;
}

__device__ __forceinline__ void bsort64(ull& k, int lane) {
#pragma unroll
  for (int size = 2; size <= 64; size <<= 1) {
#pragma unroll
    for (int stride = size >> 1; stride > 0; stride >>= 1) {
      ull o = __shfl_xor(k, stride);
      bool keepMax = (((lane & size) == 0) == ((lane & stride) == 0));
      k = cmpex_keep(k, o, keepMax);
    }
  }
}

__device__ __forceinline__ void bmerge64(ull& top, ull b, int lane) {
  ull rev = __shfl_xor(b, 63);
  ull m = top > rev ? top : rev;
#pragma unroll
  for (int stride = 32; stride > 0; stride >>= 1) {
    ull o = __shfl_xor(m, stride);
    m = cmpex_keep(m, o, (lane & stride) == 0);
  }
  top = m;
}

// ---------------- top-64 (pos desc / neg asc) via wave-bitonic streaming ----------------
__global__ __launch_bounds__(256) void topk_kernel(const float* __restrict__ score_s,
                                                   const float* __restrict__ score_t,
                                                   int* __restrict__ idx_out,
                                                   float* __restrict__ loss_acc) {
  __shared__ ull sm[256];
  int blk = blockIdx.x;
  int bi = blk >> 1, neg = blk & 1;
  int tid = threadIdx.x, lane = tid & 63, w = tid >> 6;
  if (blk == 0 && tid < 2) loss_acc[tid] = 0.f;
  const float* sp = (bi < 8 ? score_s : score_t) + (size_t)(bi & 7) * HW;
  int q0 = w * 36;
  float vals[36];
#pragma unroll
  for (int j = 0; j < 36; ++j) vals[j] = sp[(q0 + j) * 64 + lane];

  ull keys[36];
#pragma unroll
  for (int j = 0; j < 36; ++j) {
    unsigned ub = __float_as_uint(vals[j]);
    unsigned u = (ub & 0x80000000u) ? ~ub : (ub | 0x80000000u);
    if (neg) u = ~u;
    int gi = (q0 + j) * 64 + lane;
    keys[j] = ((ull)u << 32) | (unsigned)(~gi);
  }

  ull top1 = keys[0];  bsort64(top1, lane);
  ull top2 = keys[18]; bsort64(top2, lane);
#pragma unroll
  for (int j = 1; j < 18; ++j) {
    ull k1 = keys[j], k2 = keys[18 + j];
    bsort64(k1, lane);
    bsort64(k2, lane);
    bmerge64(top1, k1, lane);
    bmerge64(top2, k2, lane);
  }
  bmerge64(top1, top2, lane);
  sm[w * 64 + lane] = top1;
  __syncthreads();
  if (w < 2) {
    ull a = sm[(2 * w) * 64 + lane];
    ull b = sm[(2 * w + 1) * 64 + (63 - lane)];
    ull m = a > b ? a : b;
#pragma unroll
    for (int stride = 32; stride > 0; stride >>= 1) {
      ull o = __shfl_xor(m, stride);
      m = cmpex_keep(m, o, (lane & stride) == 0);
    }
    sm[(2 * w) * 64 + lane] = m;
  }
  __syncthreads();
  if (w == 0) {
    ull a = sm[lane];
    ull b = sm[128 + (63 - lane)];
    ull m = a > b ? a : b;
#pragma unroll
    for (int stride = 32; stride > 0; stride >>= 1) {
      ull o = __shfl_xor(m, stride);
      m = cmpex_keep(m, o, (lane & stride) == 0);
    }
    idx_out[bi * NN + neg * 64 + lane] = (int)(~(unsigned)(m & 0xffffffffull));
  }
}

// ---------------- gather nodes[row][c] = feat[b][c][pos] ----------------
__global__ __launch_bounds__(256) void gather_kernel(const float* __restrict__ feat_s,
                                                     const float* __restrict__ feat_t,
                                                     const int* __restrict__ idx,
                                                     float* __restrict__ nodes) {
  int blk = blockIdx.x;
  int bi = blk / NN, n = blk % NN;
  int b = bi & 7;
  const float* fp = (bi < 8) ? feat_s : feat_t;
  int pos = idx[bi * NN + n];
  const float* src = fp + (size_t)b * CENC * HW + pos;
  float* dst = nodes + (size_t)blk * CENC;
  for (int c = threadIdx.x; c < CENC; c += 256)
    dst[c] = src[(size_t)c * HW];
}

// ---------------- fused GEMM: C = LNopt(A)[M,K] @ W[K,256] + bias ----------------
// in_stats: per-row {4 partial sums, 4 partial sumsq} -> apply (x-m)*rstd (+relu) on A load
// out_stats: epilogue writes this block's partial row sum/sumsq (slot = blockIdx.x)
// out2: optional second output (rows < 1024) for writing n1 directly to d_out
__global__ __launch_bounds__(256) void gemm_f(const float* __restrict__ A,
                                              const float* __restrict__ W,
                                              const float* __restrict__ bias,
                                              float* __restrict__ C,
                                              int K,
                                              const float* __restrict__ in_stats, int in_relu,
                                              float* __restrict__ out_stats,
                                              float* __restrict__ out2,
                                              int Wstride, int bstride, int Cstride) {
  __shared__ float As[16][36];
  __shared__ float Bs[16][64];
  __shared__ float mS[32], rS[32];
  int z = blockIdx.z;
  W += (size_t)z * Wstride;
  if (bias) bias += (size_t)z * bstride;
  C += (size_t)z * Cstride;
  int n0 = blockIdx.x * 64;
  int m0 = blockIdx.y * 32;
  int tid = threadIdx.x;
  if (in_stats) {
    if (tid < 32) {
      const float* sp = in_stats + (size_t)(m0 + tid) * 8;
      float s = sp[0] + sp[1] + sp[2] + sp[3];
      float q = sp[4] + sp[5] + sp[6] + sp[7];
      float m = s * (1.0f / 256.f);
      float var = q * (1.0f / 256.f) - m * m;
      mS[tid] = m;
      rS[tid] = 1.0f / sqrtf(var + 1e-5f);
    }
    __syncthreads();
  }
  int arow = tid >> 3, acol = (tid & 7) * 2;
  int bk = tid >> 4, bn4 = tid & 15;
  int tx = tid & 15, ty = tid >> 4;
  float acc[2][4] = {{0.f, 0.f, 0.f, 0.f}, {0.f, 0.f, 0.f, 0.f}};
  for (int k0 = 0; k0 < K; k0 += 16) {
    float2 a2 = *(const float2*)&A[(size_t)(m0 + arow) * K + k0 + acol];
    if (in_stats) {
      float m = mS[arow], r = rS[arow];
      a2.x = (a2.x - m) * r;
      a2.y = (a2.y - m) * r;
      if (in_relu) { a2.x = fmaxf(a2.x, 0.f); a2.y = fmaxf(a2.y, 0.f); }
    }
    float4 b4 = *(const float4*)&W[(size_t)(k0 + bk) * 256 + n0 + bn4 * 4];
    As[acol][arow] = a2.x;
    As[acol + 1][arow] = a2.y;
    *(float4*)&Bs[bk][bn4 * 4] = b4;
    __syncthreads();
#pragma unroll
    for (int kk = 0; kk < 16; ++kk) {
      float2 av = *(const float2*)&As[kk][ty * 2];
      float4 bv = *(const float4*)&Bs[kk][tx * 4];
      acc[0][0] += av.x * bv.x; acc[0][1] += av.x * bv.y;
      acc[0][2] += av.x * bv.z; acc[0][3] += av.x * bv.w;
      acc[1][0] += av.y * bv.x; acc[1][1] += av.y * bv.y;
      acc[1][2] += av.y * bv.z; acc[1][3] += av.y * bv.w;
    }
    __syncthreads();
  }
  float4 bb = {0.f, 0.f, 0.f, 0.f};
  if (bias) bb = *(const float4*)&bias[n0 + tx * 4];
#pragma unroll
  for (int i = 0; i < 2; ++i) {
    int row = m0 + ty * 2 + i;
    float4 o;
    o.x = acc[i][0] + bb.x; o.y = acc[i][1] + bb.y;
    o.z = acc[i][2] + bb.z; o.w = acc[i][3] + bb.w;
    *(float4*)&C[(size_t)row * 256 + n0 + tx * 4] = o;
    if (out2 && row < ROWS1)
      *(float4*)&out2[(size_t)row * 256 + n0 + tx * 4] = o;
    if (out_stats) {
      float s = o.x + o.y + o.z + o.w;
      float q = o.x * o.x + o.y * o.y + o.z * o.z + o.w * o.w;
#pragma unroll
      for (int msk = 1; msk < 16; msk <<= 1) {
        s += __shfl_xor(s, msk);
        q += __shfl_xor(q, msk);
      }
      if (tx == 0) {
        out_stats[(size_t)row * 8 + blockIdx.x] = s;
        out_stats[(size_t)row * 8 + 4 + blockIdx.x] = q;
      }
    }
  }
}

// ---------------- NT GEMM per image: Mm[b] = A[b](128x256) @ Bt[b](128x256)^T ----------------
__global__ __launch_bounds__(256) void gemm_nt(const float* __restrict__ A,
                                               const float* __restrict__ Bt,
                                               float* __restrict__ C) {
  __shared__ float As[16][36];
  __shared__ float Bs[16][68];
  int b = blockIdx.z;
  int m0 = blockIdx.y * 32, n0 = blockIdx.x * 64;
  const float* Ab = A + (size_t)b * NN * DD;
  const float* Bb = Bt + (size_t)b * NN * DD;
  int tid = threadIdx.x;
  int arow = tid >> 3, acol = (tid & 7) * 2;
  int bn = tid >> 2, bk4 = (tid & 3) * 4;
  int tx = tid & 15, ty = tid >> 4;
  float acc[2][4] = {{0.f, 0.f, 0.f, 0.f}, {0.f, 0.f, 0.f, 0.f}};
  for (int k0 = 0; k0 < DD; k0 += 16) {
    float2 a2 = *(const float2*)&Ab[(size_t)(m0 + arow) * DD + k0 + acol];
    float4 b4 = *(const float4*)&Bb[(size_t)(n0 + bn) * DD + k0 + bk4];
    As[acol][arow] = a2.x;
    As[acol + 1][arow] = a2.y;
    Bs[bk4 + 0][bn] = b4.x; Bs[bk4 + 1][bn] = b4.y;
    Bs[bk4 + 2][bn] = b4.z; Bs[bk4 + 3][bn] = b4.w;
    __syncthreads();
#pragma unroll
    for (int kk = 0; kk < 16; ++kk) {
      float2 av = *(const float2*)&As[kk][ty * 2];
      float4 bv = *(const float4*)&Bs[kk][tx * 4];
      acc[0][0] += av.x * bv.x; acc[0][1] += av.x * bv.y;
      acc[0][2] += av.x * bv.z; acc[0][3] += av.x * bv.w;
      acc[1][0] += av.y * bv.x; acc[1][1] += av.y * bv.y;
      acc[1][2] += av.y * bv.z; acc[1][3] += av.y * bv.w;
    }
    __syncthreads();
  }
#pragma unroll
  for (int i = 0; i < 2; ++i) {
    float4 o = {acc[i][0], acc[i][1], acc[i][2], acc[i][3]};
    *(float4*)&C[(size_t)b * NN * NN + (size_t)(m0 + ty * 2 + i) * NN + n0 + tx * 4] = o;
  }
}

// ---------------- fused attention per (bb, head), j split over 2 thread-halves ----------------
__global__ __launch_bounds__(256) void attn_kernel(const float* __restrict__ q,
                                                   const float* __restrict__ k,
                                                   const float* __restrict__ v,
                                                   float* __restrict__ o, int swap) {
  __shared__ __align__(16) float Ks[NN][DH];
  __shared__ __align__(16) float Vs[NN][DH];
  __shared__ __align__(16) float Ex[NN][36];   // acc[32], mx, den
  int blk = blockIdx.x;
  int bb = blk >> 3, h = blk & 7;
  int kb = swap ? (bb ^ 8) : bb;
  int tid = threadIdx.x;
  int qrow = tid & 127, half = tid >> 7;
  for (int e4 = tid; e4 < 2 * NN * DH / 4; e4 += 256) {
    int which = e4 >> 10;       // 0 = K, 1 = V
    int idx = e4 & 1023;
    int r = idx >> 3, c4 = idx & 7;
    float4 val = *(const float4*)&((which ? v : k)[(size_t)(kb * NN + r) * DD + h * DH + c4 * 4]);
    if (which) ((float4*)Vs[r])[c4] = val;
    else       ((float4*)Ks[r])[c4] = val;
  }
  __syncthreads();
  float4 q4[8];
  const float* qp = q + (size_t)(bb * NN + qrow) * DD + h * DH;
#pragma unroll
  for (int c4 = 0; c4 < 8; ++c4) q4[c4] = ((const float4*)qp)[c4];
  const float scale = 0.17677669529663687f;   // 1/sqrt(32)
  int j0 = half * 64;
  float mx = -1e30f;
  for (int j = j0; j < j0 + 64; ++j) {
    const float4* kp = (const float4*)Ks[j];
    float s = 0.f;
#pragma unroll
    for (int c4 = 0; c4 < 8; ++c4) {
      float4 kv = kp[c4];
      s += q4[c4].x * kv.x + q4[c4].y * kv.y + q4[c4].z * kv.z + q4[c4].w * kv.w;
    }
    mx = fmaxf(mx, s * scale);
  }
  float acc[DH];
#pragma unroll
  for (int c = 0; c < DH; ++c) acc[c] = 0.f;
  float den = 0.f;
  for (int j = j0; j < j0 + 64; ++j) {
    const float4* kp = (const float4*)Ks[j];
    float s = 0.f;
#pragma unroll
    for (int c4 = 0; c4 < 8; ++c4) {
      float4 kv = kp[c4];
      s += q4[c4].x * kv.x + q4[c4].y * kv.y + q4[c4].z * kv.z + q4[c4].w * kv.w;
    }
    float e = expf(s * scale - mx);
    den += e;
    const float4* vp = (const float4*)Vs[j];
#pragma unroll
    for (int c4 = 0; c4 < 8; ++c4) {
      float4 vv = vp[c4];
      acc[c4 * 4 + 0] += e * vv.x; acc[c4 * 4 + 1] += e * vv.y;
      acc[c4 * 4 + 2] += e * vv.z; acc[c4 * 4 + 3] += e * vv.w;
    }
  }
  if (half == 1) {
#pragma unroll
    for (int c = 0; c < DH; ++c) Ex[qrow][c] = acc[c];
    Ex[qrow][32] = mx;
    Ex[qrow][33] = den;
  }
  __syncthreads();
  if (half == 0) {
    float m1 = Ex[qrow][32], d1 = Ex[qrow][33];
    float M = fmaxf(mx, m1);
    float f0 = expf(mx - M), f1 = expf(m1 - M);
    float inv = 1.0f / (den * f0 + d1 * f1);
    float* op = o + (size_t)(bb * NN + qrow) * DD + h * DH;
#pragma unroll
    for (int c4 = 0; c4 < 8; ++c4) {
      float4 ov;
      ov.x = (acc[c4 * 4 + 0] * f0 + Ex[qrow][c4 * 4 + 0] * f1) * inv;
      ov.y = (acc[c4 * 4 + 1] * f0 + Ex[qrow][c4 * 4 + 1] * f1) * inv;
      ov.z = (acc[c4 * 4 + 2] * f0 + Ex[qrow][c4 * 4 + 2] * f1) * inv;
      ov.w = (acc[c4 * 4 + 3] * f0 + Ex[qrow][c4 * 4 + 3] * f1) * inv;
      ((float4*)op)[c4] = ov;
    }
  }
}

// ---------------- cls MLP + BCEWithLogits (4 rows/block) ----------------
__global__ __launch_bounds__(128) void cls_loss_kernel(const float* __restrict__ x,
                                                       const float* __restrict__ W1,
                                                       const float* __restrict__ b1,
                                                       const float* __restrict__ W2,
                                                       const float* __restrict__ b2,
                                                       float* __restrict__ loss_acc) {
  __shared__ float xs[4][DD];
  __shared__ float red[2][4];
  int r0 = blockIdx.x * 4;
  int tid = threadIdx.x, lane = tid & 63, w = tid >> 6;
  for (int e = tid; e < 4 * DD; e += 128)
    xs[e >> 8][e & 255] = x[(size_t)(r0 + (e >> 8)) * DD + (e & 255)];
  __syncthreads();
  float bb1 = b1[tid];
  float h0 = bb1, h1 = bb1, h2 = bb1, h3 = bb1;
  for (int kk = 0; kk < DD; ++kk) {
    float wv = W1[kk * 128 + tid];
    h0 += xs[0][kk] * wv;
    h1 += xs[1][kk] * wv;
    h2 += xs[2][kk] * wv;
    h3 += xs[3][kk] * wv;
  }
  float w2 = W2[tid];
  float p0 = fmaxf(h0, 0.f) * w2, p1 = fmaxf(h1, 0.f) * w2;
  float p2 = fmaxf(h2, 0.f) * w2, p3 = fmaxf(h3, 0.f) * w2;
#pragma unroll
  for (int m = 1; m < 64; m <<= 1) {
    p0 += __shfl_xor(p0, m); p1 += __shfl_xor(p1, m);
    p2 += __shfl_xor(p2, m); p3 += __shfl_xor(p3, m);
  }
  if (lane == 0) { red[w][0] = p0; red[w][1] = p1; red[w][2] = p2; red[w][3] = p3; }
  __syncthreads();
  if (tid == 0) {
    float total = 0.f;
#pragma unroll
    for (int r = 0; r < 4; ++r) {
      float z = red[0][r] + red[1][r] + b2[0];
      float lab = (((r0 + r) & 127) < 64) ? 1.f : 0.f;
      total += fmaxf(z, 0.f) - z * lab + log1pf(expf(-fabsf(z)));
    }
    atomicAdd(loss_acc, total * (1.0f / 1024.0f));
  }
}

// ---------------- instance-norm + 10 sinkhorn iters (u/v form) + focal loss (per b) ----------------
__global__ __launch_bounds__(1024) void sinkhorn_kernel(const float* __restrict__ Mm,
                                                        float* __restrict__ loss_acc) {
  __shared__ __align__(16) float u_[NN];
  __shared__ __align__(16) float v_[NN];
  __shared__ float red[20];
  int b = blockIdx.x;
  int t = threadIdx.x;
  const float* src = Mm + (size_t)b * NN * NN;
  int r  = t >> 3, cg = t & 7;
  int c  = t >> 3, rg = t & 7;
  float kr[16], kc[16];
  {
    const float4* s4 = (const float4*)(src + (size_t)r * NN + cg * 16);
#pragma unroll
    for (int q4 = 0; q4 < 4; ++q4) {
      float4 f = s4[q4];
      kr[q4 * 4 + 0] = f.x; kr[q4 * 4 + 1] = f.y; kr[q4 * 4 + 2] = f.z; kr[q4 * 4 + 3] = f.w;
    }
#pragma unroll
    for (int q = 0; q < 16; ++q)
      kc[q] = src[(size_t)(rg * 16 + q) * NN + c];
  }
  float s = 0.f;
#pragma unroll
  for (int q = 0; q < 16; ++q) s += kr[q];
  for (int m = 1; m < 64; m <<= 1) s += __shfl_xor(s, m);
  if ((t & 63) == 0) red[t >> 6] = s;
  __syncthreads();
  if (t == 0) { float tt = 0.f; for (int i = 0; i < 16; ++i) tt += red[i]; red[16] = tt; }
  __syncthreads();
  float mu = red[16] * (1.0f / 16384.f);
  __syncthreads();
  float sq = 0.f;
#pragma unroll
  for (int q = 0; q < 16; ++q) { float d = kr[q] - mu; sq += d * d; }
  for (int m = 1; m < 64; m <<= 1) sq += __shfl_xor(sq, m);
  if ((t & 63) == 0) red[t >> 6] = sq;
  __syncthreads();
  if (t == 0) { float tt = 0.f; for (int i = 0; i < 16; ++i) tt += red[i]; red[17] = tt; }
  __syncthreads();
  float inv = 1.0f / sqrtf(red[17] * (1.0f / 16384.f) + 1e-5f);
#pragma unroll
  for (int q = 0; q < 16; ++q) { kr[q] = (kr[q] - mu) * inv; kc[q] = (kc[q] - mu) * inv; }
  if (t < NN) { u_[t] = 0.f; v_[t] = 0.f; }
  __syncthreads();
  for (int iter = 0; iter < 10; ++iter) {
    float tmp[16];
    {
      const float4* vp = (const float4*)(v_ + cg * 16);
#pragma unroll
      for (int q4 = 0; q4 < 4; ++q4) {
        float4 f = vp[q4];
        tmp[q4 * 4 + 0] = kr[q4 * 4 + 0] - f.x; tmp[q4 * 4 + 1] = kr[q4 * 4 + 1] - f.y;
        tmp[q4 * 4 + 2] = kr[q4 * 4 + 2] - f.z; tmp[q4 * 4 + 3] = kr[q4 * 4 + 3] - f.w;
      }
      float mx = tmp[0];
#pragma unroll
      for (int q = 1; q < 16; ++q) mx = fmaxf(mx, tmp[q]);
      for (int m = 1; m < 8; m <<= 1) mx = fmaxf(mx, __shfl_xor(mx, m));
      float sm = 0.f;
#pragma unroll
      for (int q = 0; q < 16; ++q) sm += expf(tmp[q] - mx);
      for (int m = 1; m < 8; m <<= 1) sm += __shfl_xor(sm, m);
      if (cg == 0) u_[r] = mx + logf(sm);
    }
    __syncthreads();
    {
      const float4* up = (const float4*)(u_ + rg * 16);
#pragma unroll
      for (int q4 = 0; q4 < 4; ++q4) {
        float4 f = up[q4];
        tmp[q4 * 4 + 0] = kc[q4 * 4 + 0] - f.x; tmp[q4 * 4 + 1] = kc[q4 * 4 + 1] - f.y;
        tmp[q4 * 4 + 2] = kc[q4 * 4 + 2] - f.z; tmp[q4 * 4 + 3] = kc[q4 * 4 + 3] - f.w;
      }
      float mx = tmp[0];
#pragma unroll
      for (int q = 1; q < 16; ++q) mx = fmaxf(mx, tmp[q]);
      for (int m = 1; m < 8; m <<= 1) mx = fmaxf(mx, __shfl_xor(mx, m));
      float sm = 0.f;
#pragma unroll
      for (int q = 0; q < 16; ++q) sm += expf(tmp[q] - mx);
      for (int m = 1; m < 8; m <<= 1) sm += __shfl_xor(sm, m);
      if (rg == 0) v_[c] = mx + logf(sm);
    }
    __syncthreads();
  }
  float ur = u_[r];
  float fsum = 0.f;
  {
    const float4* vp = (const float4*)(v_ + cg * 16);
#pragma unroll
    for (int q4 = 0; q4 < 4; ++q4) {
      float4 f = vp[q4];
      float vv[4] = {f.x, f.y, f.z, f.w};
#pragma unroll
      for (int j = 0; j < 4; ++j) {
        float P = expf(kr[q4 * 4 + j] - ur - vv[j]);
        float pt = fminf(fmaxf(P, 1e-6f), 1.0f - 1e-6f);
        int col = cg * 16 + q4 * 4 + j;
        bool gt = (r < 64) == (col < 64);
        float w = gt ? (-0.25f * (1.f - pt) * (1.f - pt)) : (-0.75f * pt * pt);
        float l = gt ? logf(pt) : logf(1.f - pt);
        fsum += w * l;
      }
    }
  }
  for (int m = 1; m < 64; m <<= 1) fsum += __shfl_xor(fsum, m);
  if ((t & 63) == 0) red[t >> 6] = fsum;
  __syncthreads();
  if (t == 0) {
    float tt = 0.f; for (int i = 0; i < 16; ++i) tt += red[i];
    atomicAdd(loss_acc + 1, tt * (1.0f / 131072.f));
  }
}

// ---------------- scalar loss write (n1 already dual-written by last gemm) ----------------
__global__ void finalize_kernel(const float* __restrict__ loss_acc,
                                float* __restrict__ out) {
  if (threadIdx.x == 0) out[ROWS1 * DD] = loss_acc[0] + 10.0f * loss_acc[1];
}

extern "C" void kernel_launch(void* const* d_in, const int* in_sizes, int n_in,
                              void* d_out, int out_size, void* d_ws, size_t ws_size,
                              hipStream_t stream) {
  const float* feat_s  = (const float*)d_in[0];
  const float* score_s = (const float*)d_in[1];
  const float* feat_t  = (const float*)d_in[2];
  const float* score_t = (const float*)d_in[3];
  const float* head_W1 = (const float*)d_in[4];
  const float* head_b1 = (const float*)d_in[5];
  const float* head_W2 = (const float*)d_in[6];
  const float* head_b2 = (const float*)d_in[7];
  const float* intra_W = (const float*)d_in[8];
  const float* intra_b = (const float*)d_in[9];
  const float* cross_W = (const float*)d_in[10];
  const float* cross_b = (const float*)d_in[11];
  const float* cls_W1  = (const float*)d_in[12];
  const float* cls_b1  = (const float*)d_in[13];
  const float* cls_W2  = (const float*)d_in[14];
  const float* cls_b2  = (const float*)d_in[15];
  const float* aff_A   = (const float*)d_in[16];

  float* ws = (float*)d_ws;
  float* nodes = ws;                         // 2048*512
  float* bufA  = nodes + 2048 * 512;         // 2048*256
  float* bufB  = bufA + ROWS2 * DD;          // 2048*256
  float* bufH  = bufB + ROWS2 * DD;          // 2048*256
  float* bufQ  = bufH + ROWS2 * DD;          // 3 x 2048*256 contiguous (Q,K,V)
  float* bufK  = bufQ + ROWS2 * DD;
  float* bufV  = bufK + ROWS2 * DD;
  float* st1   = bufV + ROWS2 * DD;          // 2048*8
  float* st2   = st1 + ROWS2 * 8;            // 2048*8
  float* acc   = st2 + ROWS2 * 8;            // 2 floats (pad 8)
  int*   idxb  = (int*)(acc + 8);            // 16*128 ints
  float* Mm    = (float*)(idxb + 2048);      // 8*128*128
  float* out_f = (float*)d_out;

  topk_kernel<<<32, 256, 0, stream>>>(score_s, score_t, idxb, acc);
  gather_kernel<<<16 * NN, 256, 0, stream>>>(feat_s, feat_t, idxb, nodes);

  dim3 g1(4, 64, 1);      // 256 blocks, M=2048
  dim3 g3(4, 64, 3);      // z-batched QKV
  dim3 gaff(4, 32, 1);    // M=1024
  const int WS = DD * DD, BS = DD, CS = ROWS2 * DD;
  float* nul = nullptr;

  // head: (Linear -> [stats]) -> (LN+ReLU on load -> Linear -> [stats])
  gemm_f<<<g1, 256, 0, stream>>>(nodes, head_W1, head_b1, bufA, CENC, nul, 0, st1, nul, 0, 0, 0);
  gemm_f<<<g1, 256, 0, stream>>>(bufA, head_W2, head_b2, bufB, DD, st1, 1, st2, nul, 0, 0, 0);

  // intra self-attention (LN2 applied on A load of QKV)
  gemm_f<<<g3, 256, 0, stream>>>(bufB, intra_W, intra_b, bufQ, DD, st2, 0, nul, nul, WS, BS, CS);
  attn_kernel<<<16 * NHEAD, 256, 0, stream>>>(bufQ, bufK, bufV, bufA, 0);
  gemm_f<<<g1, 256, 0, stream>>>(bufA, intra_W + 3 * WS, intra_b + 3 * BS, bufH, DD, nul, 0, nul, nul, 0, 0, 0); // G

  // cross attention
  gemm_f<<<g3, 256, 0, stream>>>(bufH, cross_W, cross_b, bufQ, DD, nul, 0, nul, nul, WS, BS, CS);
  attn_kernel<<<16 * NHEAD, 256, 0, stream>>>(bufQ, bufK, bufV, bufA, 1);
  gemm_f<<<g1, 256, 0, stream>>>(bufA, cross_W + 3 * WS, cross_b + 3 * BS, bufH, DD, nul, 0, nul, out_f, 0, 0, 0); // C (+n1 out)

  // node classification loss
  cls_loss_kernel<<<ROWS2 / 4, 128, 0, stream>>>(bufH, cls_W1, cls_b1, cls_W2, cls_b2, acc);

  // affinity: tmp = c1 @ aff_A ; Mm = tmp @ c2^T
  gemm_f<<<gaff, 256, 0, stream>>>(bufH, aff_A, nul, bufA, DD, nul, 0, nul, nul, 0, 0, 0);
  dim3 gnt(2, 4, BIMG);
  gemm_nt<<<gnt, 256, 0, stream>>>(bufA, bufH + (size_t)ROWS1 * DD, Mm);

  // instance-norm + sinkhorn + focal loss
  sinkhorn_kernel<<<BIMG, 1024, 0, stream>>>(Mm, acc);

  // scalar total loss
  finalize_kernel<<<1, 64, 0, stream>>>(acc, out_f);
}

// Round 5
// 300.321 us; speedup vs baseline: 3.4975x; 1.2059x over previous
//
#include <hip/hip_runtime.h>
#include <math.h>

#define BIMG 8
#define HW 9216
#define CENC 512
#define NN 128
#define DD 256
#define NHEAD 8
#define DH 32
#define ROWS1 1024
#define ROWS2 2048

typedef unsigned long long ull;
typedef __attribute__((ext_vector_type(4))) float f32x4;
typedef __attribute__((ext_vector_type(4))) unsigned u32x4;
typedef __attribute__((ext_vector_type(2))) unsigned u32x2;

__device__ __forceinline__ unsigned short f2bf(float f) {
  unsigned u = __float_as_uint(f);
  u += 0x7fffu + ((u >> 16) & 1u);
  return (unsigned short)(u >> 16);
}
__device__ __forceinline__ float bf2f(unsigned h) {
  return __uint_as_float(h << 16);
}
__device__ __forceinline__ unsigned pack2(float a, float b) {
  return (unsigned)f2bf(a) | ((unsigned)f2bf(b) << 16);
}

__device__ __forceinline__ ull cmpex_keep(ull k, ull o, bool keepMax) {
  return ((k > o) == keepMax) ? k : o;
}
__device__ __forceinline__ void bsort64(ull& k, int lane) {
#pragma unroll
  for (int size = 2; size <= 64; size <<= 1) {
#pragma unroll
    for (int stride = size >> 1; stride > 0; stride >>= 1) {
      ull o = __shfl_xor(k, stride);
      bool keepMax = (((lane & size) == 0) == ((lane & stride) == 0));
      k = cmpex_keep(k, o, keepMax);
    }
  }
}
__device__ __forceinline__ void bmerge64(ull& top, ull b, int lane) {
  ull rev = __shfl_xor(b, 63);
  ull m = top > rev ? top : rev;
#pragma unroll
  for (int stride = 32; stride > 0; stride >>= 1) {
    ull o = __shfl_xor(m, stride);
    m = cmpex_keep(m, o, (lane & stride) == 0);
  }
  top = m;
}

// ---------------- top-64 (pos desc / neg asc) via wave-bitonic streaming ----------------
__global__ __launch_bounds__(256) void topk_kernel(const float* __restrict__ score_s,
                                                   const float* __restrict__ score_t,
                                                   int* __restrict__ idx_out,
                                                   float* __restrict__ loss_acc) {
  __shared__ ull sm[256];
  int blk = blockIdx.x;
  int bi = blk >> 1, neg = blk & 1;
  int tid = threadIdx.x, lane = tid & 63, w = tid >> 6;
  if (blk == 0 && tid < 2) loss_acc[tid] = 0.f;
  const float* sp = (bi < 8 ? score_s : score_t) + (size_t)(bi & 7) * HW;
  int q0 = w * 36;
  float vals[36];
#pragma unroll
  for (int j = 0; j < 36; ++j) vals[j] = sp[(q0 + j) * 64 + lane];
  ull keys[36];
#pragma unroll
  for (int j = 0; j < 36; ++j) {
    unsigned ub = __float_as_uint(vals[j]);
    unsigned u = (ub & 0x80000000u) ? ~ub : (ub | 0x80000000u);
    if (neg) u = ~u;
    int gi = (q0 + j) * 64 + lane;
    keys[j] = ((ull)u << 32) | (unsigned)(~gi);
  }
  ull top1 = keys[0];  bsort64(top1, lane);
  ull top2 = keys[18]; bsort64(top2, lane);
#pragma unroll
  for (int j = 1; j < 18; ++j) {
    ull k1 = keys[j], k2 = keys[18 + j];
    bsort64(k1, lane);
    bsort64(k2, lane);
    bmerge64(top1, k1, lane);
    bmerge64(top2, k2, lane);
  }
  bmerge64(top1, top2, lane);
  sm[w * 64 + lane] = top1;
  __syncthreads();
  if (w < 2) {
    ull a = sm[(2 * w) * 64 + lane];
    ull b = sm[(2 * w + 1) * 64 + (63 - lane)];
    ull m = a > b ? a : b;
#pragma unroll
    for (int stride = 32; stride > 0; stride >>= 1) {
      ull o = __shfl_xor(m, stride);
      m = cmpex_keep(m, o, (lane & stride) == 0);
    }
    sm[(2 * w) * 64 + lane] = m;
  }
  __syncthreads();
  if (w == 0) {
    ull a = sm[lane];
    ull b = sm[128 + (63 - lane)];
    ull m = a > b ? a : b;
#pragma unroll
    for (int stride = 32; stride > 0; stride >>= 1) {
      ull o = __shfl_xor(m, stride);
      m = cmpex_keep(m, o, (lane & stride) == 0);
    }
    idx_out[bi * NN + neg * 64 + lane] = (int)(~(unsigned)(m & 0xffffffffull));
  }
}

// ---------------- gather -> bf16 nodes[row][c] ----------------
__global__ __launch_bounds__(256) void gather_kernel(const float* __restrict__ feat_s,
                                                     const float* __restrict__ feat_t,
                                                     const int* __restrict__ idx,
                                                     unsigned short* __restrict__ nodes) {
  int blk = blockIdx.x;
  int bi = blk >> 7, n = blk & 127;
  int b = bi & 7;
  const float* fp = (bi < 8) ? feat_s : feat_t;
  int pos = idx[bi * NN + n];
  const float* src = fp + (size_t)b * CENC * HW + pos;
  unsigned* dst = (unsigned*)(nodes + (size_t)blk * CENC);
  int t = threadIdx.x;
  float f0 = src[(size_t)(2 * t) * HW];
  float f1 = src[(size_t)(2 * t + 1) * HW];
  dst[t] = pack2(f0, f1);
}

// ---------------- weights: fp32 [K][256] -> bf16 transposed [256][K] ----------------
__global__ __launch_bounds__(256) void wconv_kernel(const float* __restrict__ hw1,
                                                    const float* __restrict__ hw2,
                                                    const float* __restrict__ iw,
                                                    const float* __restrict__ cw,
                                                    const float* __restrict__ aw,
                                                    unsigned short* __restrict__ wt) {
  __shared__ float tile[32][33];
  int bid = blockIdx.x, t = threadIdx.x;
  const float* src; unsigned short* dst; int K, k0, n0;
  if (bid < 128) {
    src = hw1; dst = wt; K = 512;
    k0 = (bid >> 3) * 32; n0 = (bid & 7) * 32;
  } else {
    int id2 = bid - 128;
    int m = id2 >> 6, tt = id2 & 63;
    K = 256;
    k0 = (tt >> 3) * 32; n0 = (tt & 7) * 32;
    src = (m == 0) ? hw2 : (m < 5) ? iw + (size_t)(m - 1) * 65536
        : (m < 9) ? cw + (size_t)(m - 5) * 65536 : aw;
    dst = wt + 131072 + (size_t)m * 65536;
  }
  int r = t >> 3, c = (t & 7) * 4;
  float4 v = *(const float4*)&src[(size_t)(k0 + r) * 256 + n0 + c];
  tile[r][c] = v.x; tile[r][c + 1] = v.y; tile[r][c + 2] = v.z; tile[r][c + 3] = v.w;
  __syncthreads();
  u32x2 o;
  o[0] = pack2(tile[c][r], tile[c + 1][r]);
  o[1] = pack2(tile[c + 2][r], tile[c + 3][r]);
  *(u32x2*)&dst[(size_t)(n0 + r) * K + k0 + c] = o;
}

// ---------------- bf16 MFMA GEMM: out = LNopt(A)[M,K] @ Wt[N,K]^T + bias ----------------
// tile 32x64, 4 waves: wave (wr,wc) -> rows m0+wr*16, cols n0+wc*32 (2 frags)
__global__ __launch_bounds__(256) void gemm_mf(const unsigned short* __restrict__ A,
                                               const unsigned short* __restrict__ Wt,
                                               const float* __restrict__ bias,
                                               unsigned short* __restrict__ Cb,
                                               float* __restrict__ Cf,
                                               int K, int ldc, int f32rows,
                                               const float* __restrict__ in_stats, int in_relu,
                                               float* __restrict__ out_stats,
                                               int Az, int Wz, int Cbz, int Cfz, int bz) {
  __shared__ unsigned short As[32][40];
  __shared__ unsigned short Bs[64][40];
  __shared__ float mS[32], rS[32];
  int z = blockIdx.z;
  A  += (size_t)z * Az;
  Wt += (size_t)z * Wz;
  if (Cb)   Cb += (size_t)z * Cbz;
  if (Cf)   Cf += (size_t)z * Cfz;
  if (bias) bias += (size_t)z * bz;
  int n0 = blockIdx.x * 64, m0 = blockIdx.y * 32;
  int t = threadIdx.x;
  if (in_stats) {
    if (t < 32) {
      const float* sp = in_stats + (size_t)(m0 + t) * 16;
      float s = 0.f, q = 0.f;
#pragma unroll
      for (int i = 0; i < 8; ++i) { s += sp[i]; q += sp[8 + i]; }
      float m = s * (1.0f / 256.f);
      float var = q * (1.0f / 256.f) - m * m;
      mS[t] = m;
      rS[t] = 1.0f / sqrtf(var + 1e-5f);
    }
    __syncthreads();
  }
  int l = t & 63, w = t >> 6;
  int wr = w >> 1, wc = w & 1;
  int sar = t >> 2, sac = (t & 3) * 8;
  int fra = wr * 16 + (l & 15);
  int frk = (l >> 4) * 8;
  int fb0 = wc * 32 + (l & 15);
  int fb1 = fb0 + 16;
  f32x4 acc0 = {0.f, 0.f, 0.f, 0.f};
  f32x4 acc1 = {0.f, 0.f, 0.f, 0.f};
  for (int k0 = 0; k0 < K; k0 += 32) {
    if (t < 128) {
      u32x4 av = *(const u32x4*)&A[(size_t)(m0 + sar) * K + k0 + sac];
      if (in_stats) {
        float m = mS[sar], r = rS[sar];
#pragma unroll
        for (int i = 0; i < 4; ++i) {
          float f0 = (bf2f(av[i] & 0xffffu) - m) * r;
          float f1 = (bf2f(av[i] >> 16) - m) * r;
          if (in_relu) { f0 = fmaxf(f0, 0.f); f1 = fmaxf(f1, 0.f); }
          av[i] = pack2(f0, f1);
        }
      }
      *(u32x4*)&As[sar][sac] = av;
    }
    u32x4 bv = *(const u32x4*)&Wt[(size_t)(n0 + sar) * K + k0 + sac];
    *(u32x4*)&Bs[sar][sac] = bv;
    __syncthreads();
    u32x4 af  = *(const u32x4*)&As[fra][frk];
    u32x4 bf0 = *(const u32x4*)&Bs[fb0][frk];
    u32x4 bf1 = *(const u32x4*)&Bs[fb1][frk];
    asm volatile("v_mfma_f32_16x16x32_bf16 %0, %1, %2, %0" : "+v"(acc0) : "v"(af), "v"(bf0));
    asm volatile("v_mfma_f32_16x16x32_bf16 %0, %1, %2, %0" : "+v"(acc1) : "v"(af), "v"(bf1));
    __syncthreads();
  }
  asm volatile("s_nop 7\n\ts_nop 7" ::);   // MFMA -> VALU read hazard padding
  int col0 = n0 + wc * 32 + (l & 15);
  int rbase = m0 + wr * 16 + (l >> 4) * 4;
  float b0 = 0.f, b1 = 0.f;
  if (bias) { b0 = bias[col0]; b1 = bias[col0 + 16]; }
#pragma unroll
  for (int r = 0; r < 4; ++r) {
    int row = rbase + r;
    float o0 = acc0[r] + b0;
    float o1 = acc1[r] + b1;
    if (Cb) {
      Cb[(size_t)row * 256 + col0]      = f2bf(o0);
      Cb[(size_t)row * 256 + col0 + 16] = f2bf(o1);
    }
    if (Cf && row < f32rows) {
      Cf[(size_t)row * ldc + col0]      = o0;
      Cf[(size_t)row * ldc + col0 + 16] = o1;
    }
    if (out_stats) {
      float s = o0 + o1, q = o0 * o0 + o1 * o1;
#pragma unroll
      for (int m = 1; m < 16; m <<= 1) { s += __shfl_xor(s, m); q += __shfl_xor(q, m); }
      if ((l & 15) == 0) {
        out_stats[(size_t)row * 16 + blockIdx.x * 2 + wc]     = s;
        out_stats[(size_t)row * 16 + 8 + blockIdx.x * 2 + wc] = q;
      }
    }
  }
}

// ---------------- fused attention per (bb, head), bf16 in/out ----------------
__global__ __launch_bounds__(256) void attn_kernel(const unsigned short* __restrict__ q,
                                                   const unsigned short* __restrict__ k,
                                                   const unsigned short* __restrict__ v,
                                                   unsigned short* __restrict__ o, int swap) {
  __shared__ __align__(16) float Ks[NN][DH];
  __shared__ __align__(16) float Vs[NN][DH];
  __shared__ __align__(16) float Ex[NN][36];
  int blk = blockIdx.x;
  int bb = blk >> 3, h = blk & 7;
  int kb = swap ? (bb ^ 8) : bb;
  int t = threadIdx.x;
  int qrow = t & 127, half = t >> 7;
  for (int e = t; e < 1024; e += 256) {
    int which = e >> 9;
    int idx2 = e & 511;
    int r = idx2 >> 2, c4 = idx2 & 3;
    u32x4 val = *(const u32x4*)&(which ? v : k)[(size_t)(kb * NN + r) * DD + h * DH + c4 * 8];
    float* dst = which ? &Vs[r][c4 * 8] : &Ks[r][c4 * 8];
#pragma unroll
    for (int i = 0; i < 4; ++i) {
      dst[2 * i]     = bf2f(val[i] & 0xffffu);
      dst[2 * i + 1] = bf2f(val[i] >> 16);
    }
  }
  __syncthreads();
  float4 q4[8];
  {
    const unsigned short* qp = q + (size_t)(bb * NN + qrow) * DD + h * DH;
#pragma unroll
    for (int c4 = 0; c4 < 4; ++c4) {
      u32x4 u = *(const u32x4*)&qp[c4 * 8];
      q4[c4 * 2].x = bf2f(u[0] & 0xffffu); q4[c4 * 2].y = bf2f(u[0] >> 16);
      q4[c4 * 2].z = bf2f(u[1] & 0xffffu); q4[c4 * 2].w = bf2f(u[1] >> 16);
      q4[c4 * 2 + 1].x = bf2f(u[2] & 0xffffu); q4[c4 * 2 + 1].y = bf2f(u[2] >> 16);
      q4[c4 * 2 + 1].z = bf2f(u[3] & 0xffffu); q4[c4 * 2 + 1].w = bf2f(u[3] >> 16);
    }
  }
  const float scale = 0.17677669529663687f;   // 1/sqrt(32)
  int j0 = half * 64;
  float mx = -1e30f;
  for (int j = j0; j < j0 + 64; ++j) {
    const float4* kp = (const float4*)Ks[j];
    float s = 0.f;
#pragma unroll
    for (int c4 = 0; c4 < 8; ++c4) {
      float4 kv = kp[c4];
      s += q4[c4].x * kv.x + q4[c4].y * kv.y + q4[c4].z * kv.z + q4[c4].w * kv.w;
    }
    mx = fmaxf(mx, s * scale);
  }
  float acc[DH];
#pragma unroll
  for (int c = 0; c < DH; ++c) acc[c] = 0.f;
  float den = 0.f;
  for (int j = j0; j < j0 + 64; ++j) {
    const float4* kp = (const float4*)Ks[j];
    float s = 0.f;
#pragma unroll
    for (int c4 = 0; c4 < 8; ++c4) {
      float4 kv = kp[c4];
      s += q4[c4].x * kv.x + q4[c4].y * kv.y + q4[c4].z * kv.z + q4[c4].w * kv.w;
    }
    float e = expf(s * scale - mx);
    den += e;
    const float4* vp = (const float4*)Vs[j];
#pragma unroll
    for (int c4 = 0; c4 < 8; ++c4) {
      float4 vv = vp[c4];
      acc[c4 * 4 + 0] += e * vv.x; acc[c4 * 4 + 1] += e * vv.y;
      acc[c4 * 4 + 2] += e * vv.z; acc[c4 * 4 + 3] += e * vv.w;
    }
  }
  if (half == 1) {
#pragma unroll
    for (int c = 0; c < DH; ++c) Ex[qrow][c] = acc[c];
    Ex[qrow][32] = mx;
    Ex[qrow][33] = den;
  }
  __syncthreads();
  if (half == 0) {
    float m1 = Ex[qrow][32], d1 = Ex[qrow][33];
    float M = fmaxf(mx, m1);
    float f0 = expf(mx - M), f1 = expf(m1 - M);
    float inv = 1.0f / (den * f0 + d1 * f1);
    unsigned ovu[16];
#pragma unroll
    for (int c = 0; c < 16; ++c) {
      float x0 = (acc[2 * c]     * f0 + Ex[qrow][2 * c]     * f1) * inv;
      float x1 = (acc[2 * c + 1] * f0 + Ex[qrow][2 * c + 1] * f1) * inv;
      ovu[c] = pack2(x0, x1);
    }
    unsigned* op = (unsigned*)(o + (size_t)(bb * NN + qrow) * DD + h * DH);
#pragma unroll
    for (int i = 0; i < 4; ++i) {
      u32x4 w4;
      w4[0] = ovu[4 * i]; w4[1] = ovu[4 * i + 1]; w4[2] = ovu[4 * i + 2]; w4[3] = ovu[4 * i + 3];
      *(u32x4*)&op[4 * i] = w4;
    }
  }
}

// ---------------- cls MLP + BCEWithLogits (4 rows/block, bf16 input) ----------------
__global__ __launch_bounds__(128) void cls_loss_kernel(const unsigned short* __restrict__ x,
                                                       const float* __restrict__ W1,
                                                       const float* __restrict__ b1,
                                                       const float* __restrict__ W2,
                                                       const float* __restrict__ b2,
                                                       float* __restrict__ loss_acc) {
  __shared__ float xs[4][DD];
  __shared__ float red[2][4];
  int r0 = blockIdx.x * 4;
  int tid = threadIdx.x, lane = tid & 63, w = tid >> 6;
  {
    int rr = tid >> 5, c8 = (tid & 31) * 8;
    u32x4 u = *(const u32x4*)&x[(size_t)(r0 + rr) * DD + c8];
#pragma unroll
    for (int i = 0; i < 4; ++i) {
      xs[rr][c8 + 2 * i]     = bf2f(u[i] & 0xffffu);
      xs[rr][c8 + 2 * i + 1] = bf2f(u[i] >> 16);
    }
  }
  __syncthreads();
  float bb1 = b1[tid];
  float h0 = bb1, h1 = bb1, h2 = bb1, h3 = bb1;
  for (int kk = 0; kk < DD; ++kk) {
    float wv = W1[kk * 128 + tid];
    h0 += xs[0][kk] * wv;
    h1 += xs[1][kk] * wv;
    h2 += xs[2][kk] * wv;
    h3 += xs[3][kk] * wv;
  }
  float w2 = W2[tid];
  float p0 = fmaxf(h0, 0.f) * w2, p1 = fmaxf(h1, 0.f) * w2;
  float p2 = fmaxf(h2, 0.f) * w2, p3 = fmaxf(h3, 0.f) * w2;
#pragma unroll
  for (int m = 1; m < 64; m <<= 1) {
    p0 += __shfl_xor(p0, m); p1 += __shfl_xor(p1, m);
    p2 += __shfl_xor(p2, m); p3 += __shfl_xor(p3, m);
  }
  if (lane == 0) { red[w][0] = p0; red[w][1] = p1; red[w][2] = p2; red[w][3] = p3; }
  __syncthreads();
  if (tid == 0) {
    float total = 0.f;
#pragma unroll
    for (int r = 0; r < 4; ++r) {
      float z = red[0][r] + red[1][r] + b2[0];
      float lab = (((r0 + r) & 127) < 64) ? 1.f : 0.f;
      total += fmaxf(z, 0.f) - z * lab + log1pf(expf(-fabsf(z)));
    }
    atomicAdd(loss_acc, total * (1.0f / 1024.0f));
  }
}

// ---------------- instance-norm + 10 sinkhorn iters (u/v form) + focal loss ----------------
__global__ __launch_bounds__(1024) void sinkhorn_kernel(const float* __restrict__ Mm,
                                                        float* __restrict__ loss_acc) {
  __shared__ __align__(16) float u_[NN];
  __shared__ __align__(16) float v_[NN];
  __shared__ float red[20];
  int b = blockIdx.x;
  int t = threadIdx.x;
  const float* src = Mm + (size_t)b * NN * NN;
  int r = t >> 3, cg = t & 7;
  int c = t >> 3, rg = t & 7;
  float kr[16], kc[16];
  {
    const float4* s4 = (const float4*)(src + (size_t)r * NN + cg * 16);
#pragma unroll
    for (int q4 = 0; q4 < 4; ++q4) {
      float4 f = s4[q4];
      kr[q4 * 4 + 0] = f.x; kr[q4 * 4 + 1] = f.y; kr[q4 * 4 + 2] = f.z; kr[q4 * 4 + 3] = f.w;
    }
#pragma unroll
    for (int q = 0; q < 16; ++q)
      kc[q] = src[(size_t)(rg * 16 + q) * NN + c];
  }
  float s = 0.f;
#pragma unroll
  for (int q = 0; q < 16; ++q) s += kr[q];
  for (int m = 1; m < 64; m <<= 1) s += __shfl_xor(s, m);
  if ((t & 63) == 0) red[t >> 6] = s;
  __syncthreads();
  if (t == 0) { float tt = 0.f; for (int i = 0; i < 16; ++i) tt += red[i]; red[16] = tt; }
  __syncthreads();
  float mu = red[16] * (1.0f / 16384.f);
  __syncthreads();
  float sq = 0.f;
#pragma unroll
  for (int q = 0; q < 16; ++q) { float d = kr[q] - mu; sq += d * d; }
  for (int m = 1; m < 64; m <<= 1) sq += __shfl_xor(sq, m);
  if ((t & 63) == 0) red[t >> 6] = sq;
  __syncthreads();
  if (t == 0) { float tt = 0.f; for (int i = 0; i < 16; ++i) tt += red[i]; red[17] = tt; }
  __syncthreads();
  float inv = 1.0f / sqrtf(red[17] * (1.0f / 16384.f) + 1e-5f);
#pragma unroll
  for (int q = 0; q < 16; ++q) { kr[q] = (kr[q] - mu) * inv; kc[q] = (kc[q] - mu) * inv; }
  if (t < NN) { u_[t] = 0.f; v_[t] = 0.f; }
  __syncthreads();
  for (int iter = 0; iter < 10; ++iter) {
    float tmp[16];
    {
      const float4* vp = (const float4*)(v_ + cg * 16);
#pragma unroll
      for (int q4 = 0; q4 < 4; ++q4) {
        float4 f = vp[q4];
        tmp[q4 * 4 + 0] = kr[q4 * 4 + 0] - f.x; tmp[q4 * 4 + 1] = kr[q4 * 4 + 1] - f.y;
        tmp[q4 * 4 + 2] = kr[q4 * 4 + 2] - f.z; tmp[q4 * 4 + 3] = kr[q4 * 4 + 3] - f.w;
      }
      float mx = tmp[0];
#pragma unroll
      for (int q = 1; q < 16; ++q) mx = fmaxf(mx, tmp[q]);
      for (int m = 1; m < 8; m <<= 1) mx = fmaxf(mx, __shfl_xor(mx, m));
      float sm = 0.f;
#pragma unroll
      for (int q = 0; q < 16; ++q) sm += expf(tmp[q] - mx);
      for (int m = 1; m < 8; m <<= 1) sm += __shfl_xor(sm, m);
      if (cg == 0) u_[r] = mx + logf(sm);
    }
    __syncthreads();
    {
      const float4* up = (const float4*)(u_ + rg * 16);
#pragma unroll
      for (int q4 = 0; q4 < 4; ++q4) {
        float4 f = up[q4];
        tmp[q4 * 4 + 0] = kc[q4 * 4 + 0] - f.x; tmp[q4 * 4 + 1] = kc[q4 * 4 + 1] - f.y;
        tmp[q4 * 4 + 2] = kc[q4 * 4 + 2] - f.z; tmp[q4 * 4 + 3] = kc[q4 * 4 + 3] - f.w;
      }
      float mx = tmp[0];
#pragma unroll
      for (int q = 1; q < 16; ++q) mx = fmaxf(mx, tmp[q]);
      for (int m = 1; m < 8; m <<= 1) mx = fmaxf(mx, __shfl_xor(mx, m));
      float sm = 0.f;
#pragma unroll
      for (int q = 0; q < 16; ++q) sm += expf(tmp[q] - mx);
      for (int m = 1; m < 8; m <<= 1) sm += __shfl_xor(sm, m);
      if (rg == 0) v_[c] = mx + logf(sm);
    }
    __syncthreads();
  }
  float ur = u_[r];
  float fsum = 0.f;
  {
    const float4* vp = (const float4*)(v_ + cg * 16);
#pragma unroll
    for (int q4 = 0; q4 < 4; ++q4) {
      float4 f = vp[q4];
      float vv[4] = {f.x, f.y, f.z, f.w};
#pragma unroll
      for (int j = 0; j < 4; ++j) {
        float P = expf(kr[q4 * 4 + j] - ur - vv[j]);
        float pt = fminf(fmaxf(P, 1e-6f), 1.0f - 1e-6f);
        int col = cg * 16 + q4 * 4 + j;
        bool gt = (r < 64) == (col < 64);
        float wgt = gt ? (-0.25f * (1.f - pt) * (1.f - pt)) : (-0.75f * pt * pt);
        float lg = gt ? logf(pt) : logf(1.f - pt);
        fsum += wgt * lg;
      }
    }
  }
  for (int m = 1; m < 64; m <<= 1) fsum += __shfl_xor(fsum, m);
  if ((t & 63) == 0) red[t >> 6] = fsum;
  __syncthreads();
  if (t == 0) {
    float tt = 0.f; for (int i = 0; i < 16; ++i) tt += red[i];
    atomicAdd(loss_acc + 1, tt * (1.0f / 131072.f));
  }
}

__global__ void finalize_kernel(const float* __restrict__ loss_acc,
                                float* __restrict__ out) {
  if (threadIdx.x == 0) out[ROWS1 * DD] = loss_acc[0] + 10.0f * loss_acc[1];
}

extern "C" void kernel_launch(void* const* d_in, const int* in_sizes, int n_in,
                              void* d_out, int out_size, void* d_ws, size_t ws_size,
                              hipStream_t stream) {
  const float* feat_s  = (const float*)d_in[0];
  const float* score_s = (const float*)d_in[1];
  const float* feat_t  = (const float*)d_in[2];
  const float* score_t = (const float*)d_in[3];
  const float* head_W1 = (const float*)d_in[4];
  const float* head_b1 = (const float*)d_in[5];
  const float* head_W2 = (const float*)d_in[6];
  const float* head_b2 = (const float*)d_in[7];
  const float* intra_W = (const float*)d_in[8];
  const float* intra_b = (const float*)d_in[9];
  const float* cross_W = (const float*)d_in[10];
  const float* cross_b = (const float*)d_in[11];
  const float* cls_W1  = (const float*)d_in[12];
  const float* cls_b1  = (const float*)d_in[13];
  const float* cls_W2  = (const float*)d_in[14];
  const float* cls_b2  = (const float*)d_in[15];
  const float* aff_A   = (const float*)d_in[16];

  unsigned short* nodes_bf = (unsigned short*)d_ws;           // 2048*512
  unsigned short* bufA_bf  = nodes_bf + 2048 * 512;           // 2048*256
  unsigned short* bufB_bf  = bufA_bf + ROWS2 * DD;
  unsigned short* bufH_bf  = bufB_bf + ROWS2 * DD;
  unsigned short* qkv_bf   = bufH_bf + ROWS2 * DD;            // 3 planes
  unsigned short* attn_bf  = qkv_bf + 3 * ROWS2 * DD;
  unsigned short* tmp_bf   = attn_bf + ROWS2 * DD;            // 1024*256
  unsigned short* wt       = tmp_bf + ROWS1 * DD;             // 786432
  float* st1  = (float*)(wt + 786432);                        // 2048*16
  float* st2  = st1 + ROWS2 * 16;
  float* acc  = st2 + ROWS2 * 16;                             // 2 floats (pad 8)
  int*   idxb = (int*)(acc + 8);                              // 2048 ints
  float* Mm   = (float*)(idxb + 2048);                        // 8*128*128
  float* out_f = (float*)d_out;

  unsigned short* wt_h1 = wt;
  unsigned short* wt_h2 = wt + 131072;
  unsigned short* wt_in = wt_h2 + 65536;
  unsigned short* wt_cr = wt_in + 4 * 65536;
  unsigned short* wt_af = wt_cr + 4 * 65536;

  topk_kernel<<<32, 256, 0, stream>>>(score_s, score_t, idxb, acc);
  gather_kernel<<<2048, 256, 0, stream>>>(feat_s, feat_t, idxb, nodes_bf);
  wconv_kernel<<<768, 256, 0, stream>>>(head_W1, head_W2, intra_W, cross_W, aff_A, wt);

  dim3 g1(4, 64, 1);
  dim3 gq(4, 64, 3);
  dim3 gaff(4, 32, 1);
  dim3 gnt(2, 4, 8);
  const float* nulf = nullptr;
  unsigned short* nulb = nullptr;
  float* nulw = nullptr;

  // head: Linear(K=512) -> [st1] ; LN+ReLU -> Linear -> [st2]
  gemm_mf<<<g1, 256, 0, stream>>>(nodes_bf, wt_h1, head_b1, bufA_bf, nulw,
                                  512, 0, 0, nulf, 0, st1, 0, 0, 0, 0, 0);
  gemm_mf<<<g1, 256, 0, stream>>>(bufA_bf, wt_h2, head_b2, bufB_bf, nulw,
                                  256, 0, 0, st1, 1, st2, 0, 0, 0, 0, 0);
  // intra: LN on load, z-batched QKV
  gemm_mf<<<gq, 256, 0, stream>>>(bufB_bf, wt_in, intra_b, qkv_bf, nulw,
                                  256, 0, 0, st2, 0, nulw, 0, 65536, ROWS2 * DD, 0, 256);
  attn_kernel<<<128, 256, 0, stream>>>(qkv_bf, qkv_bf + ROWS2 * DD, qkv_bf + 2 * ROWS2 * DD,
                                       attn_bf, 0);
  gemm_mf<<<g1, 256, 0, stream>>>(attn_bf, wt_in + 3 * 65536, intra_b + 768, bufH_bf, nulw,
                                  256, 0, 0, nulf, 0, nulw, 0, 0, 0, 0, 0);   // G
  // cross
  gemm_mf<<<gq, 256, 0, stream>>>(bufH_bf, wt_cr, cross_b, qkv_bf, nulw,
                                  256, 0, 0, nulf, 0, nulw, 0, 65536, ROWS2 * DD, 0, 256);
  attn_kernel<<<128, 256, 0, stream>>>(qkv_bf, qkv_bf + ROWS2 * DD, qkv_bf + 2 * ROWS2 * DD,
                                       attn_bf, 1);
  gemm_mf<<<g1, 256, 0, stream>>>(attn_bf, wt_cr + 3 * 65536, cross_b + 768, bufH_bf, out_f,
                                  256, 256, ROWS1, nulf, 0, nulw, 0, 0, 0, 0, 0); // C (+n1)
  // node classification loss
  cls_loss_kernel<<<ROWS2 / 4, 128, 0, stream>>>(bufH_bf, cls_W1, cls_b1, cls_W2, cls_b2, acc);
  // affinity: tmp = c1 @ aff_A ; Mm = tmp @ c2^T
  gemm_mf<<<gaff, 256, 0, stream>>>(bufH_bf, wt_af, nulf, tmp_bf, nulw,
                                    256, 0, 0, nulf, 0, nulw, 0, 0, 0, 0, 0);
  gemm_mf<<<gnt, 256, 0, stream>>>(tmp_bf, bufH_bf + ROWS1 * DD, nulf, nulb, Mm,
                                   256, 128, 128, nulf, 0, nulw,
                                   NN * DD, NN * DD, 0, NN * NN, 0);
  // sinkhorn + focal loss
  sinkhorn_kernel<<<BIMG, 1024, 0, stream>>>(Mm, acc);
  finalize_kernel<<<1, 64, 0, stream>>>(acc, out_f);
}

// Round 6
// 235.630 us; speedup vs baseline: 4.4577x; 1.2745x over previous
//
#include <hip/hip_runtime.h>
#include <math.h>

#define BIMG 8
#define HW 9216
#define CENC 512
#define NN 128
#define DD 256
#define NHEAD 8
#define DH 32
#define ROWS1 1024
#define ROWS2 2048
#define TAILB 264   // 8 sinkhorn + 256 cls blocks

typedef unsigned long long ull;
typedef __attribute__((ext_vector_type(4))) float f32x4;
typedef __attribute__((ext_vector_type(4))) unsigned u32x4;
typedef __attribute__((ext_vector_type(2))) unsigned u32x2;

__device__ __forceinline__ unsigned short f2bf(float f) {
  unsigned u = __float_as_uint(f);
  u += 0x7fffu + ((u >> 16) & 1u);
  return (unsigned short)(u >> 16);
}
__device__ __forceinline__ float bf2f(unsigned h) { return __uint_as_float(h << 16); }
__device__ __forceinline__ unsigned pack2(float a, float b) {
  return (unsigned)f2bf(a) | ((unsigned)f2bf(b) << 16);
}

__device__ __forceinline__ ull cmpex_keep(ull k, ull o, bool keepMax) {
  return ((k > o) == keepMax) ? k : o;
}
__device__ __forceinline__ void bsort64(ull& k, int lane) {
#pragma unroll
  for (int size = 2; size <= 64; size <<= 1) {
#pragma unroll
    for (int stride = size >> 1; stride > 0; stride >>= 1) {
      ull o = __shfl_xor(k, stride);
      bool keepMax = (((lane & size) == 0) == ((lane & stride) == 0));
      k = cmpex_keep(k, o, keepMax);
    }
  }
}
__device__ __forceinline__ void bmerge64(ull& top, ull b, int lane) {
  ull rev = __shfl_xor(b, 63);
  ull m = top > rev ? top : rev;
#pragma unroll
  for (int stride = 32; stride > 0; stride >>= 1) {
    ull o = __shfl_xor(m, stride);
    m = cmpex_keep(m, o, (lane & stride) == 0);
  }
  top = m;
}

// ---------- launch 1: blocks 0..31 top-64 select ; blocks 32..799 weight transpose ----------
__global__ __launch_bounds__(256) void head_kernel(const float* __restrict__ score_s,
                                                   const float* __restrict__ score_t,
                                                   int* __restrict__ idx_out,
                                                   float* __restrict__ loss_acc,
                                                   const float* __restrict__ hw1,
                                                   const float* __restrict__ hw2,
                                                   const float* __restrict__ iw,
                                                   const float* __restrict__ cw,
                                                   const float* __restrict__ aw,
                                                   unsigned short* __restrict__ wt) {
  __shared__ ull sm[256];
  __shared__ float tile[32][33];
  int tid = threadIdx.x;
  if (blockIdx.x < 32) {
    int blk = blockIdx.x;
    int bi = blk >> 1, neg = blk & 1;
    int lane = tid & 63, w = tid >> 6;
    if (blk == 0 && tid < 4) loss_acc[tid] = 0.f;   // acc[0], acc[1], pad, ticket-counter
    const float* sp = (bi < 8 ? score_s : score_t) + (size_t)(bi & 7) * HW;
    int q0 = w * 36;
    ull keys[36];
#pragma unroll
    for (int j = 0; j < 36; ++j) {
      float x = sp[(q0 + j) * 64 + lane];
      unsigned ub = __float_as_uint(x);
      unsigned u = (ub & 0x80000000u) ? ~ub : (ub | 0x80000000u);
      if (neg) u = ~u;
      int gi = (q0 + j) * 64 + lane;
      keys[j] = ((ull)u << 32) | (unsigned)(~gi);
    }
    ull top1 = keys[0];  bsort64(top1, lane);
    ull top2 = keys[18]; bsort64(top2, lane);
#pragma unroll
    for (int j = 1; j < 18; ++j) {
      ull k1 = keys[j], k2 = keys[18 + j];
      bsort64(k1, lane);
      bsort64(k2, lane);
      bmerge64(top1, k1, lane);
      bmerge64(top2, k2, lane);
    }
    bmerge64(top1, top2, lane);
    sm[w * 64 + lane] = top1;
    __syncthreads();
    if (w < 2) {
      ull a = sm[(2 * w) * 64 + lane];
      ull b = sm[(2 * w + 1) * 64 + (63 - lane)];
      ull m = a > b ? a : b;
#pragma unroll
      for (int stride = 32; stride > 0; stride >>= 1) {
        ull o = __shfl_xor(m, stride);
        m = cmpex_keep(m, o, (lane & stride) == 0);
      }
      sm[(2 * w) * 64 + lane] = m;
    }
    __syncthreads();
    if (w == 0) {
      ull a = sm[lane];
      ull b = sm[128 + (63 - lane)];
      ull m = a > b ? a : b;
#pragma unroll
      for (int stride = 32; stride > 0; stride >>= 1) {
        ull o = __shfl_xor(m, stride);
        m = cmpex_keep(m, o, (lane & stride) == 0);
      }
      idx_out[bi * NN + neg * 64 + lane] = (int)(~(unsigned)(m & 0xffffffffull));
    }
  } else {
    int bid = blockIdx.x - 32;
    const float* src; unsigned short* dst; int K, k0, n0;
    if (bid < 128) {
      src = hw1; dst = wt; K = 512;
      k0 = (bid >> 3) * 32; n0 = (bid & 7) * 32;
    } else {
      int id2 = bid - 128;
      int m = id2 >> 6, tt = id2 & 63;
      K = 256;
      k0 = (tt >> 3) * 32; n0 = (tt & 7) * 32;
      src = (m == 0) ? hw2 : (m < 5) ? iw + (size_t)(m - 1) * 65536
          : (m < 9) ? cw + (size_t)(m - 5) * 65536 : aw;
      dst = wt + 131072 + (size_t)m * 65536;
    }
    int r = tid >> 3, c = (tid & 7) * 4;
    float4 v = *(const float4*)&src[(size_t)(k0 + r) * 256 + n0 + c];
    tile[r][c] = v.x; tile[r][c + 1] = v.y; tile[r][c + 2] = v.z; tile[r][c + 3] = v.w;
    __syncthreads();
    u32x2 o;
    o[0] = pack2(tile[c][r], tile[c + 1][r]);
    o[1] = pack2(tile[c + 2][r], tile[c + 3][r]);
    *(u32x2*)&dst[(size_t)(n0 + r) * K + k0 + c] = o;
  }
}

// ---------------- gather -> bf16 nodes[row][c] ----------------
__global__ __launch_bounds__(256) void gather_kernel(const float* __restrict__ feat_s,
                                                     const float* __restrict__ feat_t,
                                                     const int* __restrict__ idx,
                                                     unsigned short* __restrict__ nodes) {
  int blk = blockIdx.x;
  int bi = blk >> 7, n = blk & 127;
  int b = bi & 7;
  const float* fp = (bi < 8) ? feat_s : feat_t;
  int pos = idx[bi * NN + n];
  const float* src = fp + (size_t)b * CENC * HW + pos;
  unsigned* dst = (unsigned*)(nodes + (size_t)blk * CENC);
  int t = threadIdx.x;
  float f0 = src[(size_t)(2 * t) * HW];
  float f1 = src[(size_t)(2 * t + 1) * HW];
  dst[t] = pack2(f0, f1);
}

// ---------------- bf16 MFMA GEMM, full-K LDS stage, barrier-free K loop ----------------
// tile 32x64, 4 waves: wave (wr,wc) -> rows m0+wr*16, cols n0+wc*32 (2 frags)
template<int K>
__global__ __launch_bounds__(256) void gemm_mf(const unsigned short* __restrict__ A,
                                               const unsigned short* __restrict__ Wt,
                                               const float* __restrict__ bias,
                                               unsigned short* __restrict__ Cb,
                                               float* __restrict__ Cf,
                                               int ldc, int f32rows,
                                               const float* __restrict__ in_stats, int in_relu,
                                               float* __restrict__ out_stats,
                                               int Az, int Wz, int Cbz, int Cfz, int bz) {
  constexpr int LDK = K + 8;
  constexpr int KC = K / 8;
  __shared__ unsigned short As[32][LDK];
  __shared__ unsigned short Bs[64][LDK];
  __shared__ float mS[32], rS[32];
  int z = blockIdx.z;
  A  += (size_t)z * Az;
  Wt += (size_t)z * Wz;
  if (Cb)   Cb += (size_t)z * Cbz;
  if (Cf)   Cf += (size_t)z * Cfz;
  if (bias) bias += (size_t)z * bz;
  int n0 = blockIdx.x * 64, m0 = blockIdx.y * 32;
  int t = threadIdx.x;
  if (in_stats) {
    if (t < 32) {
      const float* sp = in_stats + (size_t)(m0 + t) * 16;
      float s = 0.f, q = 0.f;
#pragma unroll
      for (int i = 0; i < 8; ++i) { s += sp[i]; q += sp[8 + i]; }
      float m = s * (1.0f / 256.f);
      float var = q * (1.0f / 256.f) - m * m;
      mS[t] = m;
      rS[t] = 1.0f / sqrtf(var + 1e-5f);
    }
    __syncthreads();
  }
  // stage full A (32 x K) and B (64 x K)
  for (int i = t; i < 32 * KC; i += 256) {
    int row = i / KC, c8 = (i % KC) * 8;
    u32x4 av = *(const u32x4*)&A[(size_t)(m0 + row) * K + c8];
    if (in_stats) {
      float m = mS[row], r = rS[row];
#pragma unroll
      for (int j = 0; j < 4; ++j) {
        float f0 = (bf2f(av[j] & 0xffffu) - m) * r;
        float f1 = (bf2f(av[j] >> 16) - m) * r;
        if (in_relu) { f0 = fmaxf(f0, 0.f); f1 = fmaxf(f1, 0.f); }
        av[j] = pack2(f0, f1);
      }
    }
    *(u32x4*)&As[row][c8] = av;
  }
  for (int i = t; i < 64 * KC; i += 256) {
    int row = i / KC, c8 = (i % KC) * 8;
    *(u32x4*)&Bs[row][c8] = *(const u32x4*)&Wt[(size_t)(n0 + row) * K + c8];
  }
  __syncthreads();
  int l = t & 63, w = t >> 6;
  int wr = w >> 1, wc = w & 1;
  int fra = wr * 16 + (l & 15);
  int frk = (l >> 4) * 8;
  int fb0 = wc * 32 + (l & 15), fb1 = fb0 + 16;
  f32x4 acc0 = {0.f, 0.f, 0.f, 0.f};
  f32x4 acc1 = {0.f, 0.f, 0.f, 0.f};
#pragma unroll
  for (int ks = 0; ks < K / 32; ++ks) {
    u32x4 af = *(const u32x4*)&As[fra][ks * 32 + frk];
    u32x4 b0 = *(const u32x4*)&Bs[fb0][ks * 32 + frk];
    u32x4 b1 = *(const u32x4*)&Bs[fb1][ks * 32 + frk];
    asm volatile("v_mfma_f32_16x16x32_bf16 %0, %1, %2, %0" : "+v"(acc0) : "v"(af), "v"(b0));
    asm volatile("v_mfma_f32_16x16x32_bf16 %0, %1, %2, %0" : "+v"(acc1) : "v"(af), "v"(b1));
  }
  asm volatile("s_nop 7\n\ts_nop 7" ::);
  int col0 = n0 + wc * 32 + (l & 15);
  int rbase = m0 + wr * 16 + (l >> 4) * 4;
  float b0 = 0.f, b1 = 0.f;
  if (bias) { b0 = bias[col0]; b1 = bias[col0 + 16]; }
#pragma unroll
  for (int r = 0; r < 4; ++r) {
    int row = rbase + r;
    float o0 = acc0[r] + b0;
    float o1 = acc1[r] + b1;
    if (Cb) {
      Cb[(size_t)row * 256 + col0]      = f2bf(o0);
      Cb[(size_t)row * 256 + col0 + 16] = f2bf(o1);
    }
    if (Cf && row < f32rows) {
      Cf[(size_t)row * ldc + col0]      = o0;
      Cf[(size_t)row * ldc + col0 + 16] = o1;
    }
    if (out_stats) {
      float s = o0 + o1, q = o0 * o0 + o1 * o1;
#pragma unroll
      for (int m = 1; m < 16; m <<= 1) { s += __shfl_xor(s, m); q += __shfl_xor(q, m); }
      if ((l & 15) == 0) {
        out_stats[(size_t)row * 16 + blockIdx.x * 2 + wc]     = s;
        out_stats[(size_t)row * 16 + 8 + blockIdx.x * 2 + wc] = q;
      }
    }
  }
}

// ---------------- attention: block = (bb, h, qh) -> 64 q-rows, wave p owns j-quarter p ----------------
__global__ __launch_bounds__(256) void attn_kernel(const unsigned short* __restrict__ q,
                                                   const unsigned short* __restrict__ k,
                                                   const unsigned short* __restrict__ v,
                                                   unsigned short* __restrict__ o, int swap) {
  __shared__ __align__(16) float Ks[NN][DH];
  __shared__ __align__(16) float Vs[NN][DH];
  __shared__ __align__(16) float Ex[64][3][34];
  int blk = blockIdx.x;
  int bb = blk >> 4, h = (blk >> 1) & 7, qh = blk & 1;
  int kb = swap ? (bb ^ 8) : bb;
  int t = threadIdx.x;
  int rr = t & 63, part = t >> 6;
  for (int e = t; e < 1024; e += 256) {
    int which = e >> 9;
    int idx2 = e & 511;
    int r = idx2 >> 2, c8 = (idx2 & 3) * 8;
    u32x4 val = *(const u32x4*)&(which ? v : k)[(size_t)(kb * NN + r) * DD + h * DH + c8];
    float* dst = which ? &Vs[r][c8] : &Ks[r][c8];
#pragma unroll
    for (int i = 0; i < 4; ++i) {
      dst[2 * i]     = bf2f(val[i] & 0xffffu);
      dst[2 * i + 1] = bf2f(val[i] >> 16);
    }
  }
  __syncthreads();
  int qrow = bb * NN + qh * 64 + rr;
  float4 q4[8];
  {
    const unsigned short* qp = q + (size_t)qrow * DD + h * DH;
#pragma unroll
    for (int c4 = 0; c4 < 4; ++c4) {
      u32x4 u = *(const u32x4*)&qp[c4 * 8];
      q4[c4 * 2].x = bf2f(u[0] & 0xffffu); q4[c4 * 2].y = bf2f(u[0] >> 16);
      q4[c4 * 2].z = bf2f(u[1] & 0xffffu); q4[c4 * 2].w = bf2f(u[1] >> 16);
      q4[c4 * 2 + 1].x = bf2f(u[2] & 0xffffu); q4[c4 * 2 + 1].y = bf2f(u[2] >> 16);
      q4[c4 * 2 + 1].z = bf2f(u[3] & 0xffffu); q4[c4 * 2 + 1].w = bf2f(u[3] >> 16);
    }
  }
  const float scale = 0.17677669529663687f;   // 1/sqrt(32)
  int j0 = part * 32;
  float mx = -1e30f;
  for (int j = j0; j < j0 + 32; ++j) {
    const float4* kp = (const float4*)Ks[j];
    float s = 0.f;
#pragma unroll
    for (int c4 = 0; c4 < 8; ++c4) {
      float4 kv = kp[c4];
      s += q4[c4].x * kv.x + q4[c4].y * kv.y + q4[c4].z * kv.z + q4[c4].w * kv.w;
    }
    mx = fmaxf(mx, s * scale);
  }
  float acc[DH];
#pragma unroll
  for (int c = 0; c < DH; ++c) acc[c] = 0.f;
  float den = 0.f;
  for (int j = j0; j < j0 + 32; ++j) {
    const float4* kp = (const float4*)Ks[j];
    float s = 0.f;
#pragma unroll
    for (int c4 = 0; c4 < 8; ++c4) {
      float4 kv = kp[c4];
      s += q4[c4].x * kv.x + q4[c4].y * kv.y + q4[c4].z * kv.z + q4[c4].w * kv.w;
    }
    float e = expf(s * scale - mx);
    den += e;
    const float4* vp = (const float4*)Vs[j];
#pragma unroll
    for (int c4 = 0; c4 < 8; ++c4) {
      float4 vv = vp[c4];
      acc[c4 * 4 + 0] += e * vv.x; acc[c4 * 4 + 1] += e * vv.y;
      acc[c4 * 4 + 2] += e * vv.z; acc[c4 * 4 + 3] += e * vv.w;
    }
  }
  if (part) {
#pragma unroll
    for (int c = 0; c < DH; ++c) Ex[rr][part - 1][c] = acc[c];
    Ex[rr][part - 1][32] = mx;
    Ex[rr][part - 1][33] = den;
  }
  __syncthreads();
  if (part == 0) {
    float M = mx;
#pragma unroll
    for (int p = 0; p < 3; ++p) M = fmaxf(M, Ex[rr][p][32]);
    float f0 = expf(mx - M);
    float fp[3];
    float dt = den * f0;
#pragma unroll
    for (int p = 0; p < 3; ++p) { fp[p] = expf(Ex[rr][p][32] - M); dt += Ex[rr][p][33] * fp[p]; }
    float inv = 1.0f / dt;
    unsigned ovu[16];
#pragma unroll
    for (int c = 0; c < 16; ++c) {
      float x0 = acc[2 * c] * f0, x1 = acc[2 * c + 1] * f0;
#pragma unroll
      for (int p = 0; p < 3; ++p) { x0 += Ex[rr][p][2 * c] * fp[p]; x1 += Ex[rr][p][2 * c + 1] * fp[p]; }
      ovu[c] = pack2(x0 * inv, x1 * inv);
    }
    unsigned* op = (unsigned*)(o + (size_t)qrow * DD + h * DH);
#pragma unroll
    for (int i = 0; i < 4; ++i) {
      u32x4 w4;
      w4[0] = ovu[4 * i]; w4[1] = ovu[4 * i + 1]; w4[2] = ovu[4 * i + 2]; w4[3] = ovu[4 * i + 3];
      *(u32x4*)&op[4 * i] = w4;
    }
  }
}

// ---------------- tail: blocks 0..7 = aff-GEMM + NT-GEMM + sinkhorn + focal ; 8..263 = cls ----------------
struct SkSmem {
  unsigned short tmpL[128][264];
  float Km[128][132];
  float u_[NN];
  float v_[NN];
  float red[20];
};
struct ClsSmem {
  float xs[8][256];
  float red[16];
};
union TailSmem { SkSmem sk; ClsSmem cls; };

__device__ __forceinline__ void ticket_finalize(float* acc, float* out) {
  __threadfence();
  int tk = atomicAdd((int*)acc + 3, 1);
  if (tk == TAILB - 1) {
    float a0 = atomicAdd(acc + 0, 0.0f);
    float a1 = atomicAdd(acc + 1, 0.0f);
    out[ROWS1 * DD] = a0 + 10.0f * a1;
  }
}

__global__ __launch_bounds__(1024) void tail_kernel(const unsigned short* __restrict__ bufH,
                                                    const unsigned short* __restrict__ wt_af,
                                                    const float* __restrict__ W1,
                                                    const float* __restrict__ b1,
                                                    const float* __restrict__ W2,
                                                    const float* __restrict__ b2,
                                                    float* __restrict__ acc,
                                                    float* __restrict__ out) {
  __shared__ TailSmem sm;
  int t = threadIdx.x;
  int bid = blockIdx.x;
  if (bid < 8) {
    // ============ sinkhorn mega-block for image pair b ============
    int b = bid;
    int l = t & 63, w = t >> 6;
    int tr = w >> 1;
    const unsigned short* c1 = bufH + (size_t)(b * 128) * 256;
    const unsigned short* c2 = bufH + (size_t)(1024 + b * 128) * 256;
    // stage A: tmp(128x256) = c1 @ aff  (wave covers row-tile tr, 8 col-tiles)
    {
      int tcB = (w & 1) * 8;
      f32x4 accA[8];
#pragma unroll
      for (int i = 0; i < 8; ++i) accA[i] = (f32x4){0.f, 0.f, 0.f, 0.f};
      for (int ks = 0; ks < 8; ++ks) {
        int kk = ks * 32 + (l >> 4) * 8;
        u32x4 af = *(const u32x4*)&c1[(size_t)(tr * 16 + (l & 15)) * 256 + kk];
#pragma unroll
        for (int i = 0; i < 8; ++i) {
          u32x4 bf = *(const u32x4*)&wt_af[(size_t)((tcB + i) * 16 + (l & 15)) * 256 + kk];
          asm volatile("v_mfma_f32_16x16x32_bf16 %0, %1, %2, %0" : "+v"(accA[i]) : "v"(af), "v"(bf));
        }
      }
      asm volatile("s_nop 7\n\ts_nop 7" ::);
      int rb = tr * 16 + (l >> 4) * 4;
#pragma unroll
      for (int i = 0; i < 8; ++i) {
        int col = (tcB + i) * 16 + (l & 15);
#pragma unroll
        for (int r = 0; r < 4; ++r)
          sm.sk.tmpL[rb + r][col] = f2bf(accA[i][r]);
      }
    }
    __syncthreads();
    // stage B: Km(128x128) = tmp @ c2^T  (wave covers row-tile tr, 4 col-tiles)
    {
      int tcB = (w & 1) * 4;
      f32x4 accB[4];
#pragma unroll
      for (int i = 0; i < 4; ++i) accB[i] = (f32x4){0.f, 0.f, 0.f, 0.f};
      for (int ks = 0; ks < 8; ++ks) {
        int kk = ks * 32 + (l >> 4) * 8;
        u32x4 af = *(const u32x4*)&sm.sk.tmpL[tr * 16 + (l & 15)][kk];
#pragma unroll
        for (int i = 0; i < 4; ++i) {
          u32x4 bf = *(const u32x4*)&c2[(size_t)((tcB + i) * 16 + (l & 15)) * 256 + kk];
          asm volatile("v_mfma_f32_16x16x32_bf16 %0, %1, %2, %0" : "+v"(accB[i]) : "v"(af), "v"(bf));
        }
      }
      asm volatile("s_nop 7\n\ts_nop 7" ::);
      int rb = tr * 16 + (l >> 4) * 4;
#pragma unroll
      for (int i = 0; i < 4; ++i) {
        int col = (tcB + i) * 16 + (l & 15);
#pragma unroll
        for (int r = 0; r < 4; ++r)
          sm.sk.Km[rb + r][col] = accB[i][r];
      }
    }
    __syncthreads();
    // ---- instance-norm + 10 sinkhorn iterations + focal, Km in LDS ----
    int r = t >> 3, cg = t & 7;
    int c = t >> 3, rg = t & 7;
    float kr[16], kc[16];
    {
#pragma unroll
      for (int q4 = 0; q4 < 4; ++q4) {
        float4 f = *(const float4*)&sm.sk.Km[r][cg * 16 + q4 * 4];
        kr[q4 * 4 + 0] = f.x; kr[q4 * 4 + 1] = f.y; kr[q4 * 4 + 2] = f.z; kr[q4 * 4 + 3] = f.w;
      }
#pragma unroll
      for (int q = 0; q < 16; ++q)
        kc[q] = sm.sk.Km[rg * 16 + q][c];
    }
    float s = 0.f;
#pragma unroll
    for (int q = 0; q < 16; ++q) s += kr[q];
    for (int m = 1; m < 64; m <<= 1) s += __shfl_xor(s, m);
    if ((t & 63) == 0) sm.sk.red[t >> 6] = s;
    __syncthreads();
    if (t == 0) { float tt = 0.f; for (int i = 0; i < 16; ++i) tt += sm.sk.red[i]; sm.sk.red[16] = tt; }
    __syncthreads();
    float mu = sm.sk.red[16] * (1.0f / 16384.f);
    __syncthreads();
    float sq = 0.f;
#pragma unroll
    for (int q = 0; q < 16; ++q) { float d = kr[q] - mu; sq += d * d; }
    for (int m = 1; m < 64; m <<= 1) sq += __shfl_xor(sq, m);
    if ((t & 63) == 0) sm.sk.red[t >> 6] = sq;
    __syncthreads();
    if (t == 0) { float tt = 0.f; for (int i = 0; i < 16; ++i) tt += sm.sk.red[i]; sm.sk.red[17] = tt; }
    __syncthreads();
    float inv = 1.0f / sqrtf(sm.sk.red[17] * (1.0f / 16384.f) + 1e-5f);
#pragma unroll
    for (int q = 0; q < 16; ++q) { kr[q] = (kr[q] - mu) * inv; kc[q] = (kc[q] - mu) * inv; }
    if (t < NN) { sm.sk.u_[t] = 0.f; sm.sk.v_[t] = 0.f; }
    __syncthreads();
    for (int iter = 0; iter < 10; ++iter) {
      float tmp[16];
      {
        const float4* vp = (const float4*)(sm.sk.v_ + cg * 16);
#pragma unroll
        for (int q4 = 0; q4 < 4; ++q4) {
          float4 f = vp[q4];
          tmp[q4 * 4 + 0] = kr[q4 * 4 + 0] - f.x; tmp[q4 * 4 + 1] = kr[q4 * 4 + 1] - f.y;
          tmp[q4 * 4 + 2] = kr[q4 * 4 + 2] - f.z; tmp[q4 * 4 + 3] = kr[q4 * 4 + 3] - f.w;
        }
        float mx = tmp[0];
#pragma unroll
        for (int q = 1; q < 16; ++q) mx = fmaxf(mx, tmp[q]);
        for (int m = 1; m < 8; m <<= 1) mx = fmaxf(mx, __shfl_xor(mx, m));
        float smv = 0.f;
#pragma unroll
        for (int q = 0; q < 16; ++q) smv += expf(tmp[q] - mx);
        for (int m = 1; m < 8; m <<= 1) smv += __shfl_xor(smv, m);
        if (cg == 0) sm.sk.u_[r] = mx + logf(smv);
      }
      __syncthreads();
      {
        const float4* up = (const float4*)(sm.sk.u_ + rg * 16);
#pragma unroll
        for (int q4 = 0; q4 < 4; ++q4) {
          float4 f = up[q4];
          tmp[q4 * 4 + 0] = kc[q4 * 4 + 0] - f.x; tmp[q4 * 4 + 1] = kc[q4 * 4 + 1] - f.y;
          tmp[q4 * 4 + 2] = kc[q4 * 4 + 2] - f.z; tmp[q4 * 4 + 3] = kc[q4 * 4 + 3] - f.w;
        }
        float mx = tmp[0];
#pragma unroll
        for (int q = 1; q < 16; ++q) mx = fmaxf(mx, tmp[q]);
        for (int m = 1; m < 8; m <<= 1) mx = fmaxf(mx, __shfl_xor(mx, m));
        float smv = 0.f;
#pragma unroll
        for (int q = 0; q < 16; ++q) smv += expf(tmp[q] - mx);
        for (int m = 1; m < 8; m <<= 1) smv += __shfl_xor(smv, m);
        if (rg == 0) sm.sk.v_[c] = mx + logf(smv);
      }
      __syncthreads();
    }
    float ur = sm.sk.u_[r];
    float fsum = 0.f;
    {
      const float4* vp = (const float4*)(sm.sk.v_ + cg * 16);
#pragma unroll
      for (int q4 = 0; q4 < 4; ++q4) {
        float4 f = vp[q4];
        float vv[4] = {f.x, f.y, f.z, f.w};
#pragma unroll
        for (int j = 0; j < 4; ++j) {
          float P = expf(kr[q4 * 4 + j] - ur - vv[j]);
          float pt = fminf(fmaxf(P, 1e-6f), 1.0f - 1e-6f);
          int col = cg * 16 + q4 * 4 + j;
          bool gt = (r < 64) == (col < 64);
          float wgt = gt ? (-0.25f * (1.f - pt) * (1.f - pt)) : (-0.75f * pt * pt);
          float lg = gt ? logf(pt) : logf(1.f - pt);
          fsum += wgt * lg;
        }
      }
    }
    for (int m = 1; m < 64; m <<= 1) fsum += __shfl_xor(fsum, m);
    if ((t & 63) == 0) sm.sk.red[t >> 6] = fsum;
    __syncthreads();
    if (t == 0) {
      float tt = 0.f; for (int i = 0; i < 16; ++i) tt += sm.sk.red[i];
      atomicAdd(acc + 1, tt * (1.0f / 131072.f));
      ticket_finalize(acc, out);
    }
  } else {
    // ============ cls MLP + BCE, 8 rows per block ============
    int row0 = (bid - 8) * 8;
    int col = t & 127, grp = t >> 7;
    if (t < 256) {
      int rr = t >> 5, c8 = (t & 31) * 8;
      u32x4 u = *(const u32x4*)&bufH[(size_t)(row0 + rr) * 256 + c8];
#pragma unroll
      for (int i = 0; i < 4; ++i) {
        sm.cls.xs[rr][c8 + 2 * i]     = bf2f(u[i] & 0xffffu);
        sm.cls.xs[rr][c8 + 2 * i + 1] = bf2f(u[i] >> 16);
      }
    }
    __syncthreads();
    float h = b1[col];
    for (int kk = 0; kk < 256; ++kk)
      h += sm.cls.xs[grp][kk] * W1[kk * 128 + col];
    float p = fmaxf(h, 0.f) * W2[col];
#pragma unroll
    for (int m = 1; m < 64; m <<= 1) p += __shfl_xor(p, m);
    if ((t & 63) == 0) sm.cls.red[t >> 6] = p;
    __syncthreads();
    if (t == 0) {
      float total = 0.f;
      float bb2 = b2[0];
#pragma unroll
      for (int g = 0; g < 8; ++g) {
        float z = sm.cls.red[2 * g] + sm.cls.red[2 * g + 1] + bb2;
        float lab = (((row0 + g) & 127) < 64) ? 1.f : 0.f;
        total += fmaxf(z, 0.f) - z * lab + log1pf(expf(-fabsf(z)));
      }
      atomicAdd(acc, total * (1.0f / 1024.0f));
      ticket_finalize(acc, out);
    }
  }
}

extern "C" void kernel_launch(void* const* d_in, const int* in_sizes, int n_in,
                              void* d_out, int out_size, void* d_ws, size_t ws_size,
                              hipStream_t stream) {
  const float* feat_s  = (const float*)d_in[0];
  const float* score_s = (const float*)d_in[1];
  const float* feat_t  = (const float*)d_in[2];
  const float* score_t = (const float*)d_in[3];
  const float* head_W1 = (const float*)d_in[4];
  const float* head_b1 = (const float*)d_in[5];
  const float* head_W2 = (const float*)d_in[6];
  const float* head_b2 = (const float*)d_in[7];
  const float* intra_W = (const float*)d_in[8];
  const float* intra_b = (const float*)d_in[9];
  const float* cross_W = (const float*)d_in[10];
  const float* cross_b = (const float*)d_in[11];
  const float* cls_W1  = (const float*)d_in[12];
  const float* cls_b1  = (const float*)d_in[13];
  const float* cls_W2  = (const float*)d_in[14];
  const float* cls_b2  = (const float*)d_in[15];
  const float* aff_A   = (const float*)d_in[16];

  unsigned short* nodes_bf = (unsigned short*)d_ws;           // 2048*512
  unsigned short* bufA_bf  = nodes_bf + 2048 * 512;           // 2048*256
  unsigned short* bufB_bf  = bufA_bf + ROWS2 * DD;
  unsigned short* bufH_bf  = bufB_bf + ROWS2 * DD;
  unsigned short* qkv_bf   = bufH_bf + ROWS2 * DD;            // 3 planes
  unsigned short* attn_bf  = qkv_bf + 3 * ROWS2 * DD;
  unsigned short* wt       = attn_bf + ROWS2 * DD;            // 786432
  float* st1  = (float*)(wt + 786432);                        // 2048*16
  float* st2  = st1 + ROWS2 * 16;
  float* acc  = st2 + ROWS2 * 16;                             // [loss0, loss1, pad, ticket]
  int*   idxb = (int*)(acc + 8);                              // 2048 ints
  float* out_f = (float*)d_out;

  unsigned short* wt_h1 = wt;
  unsigned short* wt_h2 = wt + 131072;
  unsigned short* wt_in = wt_h2 + 65536;
  unsigned short* wt_cr = wt_in + 4 * 65536;
  unsigned short* wt_af = wt_cr + 4 * 65536;

  head_kernel<<<800, 256, 0, stream>>>(score_s, score_t, idxb, acc,
                                       head_W1, head_W2, intra_W, cross_W, aff_A, wt);
  gather_kernel<<<2048, 256, 0, stream>>>(feat_s, feat_t, idxb, nodes_bf);

  dim3 g1(4, 64, 1);
  dim3 gq(4, 64, 3);
  const float* nulf = nullptr;
  float* nulw = nullptr;

  // head: Linear(K=512) -> [st1] ; LN+ReLU -> Linear -> [st2]
  gemm_mf<512><<<g1, 256, 0, stream>>>(nodes_bf, wt_h1, head_b1, bufA_bf, nulw,
                                       0, 0, nulf, 0, st1, 0, 0, 0, 0, 0);
  gemm_mf<256><<<g1, 256, 0, stream>>>(bufA_bf, wt_h2, head_b2, bufB_bf, nulw,
                                       0, 0, st1, 1, st2, 0, 0, 0, 0, 0);
  // intra: LN on load, z-batched QKV
  gemm_mf<256><<<gq, 256, 0, stream>>>(bufB_bf, wt_in, intra_b, qkv_bf, nulw,
                                       0, 0, st2, 0, nulw, 0, 65536, ROWS2 * DD, 0, 256);
  attn_kernel<<<256, 256, 0, stream>>>(qkv_bf, qkv_bf + ROWS2 * DD, qkv_bf + 2 * ROWS2 * DD,
                                       attn_bf, 0);
  gemm_mf<256><<<g1, 256, 0, stream>>>(attn_bf, wt_in + 3 * 65536, intra_b + 768, bufH_bf, nulw,
                                       0, 0, nulf, 0, nulw, 0, 0, 0, 0, 0);   // G
  // cross
  gemm_mf<256><<<gq, 256, 0, stream>>>(bufH_bf, wt_cr, cross_b, qkv_bf, nulw,
                                       0, 0, nulf, 0, nulw, 0, 65536, ROWS2 * DD, 0, 256);
  attn_kernel<<<256, 256, 0, stream>>>(qkv_bf, qkv_bf + ROWS2 * DD, qkv_bf + 2 * ROWS2 * DD,
                                       attn_bf, 1);
  gemm_mf<256><<<g1, 256, 0, stream>>>(attn_bf, wt_cr + 3 * 65536, cross_b + 768, bufH_bf, out_f,
                                       256, ROWS1, nulf, 0, nulw, 0, 0, 0, 0, 0); // C (+n1)
  // tail: sinkhorn-mega (8 blocks) + cls (256 blocks) + ticket finalize
  tail_kernel<<<TAILB, 1024, 0, stream>>>(bufH_bf, wt_af, cls_W1, cls_b1, cls_W2, cls_b2,
                                          acc, out_f);
}

// Round 7
// 217.724 us; speedup vs baseline: 4.8243x; 1.0822x over previous
//
#include <hip/hip_runtime.h>
#include <math.h>

#define BIMG 8
#define HW 9216
#define CENC 512
#define NN 128
#define DD 256
#define NHEAD 8
#define DH 32
#define ROWS1 1024
#define ROWS2 2048
#define TAILB 520   // 8 sinkhorn + 512 cls blocks

typedef unsigned long long ull;
typedef __attribute__((ext_vector_type(4))) float f32x4;
typedef __attribute__((ext_vector_type(4))) unsigned u32x4;
typedef __attribute__((ext_vector_type(2))) unsigned u32x2;

__device__ __forceinline__ unsigned short f2bf(float f) {
  unsigned u = __float_as_uint(f);
  u += 0x7fffu + ((u >> 16) & 1u);
  return (unsigned short)(u >> 16);
}
__device__ __forceinline__ float bf2f(unsigned h) { return __uint_as_float(h << 16); }
__device__ __forceinline__ unsigned pack2(float a, float b) {
  return (unsigned)f2bf(a) | ((unsigned)f2bf(b) << 16);
}

__device__ __forceinline__ ull cmpex_keep(ull k, ull o, bool keepMax) {
  return ((k > o) == keepMax) ? k : o;
}
__device__ __forceinline__ void bsort64(ull& k, int lane) {
#pragma unroll
  for (int size = 2; size <= 64; size <<= 1) {
#pragma unroll
    for (int stride = size >> 1; stride > 0; stride >>= 1) {
      ull o = __shfl_xor(k, stride);
      bool keepMax = (((lane & size) == 0) == ((lane & stride) == 0));
      k = cmpex_keep(k, o, keepMax);
    }
  }
}
__device__ __forceinline__ void bmerge64(ull& top, ull b, int lane) {
  ull rev = __shfl_xor(b, 63);
  ull m = top > rev ? top : rev;
#pragma unroll
  for (int stride = 32; stride > 0; stride >>= 1) {
    ull o = __shfl_xor(m, stride);
    m = cmpex_keep(m, o, (lane & stride) == 0);
  }
  top = m;
}

// ---- launch 1: 0..31 top-64 ; 32..799 weight transpose ; 800..831 cls_W1 -> bf16 W1t ----
__global__ __launch_bounds__(256) void head_kernel(const float* __restrict__ score_s,
                                                   const float* __restrict__ score_t,
                                                   int* __restrict__ idx_out,
                                                   float* __restrict__ loss_acc,
                                                   const float* __restrict__ hw1,
                                                   const float* __restrict__ hw2,
                                                   const float* __restrict__ iw,
                                                   const float* __restrict__ cw,
                                                   const float* __restrict__ aw,
                                                   const float* __restrict__ clsW1,
                                                   unsigned short* __restrict__ wt,
                                                   unsigned short* __restrict__ w1t) {
  __shared__ ull sm[256];
  __shared__ float tile[32][33];
  int tid = threadIdx.x;
  if (blockIdx.x < 32) {
    int blk = blockIdx.x;
    int bi = blk >> 1, neg = blk & 1;
    int lane = tid & 63, w = tid >> 6;
    if (blk == 0 && tid < 4) loss_acc[tid] = 0.f;   // loss0, loss1, pad, ticket
    const float* sp = (bi < 8 ? score_s : score_t) + (size_t)(bi & 7) * HW;
    int q0 = w * 36;
    ull keys[36];
#pragma unroll
    for (int j = 0; j < 36; ++j) {
      float x = sp[(q0 + j) * 64 + lane];
      unsigned ub = __float_as_uint(x);
      unsigned u = (ub & 0x80000000u) ? ~ub : (ub | 0x80000000u);
      if (neg) u = ~u;
      int gi = (q0 + j) * 64 + lane;
      keys[j] = ((ull)u << 32) | (unsigned)(~gi);
    }
    ull top1 = keys[0];  bsort64(top1, lane);
    ull top2 = keys[18]; bsort64(top2, lane);
#pragma unroll
    for (int j = 1; j < 18; ++j) {
      ull k1 = keys[j], k2 = keys[18 + j];
      bsort64(k1, lane);
      bsort64(k2, lane);
      bmerge64(top1, k1, lane);
      bmerge64(top2, k2, lane);
    }
    bmerge64(top1, top2, lane);
    sm[w * 64 + lane] = top1;
    __syncthreads();
    if (w < 2) {
      ull a = sm[(2 * w) * 64 + lane];
      ull b = sm[(2 * w + 1) * 64 + (63 - lane)];
      ull m = a > b ? a : b;
#pragma unroll
      for (int stride = 32; stride > 0; stride >>= 1) {
        ull o = __shfl_xor(m, stride);
        m = cmpex_keep(m, o, (lane & stride) == 0);
      }
      sm[(2 * w) * 64 + lane] = m;
    }
    __syncthreads();
    if (w == 0) {
      ull a = sm[lane];
      ull b = sm[128 + (63 - lane)];
      ull m = a > b ? a : b;
#pragma unroll
      for (int stride = 32; stride > 0; stride >>= 1) {
        ull o = __shfl_xor(m, stride);
        m = cmpex_keep(m, o, (lane & stride) == 0);
      }
      idx_out[bi * NN + neg * 64 + lane] = (int)(~(unsigned)(m & 0xffffffffull));
    }
  } else if (blockIdx.x < 800) {
    int bid = blockIdx.x - 32;
    const float* src; unsigned short* dst; int K, k0, n0;
    if (bid < 128) {
      src = hw1; dst = wt; K = 512;
      k0 = (bid >> 3) * 32; n0 = (bid & 7) * 32;
    } else {
      int id2 = bid - 128;
      int m = id2 >> 6, tt = id2 & 63;
      K = 256;
      k0 = (tt >> 3) * 32; n0 = (tt & 7) * 32;
      src = (m == 0) ? hw2 : (m < 5) ? iw + (size_t)(m - 1) * 65536
          : (m < 9) ? cw + (size_t)(m - 5) * 65536 : aw;
      dst = wt + 131072 + (size_t)m * 65536;
    }
    int r = tid >> 3, c = (tid & 7) * 4;
    float4 v = *(const float4*)&src[(size_t)(k0 + r) * 256 + n0 + c];
    tile[r][c] = v.x; tile[r][c + 1] = v.y; tile[r][c + 2] = v.z; tile[r][c + 3] = v.w;
    __syncthreads();
    u32x2 o;
    o[0] = pack2(tile[c][r], tile[c + 1][r]);
    o[1] = pack2(tile[c + 2][r], tile[c + 3][r]);
    *(u32x2*)&dst[(size_t)(n0 + r) * K + k0 + c] = o;
  } else {
    // cls_W1 [256][128] -> bf16 [128][256]
    int bid3 = blockIdx.x - 800;     // 0..31
    int k0 = (bid3 >> 2) * 32, n0 = (bid3 & 3) * 32;
    int r = tid >> 3, c = (tid & 7) * 4;
    float4 v = *(const float4*)&clsW1[(size_t)(k0 + r) * 128 + n0 + c];
    tile[r][c] = v.x; tile[r][c + 1] = v.y; tile[r][c + 2] = v.z; tile[r][c + 3] = v.w;
    __syncthreads();
    u32x2 o;
    o[0] = pack2(tile[c][r], tile[c + 1][r]);
    o[1] = pack2(tile[c + 2][r], tile[c + 3][r]);
    *(u32x2*)&w1t[(size_t)(n0 + r) * 256 + k0 + c] = o;
  }
}

// ---------------- gather -> bf16 nodes[row][c] ----------------
__global__ __launch_bounds__(256) void gather_kernel(const float* __restrict__ feat_s,
                                                     const float* __restrict__ feat_t,
                                                     const int* __restrict__ idx,
                                                     unsigned short* __restrict__ nodes) {
  int blk = blockIdx.x;
  int bi = blk >> 7, n = blk & 127;
  int b = bi & 7;
  const float* fp = (bi < 8) ? feat_s : feat_t;
  int pos = idx[bi * NN + n];
  const float* src = fp + (size_t)b * CENC * HW + pos;
  unsigned* dst = (unsigned*)(nodes + (size_t)blk * CENC);
  int t = threadIdx.x;
  float f0 = src[(size_t)(2 * t) * HW];
  float f1 = src[(size_t)(2 * t + 1) * HW];
  dst[t] = pack2(f0, f1);
}

// ---------------- bf16 MFMA GEMM, full-K LDS stage, barrier-free K loop ----------------
template<int K>
__global__ __launch_bounds__(256) void gemm_mf(const unsigned short* __restrict__ A,
                                               const unsigned short* __restrict__ Wt,
                                               const float* __restrict__ bias,
                                               unsigned short* __restrict__ Cb,
                                               float* __restrict__ Cf,
                                               int ldc, int f32rows,
                                               const float* __restrict__ in_stats, int in_relu,
                                               float* __restrict__ out_stats,
                                               int Az, int Wz, int Cbz, int Cfz, int bz) {
  constexpr int LDK = K + 8;
  constexpr int KC = K / 8;
  __shared__ unsigned short As[32][LDK];
  __shared__ unsigned short Bs[64][LDK];
  __shared__ float mS[32], rS[32];
  int z = blockIdx.z;
  A  += (size_t)z * Az;
  Wt += (size_t)z * Wz;
  if (Cb)   Cb += (size_t)z * Cbz;
  if (Cf)   Cf += (size_t)z * Cfz;
  if (bias) bias += (size_t)z * bz;
  int n0 = blockIdx.x * 64, m0 = blockIdx.y * 32;
  int t = threadIdx.x;
  if (in_stats) {
    if (t < 32) {
      const float* sp = in_stats + (size_t)(m0 + t) * 16;
      float s = 0.f, q = 0.f;
#pragma unroll
      for (int i = 0; i < 8; ++i) { s += sp[i]; q += sp[8 + i]; }
      float m = s * (1.0f / 256.f);
      float var = q * (1.0f / 256.f) - m * m;
      mS[t] = m;
      rS[t] = 1.0f / sqrtf(var + 1e-5f);
    }
    __syncthreads();
  }
  for (int i = t; i < 32 * KC; i += 256) {
    int row = i / KC, c8 = (i % KC) * 8;
    u32x4 av = *(const u32x4*)&A[(size_t)(m0 + row) * K + c8];
    if (in_stats) {
      float m = mS[row], r = rS[row];
#pragma unroll
      for (int j = 0; j < 4; ++j) {
        float f0 = (bf2f(av[j] & 0xffffu) - m) * r;
        float f1 = (bf2f(av[j] >> 16) - m) * r;
        if (in_relu) { f0 = fmaxf(f0, 0.f); f1 = fmaxf(f1, 0.f); }
        av[j] = pack2(f0, f1);
      }
    }
    *(u32x4*)&As[row][c8] = av;
  }
  for (int i = t; i < 64 * KC; i += 256) {
    int row = i / KC, c8 = (i % KC) * 8;
    *(u32x4*)&Bs[row][c8] = *(const u32x4*)&Wt[(size_t)(n0 + row) * K + c8];
  }
  __syncthreads();
  int l = t & 63, w = t >> 6;
  int wr = w >> 1, wc = w & 1;
  int fra = wr * 16 + (l & 15);
  int frk = (l >> 4) * 8;
  int fb0 = wc * 32 + (l & 15), fb1 = fb0 + 16;
  f32x4 acc0 = {0.f, 0.f, 0.f, 0.f};
  f32x4 acc1 = {0.f, 0.f, 0.f, 0.f};
#pragma unroll
  for (int ks = 0; ks < K / 32; ++ks) {
    u32x4 af = *(const u32x4*)&As[fra][ks * 32 + frk];
    u32x4 b0 = *(const u32x4*)&Bs[fb0][ks * 32 + frk];
    u32x4 b1 = *(const u32x4*)&Bs[fb1][ks * 32 + frk];
    asm volatile("v_mfma_f32_16x16x32_bf16 %0, %1, %2, %0" : "+v"(acc0) : "v"(af), "v"(b0));
    asm volatile("v_mfma_f32_16x16x32_bf16 %0, %1, %2, %0" : "+v"(acc1) : "v"(af), "v"(b1));
  }
  asm volatile("s_nop 7\n\ts_nop 7" ::);
  int col0 = n0 + wc * 32 + (l & 15);
  int rbase = m0 + wr * 16 + (l >> 4) * 4;
  float b0 = 0.f, b1 = 0.f;
  if (bias) { b0 = bias[col0]; b1 = bias[col0 + 16]; }
#pragma unroll
  for (int r = 0; r < 4; ++r) {
    int row = rbase + r;
    float o0 = acc0[r] + b0;
    float o1 = acc1[r] + b1;
    if (Cb) {
      Cb[(size_t)row * 256 + col0]      = f2bf(o0);
      Cb[(size_t)row * 256 + col0 + 16] = f2bf(o1);
    }
    if (Cf && row < f32rows) {
      Cf[(size_t)row * ldc + col0]      = o0;
      Cf[(size_t)row * ldc + col0 + 16] = o1;
    }
    if (out_stats) {
      float s = o0 + o1, q = o0 * o0 + o1 * o1;
#pragma unroll
      for (int m = 1; m < 16; m <<= 1) { s += __shfl_xor(s, m); q += __shfl_xor(q, m); }
      if ((l & 15) == 0) {
        out_stats[(size_t)row * 16 + blockIdx.x * 2 + wc]     = s;
        out_stats[(size_t)row * 16 + 8 + blockIdx.x * 2 + wc] = q;
      }
    }
  }
}

// ---------------- attention: block = (bb, h, qh) -> 64 q-rows, wave p owns j-quarter ----------------
__global__ __launch_bounds__(256) void attn_kernel(const unsigned short* __restrict__ q,
                                                   const unsigned short* __restrict__ k,
                                                   const unsigned short* __restrict__ v,
                                                   unsigned short* __restrict__ o, int swap) {
  __shared__ __align__(16) float Ks[NN][DH];
  __shared__ __align__(16) float Vs[NN][DH];
  __shared__ __align__(16) float Ex[64][3][34];
  int blk = blockIdx.x;
  int bb = blk >> 4, h = (blk >> 1) & 7, qh = blk & 1;
  int kb = swap ? (bb ^ 8) : bb;
  int t = threadIdx.x;
  int rr = t & 63, part = t >> 6;
  for (int e = t; e < 1024; e += 256) {
    int which = e >> 9;
    int idx2 = e & 511;
    int r = idx2 >> 2, c8 = (idx2 & 3) * 8;
    u32x4 val = *(const u32x4*)&(which ? v : k)[(size_t)(kb * NN + r) * DD + h * DH + c8];
    float* dst = which ? &Vs[r][c8] : &Ks[r][c8];
#pragma unroll
    for (int i = 0; i < 4; ++i) {
      dst[2 * i]     = bf2f(val[i] & 0xffffu);
      dst[2 * i + 1] = bf2f(val[i] >> 16);
    }
  }
  __syncthreads();
  int qrow = bb * NN + qh * 64 + rr;
  float4 q4[8];
  {
    const unsigned short* qp = q + (size_t)qrow * DD + h * DH;
#pragma unroll
    for (int c4 = 0; c4 < 4; ++c4) {
      u32x4 u = *(const u32x4*)&qp[c4 * 8];
      q4[c4 * 2].x = bf2f(u[0] & 0xffffu); q4[c4 * 2].y = bf2f(u[0] >> 16);
      q4[c4 * 2].z = bf2f(u[1] & 0xffffu); q4[c4 * 2].w = bf2f(u[1] >> 16);
      q4[c4 * 2 + 1].x = bf2f(u[2] & 0xffffu); q4[c4 * 2 + 1].y = bf2f(u[2] >> 16);
      q4[c4 * 2 + 1].z = bf2f(u[3] & 0xffffu); q4[c4 * 2 + 1].w = bf2f(u[3] >> 16);
    }
  }
  const float scale = 0.17677669529663687f;   // 1/sqrt(32)
  int j0 = part * 32;
  float mx = -1e30f;
  for (int j = j0; j < j0 + 32; ++j) {
    const float4* kp = (const float4*)Ks[j];
    float s = 0.f;
#pragma unroll
    for (int c4 = 0; c4 < 8; ++c4) {
      float4 kv = kp[c4];
      s += q4[c4].x * kv.x + q4[c4].y * kv.y + q4[c4].z * kv.z + q4[c4].w * kv.w;
    }
    mx = fmaxf(mx, s * scale);
  }
  float acc[DH];
#pragma unroll
  for (int c = 0; c < DH; ++c) acc[c] = 0.f;
  float den = 0.f;
  for (int j = j0; j < j0 + 32; ++j) {
    const float4* kp = (const float4*)Ks[j];
    float s = 0.f;
#pragma unroll
    for (int c4 = 0; c4 < 8; ++c4) {
      float4 kv = kp[c4];
      s += q4[c4].x * kv.x + q4[c4].y * kv.y + q4[c4].z * kv.z + q4[c4].w * kv.w;
    }
    float e = __expf(s * scale - mx);
    den += e;
    const float4* vp = (const float4*)Vs[j];
#pragma unroll
    for (int c4 = 0; c4 < 8; ++c4) {
      float4 vv = vp[c4];
      acc[c4 * 4 + 0] += e * vv.x; acc[c4 * 4 + 1] += e * vv.y;
      acc[c4 * 4 + 2] += e * vv.z; acc[c4 * 4 + 3] += e * vv.w;
    }
  }
  if (part) {
#pragma unroll
    for (int c = 0; c < DH; ++c) Ex[rr][part - 1][c] = acc[c];
    Ex[rr][part - 1][32] = mx;
    Ex[rr][part - 1][33] = den;
  }
  __syncthreads();
  if (part == 0) {
    float M = mx;
#pragma unroll
    for (int p = 0; p < 3; ++p) M = fmaxf(M, Ex[rr][p][32]);
    float f0 = __expf(mx - M);
    float fp[3];
    float dt = den * f0;
#pragma unroll
    for (int p = 0; p < 3; ++p) { fp[p] = __expf(Ex[rr][p][32] - M); dt += Ex[rr][p][33] * fp[p]; }
    float inv = 1.0f / dt;
    unsigned ovu[16];
#pragma unroll
    for (int c = 0; c < 16; ++c) {
      float x0 = acc[2 * c] * f0, x1 = acc[2 * c + 1] * f0;
#pragma unroll
      for (int p = 0; p < 3; ++p) { x0 += Ex[rr][p][2 * c] * fp[p]; x1 += Ex[rr][p][2 * c + 1] * fp[p]; }
      ovu[c] = pack2(x0 * inv, x1 * inv);
    }
    unsigned* op = (unsigned*)(o + (size_t)qrow * DD + h * DH);
#pragma unroll
    for (int i = 0; i < 4; ++i) {
      u32x4 w4;
      w4[0] = ovu[4 * i]; w4[1] = ovu[4 * i + 1]; w4[2] = ovu[4 * i + 2]; w4[3] = ovu[4 * i + 3];
      *(u32x4*)&op[4 * i] = w4;
    }
  }
}

// ---------------- tail: 0..7 = aff+NT+sinkhorn+focal ; 8..519 = cls (4 rows each) ----------------
struct SkSmem {
  union { unsigned short tmpL[128][264]; float Km[128][132]; } u;  // aliased stages
  float u_[NN];
  float v_[NN];
  float red[20];
};
struct ClsSmem {
  float xs[4][256];
  float part[4][128];
  float red[8];
};
union TailSmem { SkSmem sk; ClsSmem cls; };

__device__ __forceinline__ void ticket_finalize(float* acc, float* out) {
  __threadfence();
  int tk = atomicAdd((int*)acc + 3, 1);
  if (tk == TAILB - 1) {
    float a0 = atomicAdd(acc + 0, 0.0f);
    float a1 = atomicAdd(acc + 1, 0.0f);
    out[ROWS1 * DD] = a0 + 10.0f * a1;
  }
}

__global__ __launch_bounds__(1024) void tail_kernel(const unsigned short* __restrict__ bufH,
                                                    const unsigned short* __restrict__ wt_af,
                                                    const unsigned short* __restrict__ w1t,
                                                    const float* __restrict__ b1,
                                                    const float* __restrict__ W2,
                                                    const float* __restrict__ b2,
                                                    float* __restrict__ acc,
                                                    float* __restrict__ out) {
  __shared__ TailSmem sm;
  int t = threadIdx.x;
  int bid = blockIdx.x;
  if (bid < 8) {
    int b = bid;
    int l = t & 63, w = t >> 6;
    int tr = w >> 1;
    const unsigned short* c1 = bufH + (size_t)(b * 128) * 256;
    const unsigned short* c2 = bufH + (size_t)(1024 + b * 128) * 256;
    // stage A: tmp(128x256) = c1 @ aff -> bf16 LDS
    {
      int tcB = (w & 1) * 8;
      f32x4 accA[8];
#pragma unroll
      for (int i = 0; i < 8; ++i) accA[i] = (f32x4){0.f, 0.f, 0.f, 0.f};
      for (int ks = 0; ks < 8; ++ks) {
        int kk = ks * 32 + (l >> 4) * 8;
        u32x4 af = *(const u32x4*)&c1[(size_t)(tr * 16 + (l & 15)) * 256 + kk];
#pragma unroll
        for (int i = 0; i < 8; ++i) {
          u32x4 bf = *(const u32x4*)&wt_af[(size_t)((tcB + i) * 16 + (l & 15)) * 256 + kk];
          asm volatile("v_mfma_f32_16x16x32_bf16 %0, %1, %2, %0" : "+v"(accA[i]) : "v"(af), "v"(bf));
        }
      }
      asm volatile("s_nop 7\n\ts_nop 7" ::);
      int rb = tr * 16 + (l >> 4) * 4;
#pragma unroll
      for (int i = 0; i < 8; ++i) {
        int col = (tcB + i) * 16 + (l & 15);
#pragma unroll
        for (int r = 0; r < 4; ++r)
          sm.sk.u.tmpL[rb + r][col] = f2bf(accA[i][r]);
      }
    }
    __syncthreads();
    // stage B: Km = tmp @ c2^T (read tmpL into regs), then overwrite union with fp32 Km
    f32x4 accB[4];
    {
      int tcB = (w & 1) * 4;
#pragma unroll
      for (int i = 0; i < 4; ++i) accB[i] = (f32x4){0.f, 0.f, 0.f, 0.f};
      for (int ks = 0; ks < 8; ++ks) {
        int kk = ks * 32 + (l >> 4) * 8;
        u32x4 af = *(const u32x4*)&sm.sk.u.tmpL[tr * 16 + (l & 15)][kk];
#pragma unroll
        for (int i = 0; i < 4; ++i) {
          u32x4 bf = *(const u32x4*)&c2[(size_t)((tcB + i) * 16 + (l & 15)) * 256 + kk];
          asm volatile("v_mfma_f32_16x16x32_bf16 %0, %1, %2, %0" : "+v"(accB[i]) : "v"(af), "v"(bf));
        }
      }
      asm volatile("s_nop 7\n\ts_nop 7" ::);
    }
    __syncthreads();   // all tmpL reads complete before aliased Km writes
    {
      int tcB = (w & 1) * 4;
      int rb = tr * 16 + (l >> 4) * 4;
#pragma unroll
      for (int i = 0; i < 4; ++i) {
        int col = (tcB + i) * 16 + (l & 15);
#pragma unroll
        for (int r = 0; r < 4; ++r)
          sm.sk.u.Km[rb + r][col] = accB[i][r];
      }
    }
    __syncthreads();
    // ---- instance-norm + 10 sinkhorn iterations + focal ----
    int r = t >> 3, cg = t & 7;
    int c = t >> 3, rg = t & 7;
    float kr[16], kc[16];
    {
#pragma unroll
      for (int q4 = 0; q4 < 4; ++q4) {
        float4 f = *(const float4*)&sm.sk.u.Km[r][cg * 16 + q4 * 4];
        kr[q4 * 4 + 0] = f.x; kr[q4 * 4 + 1] = f.y; kr[q4 * 4 + 2] = f.z; kr[q4 * 4 + 3] = f.w;
      }
#pragma unroll
      for (int q = 0; q < 16; ++q)
        kc[q] = sm.sk.u.Km[rg * 16 + q][c];
    }
    float s = 0.f;
#pragma unroll
    for (int q = 0; q < 16; ++q) s += kr[q];
    for (int m = 1; m < 64; m <<= 1) s += __shfl_xor(s, m);
    if ((t & 63) == 0) sm.sk.red[t >> 6] = s;
    __syncthreads();
    if (t == 0) { float tt = 0.f; for (int i = 0; i < 16; ++i) tt += sm.sk.red[i]; sm.sk.red[16] = tt; }
    __syncthreads();
    float mu = sm.sk.red[16] * (1.0f / 16384.f);
    __syncthreads();
    float sq = 0.f;
#pragma unroll
    for (int q = 0; q < 16; ++q) { float d = kr[q] - mu; sq += d * d; }
    for (int m = 1; m < 64; m <<= 1) sq += __shfl_xor(sq, m);
    if ((t & 63) == 0) sm.sk.red[t >> 6] = sq;
    __syncthreads();
    if (t == 0) { float tt = 0.f; for (int i = 0; i < 16; ++i) tt += sm.sk.red[i]; sm.sk.red[17] = tt; }
    __syncthreads();
    float inv = 1.0f / sqrtf(sm.sk.red[17] * (1.0f / 16384.f) + 1e-5f);
#pragma unroll
    for (int q = 0; q < 16; ++q) { kr[q] = (kr[q] - mu) * inv; kc[q] = (kc[q] - mu) * inv; }
    if (t < NN) { sm.sk.u_[t] = 0.f; sm.sk.v_[t] = 0.f; }
    __syncthreads();
    for (int iter = 0; iter < 10; ++iter) {
      float tmp[16];
      {
        const float4* vp = (const float4*)(sm.sk.v_ + cg * 16);
#pragma unroll
        for (int q4 = 0; q4 < 4; ++q4) {
          float4 f = vp[q4];
          tmp[q4 * 4 + 0] = kr[q4 * 4 + 0] - f.x; tmp[q4 * 4 + 1] = kr[q4 * 4 + 1] - f.y;
          tmp[q4 * 4 + 2] = kr[q4 * 4 + 2] - f.z; tmp[q4 * 4 + 3] = kr[q4 * 4 + 3] - f.w;
        }
        float mx = tmp[0];
#pragma unroll
        for (int q = 1; q < 16; ++q) mx = fmaxf(mx, tmp[q]);
        for (int m = 1; m < 8; m <<= 1) mx = fmaxf(mx, __shfl_xor(mx, m));
        float smv = 0.f;
#pragma unroll
        for (int q = 0; q < 16; ++q) smv += __expf(tmp[q] - mx);
        for (int m = 1; m < 8; m <<= 1) smv += __shfl_xor(smv, m);
        if (cg == 0) sm.sk.u_[r] = mx + __logf(smv);
      }
      __syncthreads();
      {
        const float4* up = (const float4*)(sm.sk.u_ + rg * 16);
#pragma unroll
        for (int q4 = 0; q4 < 4; ++q4) {
          float4 f = up[q4];
          tmp[q4 * 4 + 0] = kc[q4 * 4 + 0] - f.x; tmp[q4 * 4 + 1] = kc[q4 * 4 + 1] - f.y;
          tmp[q4 * 4 + 2] = kc[q4 * 4 + 2] - f.z; tmp[q4 * 4 + 3] = kc[q4 * 4 + 3] - f.w;
        }
        float mx = tmp[0];
#pragma unroll
        for (int q = 1; q < 16; ++q) mx = fmaxf(mx, tmp[q]);
        for (int m = 1; m < 8; m <<= 1) mx = fmaxf(mx, __shfl_xor(mx, m));
        float smv = 0.f;
#pragma unroll
        for (int q = 0; q < 16; ++q) smv += __expf(tmp[q] - mx);
        for (int m = 1; m < 8; m <<= 1) smv += __shfl_xor(smv, m);
        if (rg == 0) sm.sk.v_[c] = mx + __logf(smv);
      }
      __syncthreads();
    }
    float ur = sm.sk.u_[r];
    float fsum = 0.f;
    {
      const float4* vp = (const float4*)(sm.sk.v_ + cg * 16);
#pragma unroll
      for (int q4 = 0; q4 < 4; ++q4) {
        float4 f = vp[q4];
        float vv[4] = {f.x, f.y, f.z, f.w};
#pragma unroll
        for (int j = 0; j < 4; ++j) {
          float P = __expf(kr[q4 * 4 + j] - ur - vv[j]);
          float pt = fminf(fmaxf(P, 1e-6f), 1.0f - 1e-6f);
          int col = cg * 16 + q4 * 4 + j;
          bool gt = (r < 64) == (col < 64);
          float wgt = gt ? (-0.25f * (1.f - pt) * (1.f - pt)) : (-0.75f * pt * pt);
          float lg = gt ? __logf(pt) : __logf(1.f - pt);
          fsum += wgt * lg;
        }
      }
    }
    for (int m = 1; m < 64; m <<= 1) fsum += __shfl_xor(fsum, m);
    if ((t & 63) == 0) sm.sk.red[t >> 6] = fsum;
    __syncthreads();
    if (t == 0) {
      float tt = 0.f; for (int i = 0; i < 16; ++i) tt += sm.sk.red[i];
      atomicAdd(acc + 1, tt * (1.0f / 131072.f));
      ticket_finalize(acc, out);
    }
  } else {
    // ============ cls MLP + BCE, 4 rows per block, bf16 W1t, kk split ============
    int row0 = (bid - 8) * 4;
    {
      int rr = t >> 8, cc = t & 255;
      sm.cls.xs[rr][cc] = bf2f(bufH[(size_t)(row0 + rr) * 256 + cc]);
    }
    __syncthreads();
    int grp = t >> 8, col = t & 127, kh = (t >> 7) & 1;
    const unsigned short* wp = w1t + (size_t)col * 256 + kh * 128;
    const float* xp = &sm.cls.xs[grp][kh * 128];
    float h = 0.f;
#pragma unroll
    for (int i = 0; i < 16; ++i) {
      u32x4 wv = *(const u32x4*)&wp[i * 8];
      const float* x8 = xp + i * 8;
      h += x8[0] * bf2f(wv[0] & 0xffffu) + x8[1] * bf2f(wv[0] >> 16)
         + x8[2] * bf2f(wv[1] & 0xffffu) + x8[3] * bf2f(wv[1] >> 16)
         + x8[4] * bf2f(wv[2] & 0xffffu) + x8[5] * bf2f(wv[2] >> 16)
         + x8[6] * bf2f(wv[3] & 0xffffu) + x8[7] * bf2f(wv[3] >> 16);
    }
    if (kh == 1) sm.cls.part[grp][col] = h;
    __syncthreads();
    if (kh == 0) {
      float z = h + sm.cls.part[grp][col] + b1[col];
      float p = fmaxf(z, 0.f) * W2[col];
#pragma unroll
      for (int m = 1; m < 64; m <<= 1) p += __shfl_xor(p, m);
      if ((t & 63) == 0) sm.cls.red[grp * 2 + ((t >> 6) & 1)] = p;
    }
    __syncthreads();
    if (t == 0) {
      float total = 0.f;
      float bb2 = b2[0];
#pragma unroll
      for (int g = 0; g < 4; ++g) {
        float z = sm.cls.red[2 * g] + sm.cls.red[2 * g + 1] + bb2;
        float lab = (((row0 + g) & 127) < 64) ? 1.f : 0.f;
        total += fmaxf(z, 0.f) - z * lab + log1pf(__expf(-fabsf(z)));
      }
      atomicAdd(acc, total * (1.0f / 1024.0f));
      ticket_finalize(acc, out);
    }
  }
}

extern "C" void kernel_launch(void* const* d_in, const int* in_sizes, int n_in,
                              void* d_out, int out_size, void* d_ws, size_t ws_size,
                              hipStream_t stream) {
  const float* feat_s  = (const float*)d_in[0];
  const float* score_s = (const float*)d_in[1];
  const float* feat_t  = (const float*)d_in[2];
  const float* score_t = (const float*)d_in[3];
  const float* head_W1 = (const float*)d_in[4];
  const float* head_b1 = (const float*)d_in[5];
  const float* head_W2 = (const float*)d_in[6];
  const float* head_b2 = (const float*)d_in[7];
  const float* intra_W = (const float*)d_in[8];
  const float* intra_b = (const float*)d_in[9];
  const float* cross_W = (const float*)d_in[10];
  const float* cross_b = (const float*)d_in[11];
  const float* cls_W1  = (const float*)d_in[12];
  const float* cls_b1  = (const float*)d_in[13];
  const float* cls_W2  = (const float*)d_in[14];
  const float* cls_b2  = (const float*)d_in[15];
  const float* aff_A   = (const float*)d_in[16];

  unsigned short* nodes_bf = (unsigned short*)d_ws;           // 2048*512
  unsigned short* bufA_bf  = nodes_bf + 2048 * 512;           // 2048*256
  unsigned short* bufB_bf  = bufA_bf + ROWS2 * DD;
  unsigned short* bufH_bf  = bufB_bf + ROWS2 * DD;
  unsigned short* qkv_bf   = bufH_bf + ROWS2 * DD;            // 3 planes
  unsigned short* attn_bf  = qkv_bf + 3 * ROWS2 * DD;
  unsigned short* wt       = attn_bf + ROWS2 * DD;            // 786432
  unsigned short* w1t      = wt + 786432;                     // 32768
  float* st1  = (float*)(w1t + 32768);                        // 2048*16
  float* st2  = st1 + ROWS2 * 16;
  float* acc  = st2 + ROWS2 * 16;                             // [loss0, loss1, pad, ticket]
  int*   idxb = (int*)(acc + 8);                              // 2048 ints
  float* out_f = (float*)d_out;

  unsigned short* wt_h1 = wt;
  unsigned short* wt_h2 = wt + 131072;
  unsigned short* wt_in = wt_h2 + 65536;
  unsigned short* wt_cr = wt_in + 4 * 65536;
  unsigned short* wt_af = wt_cr + 4 * 65536;

  head_kernel<<<832, 256, 0, stream>>>(score_s, score_t, idxb, acc,
                                       head_W1, head_W2, intra_W, cross_W, aff_A, cls_W1,
                                       wt, w1t);
  gather_kernel<<<2048, 256, 0, stream>>>(feat_s, feat_t, idxb, nodes_bf);

  dim3 g1(4, 64, 1);
  dim3 gq(4, 64, 3);
  const float* nulf = nullptr;
  float* nulw = nullptr;

  gemm_mf<512><<<g1, 256, 0, stream>>>(nodes_bf, wt_h1, head_b1, bufA_bf, nulw,
                                       0, 0, nulf, 0, st1, 0, 0, 0, 0, 0);
  gemm_mf<256><<<g1, 256, 0, stream>>>(bufA_bf, wt_h2, head_b2, bufB_bf, nulw,
                                       0, 0, st1, 1, st2, 0, 0, 0, 0, 0);
  gemm_mf<256><<<gq, 256, 0, stream>>>(bufB_bf, wt_in, intra_b, qkv_bf, nulw,
                                       0, 0, st2, 0, nulw, 0, 65536, ROWS2 * DD, 0, 256);
  attn_kernel<<<256, 256, 0, stream>>>(qkv_bf, qkv_bf + ROWS2 * DD, qkv_bf + 2 * ROWS2 * DD,
                                       attn_bf, 0);
  gemm_mf<256><<<g1, 256, 0, stream>>>(attn_bf, wt_in + 3 * 65536, intra_b + 768, bufH_bf, nulw,
                                       0, 0, nulf, 0, nulw, 0, 0, 0, 0, 0);   // G
  gemm_mf<256><<<gq, 256, 0, stream>>>(bufH_bf, wt_cr, cross_b, qkv_bf, nulw,
                                       0, 0, nulf, 0, nulw, 0, 65536, ROWS2 * DD, 0, 256);
  attn_kernel<<<256, 256, 0, stream>>>(qkv_bf, qkv_bf + ROWS2 * DD, qkv_bf + 2 * ROWS2 * DD,
                                       attn_bf, 1);
  gemm_mf<256><<<g1, 256, 0, stream>>>(attn_bf, wt_cr + 3 * 65536, cross_b + 768, bufH_bf, out_f,
                                       256, ROWS1, nulf, 0, nulw, 0, 0, 0, 0, 0); // C (+n1)
  tail_kernel<<<TAILB, 1024, 0, stream>>>(bufH_bf, wt_af, w1t, cls_b1, cls_W2, cls_b2,
                                          acc, out_f);
}